// Round 9
// baseline (603.144 us; speedup 1.0000x reference)
//
#include <hip/hip_runtime.h>
#include <math.h>

namespace {
constexpr int Bc = 2, Tc = 2048, Cc = 1024, Hc = 16, KVc = 4, HDc = 64, Ec = 8, Fc = 1024;
constexpr int Nc = Bc * Tc;               // 4096 tokens
constexpr int QKVD = Cc + 2 * KVc * HDc;  // 1536
constexpr int GRP = Hc / KVc;             // 4
constexpr float RBASE = 50000.0f;
constexpr int MAXTILES = 72;              // worst-case sum of ceil(cnt[e]/128)

// workspace layout (floats) — peak ≤ 24M floats = 96 MB (proven footprint)
// ---- attention phase ----
constexpr size_t OFF_WQH = 0;                        // 0.75M (attn_w hi, bf16)
constexpr size_t OFF_WQL = 768u * 1024;              // 0.75M
constexpr size_t OFF_WPH = 1536u * 1024;             // 0.5M  (proj_w hi)
constexpr size_t OFF_WPL = 2048u * 1024;             // 0.5M
constexpr size_t OFF_H   = 2560u * 1024;             // 4M    (rmsnorm out; dead after conv)
constexpr size_t OFF_HCH = 6656u * 1024;             // 2M    (conv out hi, bf16)
constexpr size_t OFF_HCL = 8704u * 1024;             // 2M
constexpr size_t OFF_QKV = 10752u * 1024;            // 6M fp32
constexpr size_t OFF_QHB = 16896u * 1024;            // 2M floats = 4M bf16 (q hi, tiled)
constexpr size_t OFF_QLB = 18944u * 1024;            // 2M floats (q lo)
constexpr size_t OFF_KHB = 20992u * 1024;            // 0.5M floats (k hi, tiled swz)
constexpr size_t OFF_KLB = 21504u * 1024;            // 0.5M
constexpr size_t OFF_VHB = 22016u * 1024;            // 0.5M (v hi, slab layout)
constexpr size_t OFF_VLB = 22528u * 1024;            // 0.5M
constexpr size_t OFF_YH  = 2560u * 1024;             // 2M (attn out hi; over dead h)
constexpr size_t OFF_YL  = 4608u * 1024;             // 2M
// ---- MoE phase (attention buffers dead) ----
constexpr size_t OFF_H2   = 0;                       // 4M (h2 fp32)
constexpr size_t OFF_H2BF = 4u * 1024 * 1024;        // 2M floats = 4M bf16
constexpr size_t OFF_EHBF = 6u * 1024 * 1024;        // 4M floats = 8192 x 1024 bf16
constexpr size_t OFF_WVBF = 10u * 1024 * 1024;       // 8.4M floats
constexpr size_t OFF_WOBF = 18u * 1024 * 1024 + 512u * 1024;  // 4.2M floats
constexpr size_t OFF_PROB = 23u * 1024 * 1024;       // 32k floats
constexpr size_t OFF_IDX  = OFF_PROB + 32768;        // 32k ints (E x Nc)
constexpr size_t OFF_WT   = OFF_IDX + 32768;         // 32k floats
constexpr size_t OFF_CNT  = OFF_WT + 32768;          // 64 ints
constexpr size_t OFF_META = OFF_CNT + 64;            // 32 ints
}

typedef __attribute__((ext_vector_type(8))) short short8v;   // 8 bf16 (4 VGPRs)
typedef __attribute__((ext_vector_type(4))) short short4v;   // 4 bf16 (2 VGPRs)
typedef __attribute__((ext_vector_type(4))) float f32x4;

#define MF32(a, b, c) __builtin_amdgcn_mfma_f32_16x16x32_bf16((a), (b), (c), 0, 0, 0)
#define AS1 __attribute__((address_space(1)))
#define AS3 __attribute__((address_space(3)))

__device__ __forceinline__ unsigned short f2b1(float f) {
  union { float f; unsigned int u; } x;
  x.f = f;
  unsigned int r = (x.u + 0x7FFFu + ((x.u >> 16) & 1u)) >> 16;
  return (unsigned short)r;
}

__device__ __forceinline__ float b2f(unsigned short h) {
  union { unsigned int u; float f; } x;
  x.u = (unsigned int)h << 16;
  return x.f;
}

// split fp32 -> bf16 hi + bf16 lo (x ~= hi + lo, |err| ~ 2^-18 |x|)
__device__ __forceinline__ void split4(float4 v, short4v& hi, short4v& lo) {
  unsigned short h0 = f2b1(v.x), h1 = f2b1(v.y), h2 = f2b1(v.z), h3 = f2b1(v.w);
  hi = short4v{(short)h0, (short)h1, (short)h2, (short)h3};
  lo = short4v{(short)f2b1(v.x - b2f(h0)), (short)f2b1(v.y - b2f(h1)),
               (short)f2b1(v.z - b2f(h2)), (short)f2b1(v.w - b2f(h3))};
}

// ---------------- rmsnorm ----------------
__global__ __launch_bounds__(256) void k_rmsnorm(const float* __restrict__ in,
                                                 const float* __restrict__ w,
                                                 float* __restrict__ out) {
  int n = blockIdx.x;
  int tid = threadIdx.x;
  const float* row = in + (size_t)n * Cc;
  float v[4];
  float ss = 0.f;
#pragma unroll
  for (int i = 0; i < 4; i++) {
    v[i] = row[tid + i * 256];
    ss += v[i] * v[i];
  }
#pragma unroll
  for (int m = 1; m < 64; m <<= 1) ss += __shfl_xor(ss, m);
  __shared__ float red[4];
  if ((tid & 63) == 0) red[tid >> 6] = ss;
  __syncthreads();
  float tot = red[0] + red[1] + red[2] + red[3];
  float rs = rsqrtf(tot * (1.0f / Cc) + 1e-6f);
  float* orow = out + (size_t)n * Cc;
#pragma unroll
  for (int i = 0; i < 4; i++) orow[tid + i * 256] = v[i] * rs * w[tid + i * 256];
}

// -------- causal depthwise conv1d, fused fp32->bf16 hi/lo split --------
__global__ __launch_bounds__(256) void k_conv_split(const float* __restrict__ h,
                                                    const float* __restrict__ cw,
                                                    unsigned short* __restrict__ oh,
                                                    unsigned short* __restrict__ ol) {
  int i4 = blockIdx.x * 256 + threadIdx.x;
  if (i4 >= Nc * Cc / 4) return;
  int idx = i4 * 4;
  int c = idx & (Cc - 1);
  int n = idx >> 10;
  int t = n & (Tc - 1);
  float4 z = make_float4(0.f, 0.f, 0.f, 0.f);
  float4 d2 = (t >= 2) ? *(const float4*)&h[idx - 2 * Cc] : z;
  float4 d1 = (t >= 1) ? *(const float4*)&h[idx - Cc] : z;
  float4 d0 = *(const float4*)&h[idx];
  float4 r;
  r.x = d2.x * cw[(c + 0) * 3] + d1.x * cw[(c + 0) * 3 + 1] + d0.x * cw[(c + 0) * 3 + 2];
  r.y = d2.y * cw[(c + 1) * 3] + d1.y * cw[(c + 1) * 3 + 1] + d0.y * cw[(c + 1) * 3 + 2];
  r.z = d2.z * cw[(c + 2) * 3] + d1.z * cw[(c + 2) * 3 + 1] + d0.z * cw[(c + 2) * 3 + 2];
  r.w = d2.w * cw[(c + 3) * 3] + d1.w * cw[(c + 3) * 3 + 1] + d0.w * cw[(c + 3) * 3 + 2];
  short4v hi, lo;
  split4(r, hi, lo);
  *(short4v*)&oh[idx] = hi;
  *(short4v*)&ol[idx] = lo;
}

// ---------------- fp32 -> bf16 hi/lo split (weights) ----------------
__global__ __launch_bounds__(256) void k_f2bsp(const float* __restrict__ in,
                                               unsigned short* __restrict__ oh,
                                               unsigned short* __restrict__ ol, int n) {
  int i = (blockIdx.x * 256 + threadIdx.x) * 4;
  if (i >= n) return;
  float4 v = *(const float4*)&in[i];
  short4v hi, lo;
  split4(v, hi, lo);
  *(short4v*)&oh[i] = hi;
  *(short4v*)&ol[i] = lo;
}

// ---------------- fp32 -> bf16 conversion ----------------
__global__ __launch_bounds__(256) void k_f2b(const float* __restrict__ in,
                                             unsigned short* __restrict__ outp, int n) {
  int i = (blockIdx.x * 256 + threadIdx.x) * 4;
  if (i >= n) return;
  float4 v = *(const float4*)&in[i];
  uint2 o;
  o.x = (unsigned int)f2b1(v.x) | ((unsigned int)f2b1(v.y) << 16);
  o.y = (unsigned int)f2b1(v.z) | ((unsigned int)f2b1(v.w) << 16);
  *(uint2*)&outp[i] = o;
}

// ------- bf16x3 MFMA GEMM: C = A.B^T with A,B split hi/lo (m97 structure) ----
// EPI 0: C = acc ; EPI 1: C = resid + acc
template <int EPI>
__global__ __launch_bounds__(256) void k_gemm_x3(const unsigned short* __restrict__ Ah,
                                                 const unsigned short* __restrict__ Al,
                                                 const unsigned short* __restrict__ Bh,
                                                 const unsigned short* __restrict__ Bl,
                                                 float* __restrict__ Cm,
                                                 const float* __restrict__ resid,
                                                 int M, int N, int K) {
  constexpr int BM = 128, BN = 128, BK = 32;
  __shared__ __align__(16) unsigned short lAh[BM * BK];
  __shared__ __align__(16) unsigned short lAl[BM * BK];
  __shared__ __align__(16) unsigned short lBh[BN * BK];
  __shared__ __align__(16) unsigned short lBl[BN * BK];
  int tid = threadIdx.x;
  int lane = tid & 63;
  int wave = tid >> 6;
  int wr = wave >> 1, wc = wave & 1;
  int m0 = blockIdx.y * BM, n0 = blockIdx.x * BN;

  f32x4 acc[4][4];
#pragma unroll
  for (int i = 0; i < 4; i++)
#pragma unroll
    for (int j = 0; j < 4; j++) acc[i][j] = (f32x4)0.f;

  int kf = (lane >> 4) * 8;
  int rl = lane & 15;

  for (int k0 = 0; k0 < K; k0 += BK) {
    __syncthreads();
#pragma unroll
    for (int j = 0; j < 2; j++) {
      int chunk = j * 256 + tid;
      int row = chunk >> 2;
      int cb = (chunk & 3) * 8;
      size_t aoff = (size_t)(m0 + row) * K + k0 + cb;
      size_t boff = (size_t)(n0 + row) * K + k0 + cb;
      __builtin_amdgcn_global_load_lds((const AS1 void*)(Ah + aoff),
                                       (AS3 void*)(&lAh[chunk * 8]), 16, 0, 0);
      __builtin_amdgcn_global_load_lds((const AS1 void*)(Al + aoff),
                                       (AS3 void*)(&lAl[chunk * 8]), 16, 0, 0);
      __builtin_amdgcn_global_load_lds((const AS1 void*)(Bh + boff),
                                       (AS3 void*)(&lBh[chunk * 8]), 16, 0, 0);
      __builtin_amdgcn_global_load_lds((const AS1 void*)(Bl + boff),
                                       (AS3 void*)(&lBl[chunk * 8]), 16, 0, 0);
    }
    asm volatile("s_waitcnt vmcnt(0)" ::: "memory");
    __syncthreads();

    short8v ah[4], al4[4], bh4[4], bl4[4];
#pragma unroll
    for (int i = 0; i < 4; i++) {
      int ro = (wr * 64 + i * 16 + rl) * BK + kf;
      ah[i] = *(const short8v*)&lAh[ro];
      al4[i] = *(const short8v*)&lAl[ro];
    }
#pragma unroll
    for (int j = 0; j < 4; j++) {
      int ro = (wc * 64 + j * 16 + rl) * BK + kf;
      bh4[j] = *(const short8v*)&lBh[ro];
      bl4[j] = *(const short8v*)&lBl[ro];
    }
#pragma unroll
    for (int i = 0; i < 4; i++)
#pragma unroll
      for (int j = 0; j < 4; j++) {
        acc[i][j] = MF32(ah[i], bh4[j], acc[i][j]);
        acc[i][j] = MF32(ah[i], bl4[j], acc[i][j]);
        acc[i][j] = MF32(al4[i], bh4[j], acc[i][j]);
      }
  }

  int cl = lane & 15;
  int rb = (lane >> 4) * 4;
#pragma unroll
  for (int i = 0; i < 4; i++) {
#pragma unroll
    for (int r = 0; r < 4; r++) {
      int m = m0 + wr * 64 + i * 16 + rb + r;
#pragma unroll
      for (int j = 0; j < 4; j++) {
        int n = n0 + wc * 64 + j * 16 + cl;
        size_t off = (size_t)m * N + n;
        if (EPI == 0) Cm[off] = acc[i][j][r];
        else Cm[off] = resid[off] + acc[i][j][r];
      }
    }
  }
}

// ------- grouped MoE up-proj + fused SwiGLU: all experts, one launch --------
__global__ __launch_bounds__(256) void k_moe_wv(const unsigned short* __restrict__ A,
                                                const unsigned short* __restrict__ Wv,
                                                unsigned short* __restrict__ Eh,
                                                const int* __restrict__ idx,
                                                const int* __restrict__ cnt,
                                                const int* __restrict__ meta) {
  constexpr int BK = 32;
  if ((int)blockIdx.y >= meta[16 + 8]) return;
  int e = 0;
#pragma unroll
  for (int i = 1; i < Ec; i++)
    if ((int)blockIdx.y >= meta[16 + i]) e = i;
  int lm = blockIdx.y - meta[16 + e];
  int count = cnt[e];
  int gb = meta[e];
  int m0 = lm * 128;
  int n0 = blockIdx.x * 128;

  __shared__ __align__(16) unsigned short lA[128 * BK];
  __shared__ __align__(16) unsigned short lBg[128 * BK];
  __shared__ __align__(16) unsigned short lBv[128 * BK];
  int tid = threadIdx.x;
  int lane = tid & 63;
  int wave = tid >> 6;
  int wr = wave >> 1, wc = wave & 1;

  const unsigned short* srcA[2];
  const unsigned short* srcG[2];
  const unsigned short* srcV[2];
#pragma unroll
  for (int j = 0; j < 2; j++) {
    int chunk = j * 256 + tid;
    int row = chunk >> 2, cb = (chunk & 3) * 8;
    int mrow = m0 + row;
    int tok = idx[e * Nc + (mrow < count ? mrow : count - 1)];
    srcA[j] = A + (size_t)tok * Cc + cb;
    const unsigned short* wbase = Wv + (size_t)e * 2 * Fc * Cc;
    srcG[j] = wbase + (size_t)(n0 + row) * Cc + cb;
    srcV[j] = wbase + (size_t)(Fc + n0 + row) * Cc + cb;
  }

  f32x4 accG[4][4], accV[4][4];
#pragma unroll
  for (int i = 0; i < 4; i++)
#pragma unroll
    for (int j = 0; j < 4; j++) {
      accG[i][j] = (f32x4)0.f;
      accV[i][j] = (f32x4)0.f;
    }

  int kf = (lane >> 4) * 8;
  int rl = lane & 15;

  for (int k0 = 0; k0 < Cc; k0 += BK) {
    __syncthreads();
#pragma unroll
    for (int j = 0; j < 2; j++) {
      int chunk = j * 256 + tid;
      __builtin_amdgcn_global_load_lds((const AS1 void*)(srcA[j] + k0),
                                       (AS3 void*)(&lA[chunk * 8]), 16, 0, 0);
      __builtin_amdgcn_global_load_lds((const AS1 void*)(srcG[j] + k0),
                                       (AS3 void*)(&lBg[chunk * 8]), 16, 0, 0);
      __builtin_amdgcn_global_load_lds((const AS1 void*)(srcV[j] + k0),
                                       (AS3 void*)(&lBv[chunk * 8]), 16, 0, 0);
    }
    asm volatile("s_waitcnt vmcnt(0)" ::: "memory");
    __syncthreads();

    short8v a[4], bg[4], bv[4];
#pragma unroll
    for (int i = 0; i < 4; i++)
      a[i] = *(const short8v*)&lA[(wr * 64 + i * 16 + rl) * BK + kf];
#pragma unroll
    for (int j = 0; j < 4; j++) {
      bg[j] = *(const short8v*)&lBg[(wc * 64 + j * 16 + rl) * BK + kf];
      bv[j] = *(const short8v*)&lBv[(wc * 64 + j * 16 + rl) * BK + kf];
    }
#pragma unroll
    for (int i = 0; i < 4; i++)
#pragma unroll
      for (int j = 0; j < 4; j++) {
        accG[i][j] = MF32(a[i], bg[j], accG[i][j]);
        accV[i][j] = MF32(a[i], bv[j], accV[i][j]);
      }
  }

  int cl = lane & 15;
  int rb = (lane >> 4) * 4;
#pragma unroll
  for (int i = 0; i < 4; i++) {
#pragma unroll
    for (int r = 0; r < 4; r++) {
      int m = m0 + wr * 64 + i * 16 + rb + r;
      if (m < count) {
        size_t gs = (size_t)(gb + m);
#pragma unroll
        for (int j = 0; j < 4; j++) {
          int n = n0 + wc * 64 + j * 16 + cl;
          float g = accG[i][j][r];
          float v = accV[i][j][r];
          Eh[gs * Fc + n] = f2b1(g / (1.0f + __expf(-g)) * v);
        }
      }
    }
  }
}

// ------- grouped MoE down-proj + weighted scatter: all experts, one launch ---
__global__ __launch_bounds__(256) void k_moe_wo(const unsigned short* __restrict__ Eh,
                                                const unsigned short* __restrict__ Wo,
                                                float* __restrict__ C,
                                                const int* __restrict__ idx,
                                                const float* __restrict__ wt,
                                                const int* __restrict__ cnt,
                                                const int* __restrict__ meta) {
  constexpr int BK = 32;
  if ((int)blockIdx.y >= meta[16 + 8]) return;
  int e = 0;
#pragma unroll
  for (int i = 1; i < Ec; i++)
    if ((int)blockIdx.y >= meta[16 + i]) e = i;
  int lm = blockIdx.y - meta[16 + e];
  int count = cnt[e];
  int gb = meta[e];
  int m0 = lm * 128;
  int n0 = blockIdx.x * 128;

  __shared__ __align__(16) unsigned short lA[128 * BK];
  __shared__ __align__(16) unsigned short lB[128 * BK];
  int tid = threadIdx.x;
  int lane = tid & 63;
  int wave = tid >> 6;
  int wr = wave >> 1, wc = wave & 1;

  f32x4 acc[4][4];
#pragma unroll
  for (int i = 0; i < 4; i++)
#pragma unroll
    for (int j = 0; j < 4; j++) acc[i][j] = (f32x4)0.f;

  int kf = (lane >> 4) * 8;
  int rl = lane & 15;

  for (int k0 = 0; k0 < Fc; k0 += BK) {
    __syncthreads();
#pragma unroll
    for (int j = 0; j < 2; j++) {
      int chunk = j * 256 + tid;
      int row = chunk >> 2;
      int cb = (chunk & 3) * 8;
      __builtin_amdgcn_global_load_lds(
          (const AS1 void*)(Eh + (size_t)(gb + m0 + row) * Fc + k0 + cb),
          (AS3 void*)(&lA[chunk * 8]), 16, 0, 0);
      __builtin_amdgcn_global_load_lds(
          (const AS1 void*)(Wo + (size_t)e * Cc * Fc + (size_t)(n0 + row) * Fc + k0 + cb),
          (AS3 void*)(&lB[chunk * 8]), 16, 0, 0);
    }
    asm volatile("s_waitcnt vmcnt(0)" ::: "memory");
    __syncthreads();

    short8v a[4], b[4];
#pragma unroll
    for (int i = 0; i < 4; i++)
      a[i] = *(const short8v*)&lA[(wr * 64 + i * 16 + rl) * BK + kf];
#pragma unroll
    for (int j = 0; j < 4; j++)
      b[j] = *(const short8v*)&lB[(wc * 64 + j * 16 + rl) * BK + kf];
#pragma unroll
    for (int i = 0; i < 4; i++)
#pragma unroll
      for (int j = 0; j < 4; j++)
        acc[i][j] = MF32(a[i], b[j], acc[i][j]);
  }

  int cl = lane & 15;
  int rb = (lane >> 4) * 4;
#pragma unroll
  for (int i = 0; i < 4; i++) {
#pragma unroll
    for (int r = 0; r < 4; r++) {
      int m = m0 + wr * 64 + i * 16 + rb + r;
      if (m < count) {
        int slot = e * Nc + m;
        int tok = idx[slot];
        float w = wt[slot];
#pragma unroll
        for (int j = 0; j < 4; j++) {
          int n = n0 + wc * 64 + j * 16 + cl;
          atomicAdd(&C[(size_t)tok * Cc + n], w * acc[i][j][r]);
        }
      }
    }
  }
}

// ---------------- RoPE + layernorm ----------------
__device__ __forceinline__ float rope_ln(float q, int lane, int t, float scale) {
  int j = lane & 31;
  float invf = powf(RBASE, -(float)j * (1.0f / 32.0f));
  float ang = (float)t * invf;
  float s, c;
  sincosf(ang, &s, &c);
  float p = __shfl_xor(q, 32);
  float rot = (lane < 32) ? -p : p;
  float qr = q * c + rot * s;
  float sum = qr, sq = qr * qr;
#pragma unroll
  for (int m = 1; m < 64; m <<= 1) {
    sum += __shfl_xor(sum, m);
    sq += __shfl_xor(sq, m);
  }
  float mean = sum * (1.0f / 64.0f);
  float var = sq * (1.0f / 64.0f) - mean * mean;
  return (qr - mean) * rsqrtf(var + 1e-5f) * scale;
}

// Q: write bf16 hi/lo in pre-swizzled tile-blocked layout (matches old LDS bytes):
//   tile (64 rows x 64 d) at ((b*H+h)*32 + t/64)*4096; short off = row*64 + (d ^ ((row&7)<<3))
__global__ __launch_bounds__(256) void k_ropeln_q(const float* __restrict__ qkv,
                                                  unsigned short* __restrict__ qh,
                                                  unsigned short* __restrict__ ql) {
  int gw = (blockIdx.x * 256 + threadIdx.x) >> 6;
  int lane = threadIdx.x & 63;
  if (gw >= Nc * Hc) return;
  int h = gw & (Hc - 1);
  int n = gw / Hc;
  int t = n & (Tc - 1);
  int b = n / Tc;
  float q = qkv[(size_t)n * QKVD + h * HDc + lane];
  float o = rope_ln(q, lane, t, 0.125f);  // fold 1/sqrt(hd)
  int row = t & 63;
  size_t ob = (((size_t)(b * Hc + h)) * 32 + (t >> 6)) * 4096 + row * 64 +
              (lane ^ ((row & 7) << 3));
  unsigned short hi = f2b1(o);
  qh[ob] = hi;
  ql[ob] = f2b1(o - b2f(hi));
}

// K: same swizzled tile layout as Q. V: tr_read slab layout:
//   short off = (d>>4)*1024 + row*16 + (d&15), tile at ((b*KV+kv)*32 + t/64)*4096
__global__ __launch_bounds__(256) void k_ropeln_kv(const float* __restrict__ qkv,
                                                   unsigned short* __restrict__ kh,
                                                   unsigned short* __restrict__ kl,
                                                   unsigned short* __restrict__ vh,
                                                   unsigned short* __restrict__ vl) {
  int gw = (blockIdx.x * 256 + threadIdx.x) >> 6;
  int lane = threadIdx.x & 63;
  if (gw >= Nc * KVc) return;
  int kv = gw & (KVc - 1);
  int n = gw / KVc;
  int t = n & (Tc - 1);
  int b = n / Tc;
  size_t base = (size_t)n * QKVD + Cc + kv * HDc;
  float kval = qkv[base + lane];
  float vval = qkv[base + KVc * HDc + lane];
  float o = rope_ln(kval, lane, t, 1.0f);
  int row = t & 63;
  size_t tb = (((size_t)(b * KVc + kv)) * 32 + (t >> 6)) * 4096;
  size_t ko = tb + row * 64 + (lane ^ ((row & 7) << 3));
  unsigned short khi = f2b1(o);
  kh[ko] = khi;
  kl[ko] = f2b1(o - b2f(khi));
  size_t vo = tb + (lane >> 4) * 1024 + row * 16 + (lane & 15);
  unsigned short vhi = f2b1(vval);
  vh[vo] = vhi;
  vl[vo] = f2b1(vval - b2f(vhi));
}

// ---------------- flash attention, bf16x3 MFMA, swapped-operand S^T ---------
// BQ=64 (4 waves x 16 q), BK=64. Double-buffered K/V (80KB LDS, 2 blocks/CU):
// issue STAGE(kt+1) before waiting vmcnt(8) for tile kt -> loads in flight
// across the whole compute phase (counted vmcnt, never drained mid-loop).
#define TRD(dst, off) \
  asm volatile("ds_read_b64_tr_b16 %0, %1 offset:" off : "=v"(dst) : "v"(va))

__global__ __launch_bounds__(256, 2) void k_attn2(const unsigned short* __restrict__ Qh,
                                                  const unsigned short* __restrict__ Ql,
                                                  const unsigned short* __restrict__ Kht,
                                                  const unsigned short* __restrict__ Klt,
                                                  const unsigned short* __restrict__ Vht,
                                                  const unsigned short* __restrict__ Vlt,
                                                  unsigned short* __restrict__ Yh,
                                                  unsigned short* __restrict__ Yl) {
  __shared__ __align__(16) unsigned char smem[81920];
  constexpr unsigned QH = 0, QL = 8192, PB = 0;   // P aliases Q after frag read
  int tid = threadIdx.x;
  int l = tid & 63, w = tid >> 6, g = l >> 4, q15 = l & 15;
  int qtile = gridDim.x - 1 - blockIdx.x;  // longest causal blocks dispatched first
  int hh = blockIdx.y, b = blockIdx.z;
  int kvh = hh >> 2;  // GQA
  size_t qtb = (((size_t)(b * Hc + hh)) * 32 + qtile) * 4096;
  size_t kvb = ((size_t)(b * KVc + kvh)) * 32 * 4096;

  // K/V double buffers at 16K and 48K: [KH 8K][KL 8K][VH 8K][VL 8K] each
  const unsigned bufb[2] = {16384u, 49152u};

  auto STAGE = [&](unsigned bb, int kt) {
    size_t ktb = kvb + (size_t)kt * 4096;
#pragma unroll
    for (int j = 0; j < 2; j++) {
      int chunk = j * 256 + tid;
      __builtin_amdgcn_global_load_lds((const AS1 void*)(Kht + ktb + chunk * 8),
                                       (AS3 void*)(smem + bb + chunk * 16), 16, 0, 0);
      __builtin_amdgcn_global_load_lds((const AS1 void*)(Klt + ktb + chunk * 8),
                                       (AS3 void*)(smem + bb + 8192 + chunk * 16), 16, 0, 0);
      __builtin_amdgcn_global_load_lds((const AS1 void*)(Vht + ktb + chunk * 8),
                                       (AS3 void*)(smem + bb + 16384 + chunk * 16), 16, 0, 0);
      __builtin_amdgcn_global_load_lds((const AS1 void*)(Vlt + ktb + chunk * 8),
                                       (AS3 void*)(smem + bb + 24576 + chunk * 16), 16, 0, 0);
    }
  };

  // ---- prologue: issue Q loads (4) + tile-0 K/V loads (8), wait Q only ----
#pragma unroll
  for (int j = 0; j < 2; j++) {
    int chunk = j * 256 + tid;
    __builtin_amdgcn_global_load_lds((const AS1 void*)(Qh + qtb + chunk * 8),
                                     (AS3 void*)(smem + QH + chunk * 16), 16, 0, 0);
    __builtin_amdgcn_global_load_lds((const AS1 void*)(Ql + qtb + chunk * 8),
                                     (AS3 void*)(smem + QL + chunk * 16), 16, 0, 0);
  }
  STAGE(bufb[0], 0);
  asm volatile("s_waitcnt vmcnt(8)" ::: "memory");  // Q's 4 loads (oldest) done
  __syncthreads();
  unsigned qsw = (unsigned)((q15 & 7) << 4);
  unsigned qro = (unsigned)((w * 16 + q15) * 128);
  short8v qhf[2], qlf[2];
  qhf[0] = *(const short8v*)(smem + QH + qro + ((16 * g) ^ qsw));
  qhf[1] = *(const short8v*)(smem + QH + qro + ((64 + 16 * g) ^ qsw));
  qlf[0] = *(const short8v*)(smem + QL + qro + ((16 * g) ^ qsw));
  qlf[1] = *(const short8v*)(smem + QL + qro + ((64 + 16 * g) ^ qsw));

  f32x4 o[4];
#pragma unroll
  for (int dt = 0; dt < 4; dt++) o[dt] = (f32x4)0.f;
  float m = -1e30f, lsum = 0.f;
  int qloc = w * 16 + q15;
  int cur = 0;

  for (int kt = 0; kt <= qtile; ++kt) {
    // issue next-tile loads into spare buffer BEFORE waiting on current tile
    if (kt < qtile) {
      STAGE(bufb[cur ^ 1], kt + 1);
      asm volatile("s_waitcnt vmcnt(8)" ::: "memory");  // tile kt (oldest 8) ready
    } else {
      asm volatile("s_waitcnt vmcnt(0)" ::: "memory");
    }
    __syncthreads();
    const bool diag = (kt == qtile);
    unsigned kb = bufb[cur];

    // ---- S^T = K·Q^T (3-term bf16 split), per wave: [64 keys][16 q] ----
    f32x4 sv[4];
    __builtin_amdgcn_s_setprio(1);
#pragma unroll
    for (int s = 0; s < 4; ++s) {
      unsigned ro = (unsigned)((s * 16 + q15) * 128);
      short8v kh0 = *(const short8v*)(smem + kb + ro + ((16 * g) ^ qsw));
      short8v kh1 = *(const short8v*)(smem + kb + ro + ((64 + 16 * g) ^ qsw));
      short8v kl0 = *(const short8v*)(smem + kb + 8192 + ro + ((16 * g) ^ qsw));
      short8v kl1 = *(const short8v*)(smem + kb + 8192 + ro + ((64 + 16 * g) ^ qsw));
      f32x4 a = (f32x4)0.f;
      a = MF32(kh0, qhf[0], a);
      a = MF32(kh1, qhf[1], a);
      a = MF32(kh0, qlf[0], a);
      a = MF32(kh1, qlf[1], a);
      a = MF32(kl0, qhf[0], a);
      a = MF32(kl1, qhf[1], a);
      sv[s] = a;
    }
    __builtin_amdgcn_s_setprio(0);
    // ---- causal mask + online softmax ----
    float mx = -1e30f;
#pragma unroll
    for (int s = 0; s < 4; ++s)
#pragma unroll
      for (int r = 0; r < 4; ++r) {
        if (diag && (s * 16 + g * 4 + r) > qloc) sv[s][r] = -1e30f;
        mx = fmaxf(mx, sv[s][r]);
      }
    mx = fmaxf(mx, __shfl_xor(mx, 16));
    mx = fmaxf(mx, __shfl_xor(mx, 32));
    float mnew = fmaxf(m, mx);
    float alpha = __expf(m - mnew);
    float p[4][4];
    float ps = 0.f;
#pragma unroll
    for (int s = 0; s < 4; ++s)
#pragma unroll
      for (int r = 0; r < 4; ++r) {
        p[s][r] = __expf(sv[s][r] - mnew);
        ps += p[s][r];
      }
    ps += __shfl_xor(ps, 16);
    ps += __shfl_xor(ps, 32);
    lsum = lsum * alpha + ps;
    m = mnew;
#pragma unroll
    for (int dt = 0; dt < 4; dt++) o[dt] *= alpha;
    // ---- P -> bf16 hi/lo, bounce through per-wave LDS ----
#pragma unroll
    for (int s = 0; s < 4; ++s) {
      unsigned short h0 = f2b1(p[s][0]), h1 = f2b1(p[s][1]), h2 = f2b1(p[s][2]),
                     h3 = f2b1(p[s][3]);
      short4v ph = short4v{(short)h0, (short)h1, (short)h2, (short)h3};
      short4v pl = short4v{(short)f2b1(p[s][0] - b2f(h0)), (short)f2b1(p[s][1] - b2f(h1)),
                           (short)f2b1(p[s][2] - b2f(h2)), (short)f2b1(p[s][3] - b2f(h3))};
      unsigned pb = (unsigned)(PB + w * 4096 + q15 * 128 +
                               (((unsigned)(s * 32 + 8 * g)) ^ qsw));
      *(short4v*)(smem + pb) = ph;
      *(short4v*)(smem + pb + 2048) = pl;
    }
    asm volatile("" ::: "memory");
    // ---- O^T += V^T·P^T (3-term), V^T frags via HW transpose-read ----
#pragma unroll
    for (int u = 0; u < 2; ++u) {
      unsigned va = (unsigned)(kb + 16384 + u * 1024 + g * 256 + q15 * 8);
      unsigned pq = (unsigned)(PB + w * 4096 + q15 * 128 +
                               (((unsigned)(u * 64 + 16 * g)) ^ qsw));
      short8v ph8 = *(const short8v*)(smem + pq);
      short8v pl8 = *(const short8v*)(smem + pq + 2048);
      {  // dt 0,1
        short4v a0, a1, b0, b1, c0, c1, d0, d1;
        TRD(a0, "0");
        TRD(a1, "128");
        TRD(b0, "2048");
        TRD(b1, "2176");
        TRD(c0, "8192");
        TRD(c1, "8320");
        TRD(d0, "10240");
        TRD(d1, "10368");
        asm volatile("s_waitcnt lgkmcnt(0)" ::: "memory");
        __builtin_amdgcn_sched_barrier(0);
        short8v v0h = __builtin_shufflevector(a0, a1, 0, 1, 2, 3, 4, 5, 6, 7);
        short8v v1h = __builtin_shufflevector(b0, b1, 0, 1, 2, 3, 4, 5, 6, 7);
        short8v v0l = __builtin_shufflevector(c0, c1, 0, 1, 2, 3, 4, 5, 6, 7);
        short8v v1l = __builtin_shufflevector(d0, d1, 0, 1, 2, 3, 4, 5, 6, 7);
        __builtin_amdgcn_s_setprio(1);
        o[0] = MF32(v0h, ph8, o[0]);
        o[0] = MF32(v0h, pl8, o[0]);
        o[0] = MF32(v0l, ph8, o[0]);
        o[1] = MF32(v1h, ph8, o[1]);
        o[1] = MF32(v1h, pl8, o[1]);
        o[1] = MF32(v1l, ph8, o[1]);
        __builtin_amdgcn_s_setprio(0);
      }
      {  // dt 2,3
        short4v a0, a1, b0, b1, c0, c1, d0, d1;
        TRD(a0, "4096");
        TRD(a1, "4224");
        TRD(b0, "6144");
        TRD(b1, "6272");
        TRD(c0, "12288");
        TRD(c1, "12416");
        TRD(d0, "14336");
        TRD(d1, "14464");
        asm volatile("s_waitcnt lgkmcnt(0)" ::: "memory");
        __builtin_amdgcn_sched_barrier(0);
        short8v v2h = __builtin_shufflevector(a0, a1, 0, 1, 2, 3, 4, 5, 6, 7);
        short8v v3h = __builtin_shufflevector(b0, b1, 0, 1, 2, 3, 4, 5, 6, 7);
        short8v v2l = __builtin_shufflevector(c0, c1, 0, 1, 2, 3, 4, 5, 6, 7);
        short8v v3l = __builtin_shufflevector(d0, d1, 0, 1, 2, 3, 4, 5, 6, 7);
        __builtin_amdgcn_s_setprio(1);
        o[2] = MF32(v2h, ph8, o[2]);
        o[2] = MF32(v2h, pl8, o[2]);
        o[2] = MF32(v2l, ph8, o[2]);
        o[3] = MF32(v3h, ph8, o[3]);
        o[3] = MF32(v3h, pl8, o[3]);
        o[3] = MF32(v3l, ph8, o[3]);
        __builtin_amdgcn_s_setprio(0);
      }
    }
    __syncthreads();  // all waves done reading buf[cur] before next STAGE hits it
    cur ^= 1;
  }
  // ---- epilogue: write y as bf16 hi/lo (feeds bf16x3 proj GEMM) ----
  float inv = 1.0f / lsum;
  size_t ybase = ((size_t)(b * Tc + qtile * 64 + qloc)) * Cc + hh * 64;
#pragma unroll
  for (int dt = 0; dt < 4; dt++) {
    float4 s4 = make_float4(o[dt][0] * inv, o[dt][1] * inv, o[dt][2] * inv, o[dt][3] * inv);
    short4v hi, lo;
    split4(s4, hi, lo);
    *(short4v*)&Yh[ybase + dt * 16 + 4 * g] = hi;
    *(short4v*)&Yl[ybase + dt * 16 + 4 * g] = lo;
  }
}

// ---------------- zero expert counters ----------------
__global__ void k_zcnt(int* cnt) {
  if (threadIdx.x < Ec) cnt[threadIdx.x] = 0;
}

// ---------------- prefix sums: gbase + tilebase ----------------
__global__ void k_meta(const int* __restrict__ cnt, int* __restrict__ meta) {
  if (threadIdx.x == 0) {
    int gb = 0, tb = 0;
    for (int e = 0; e < Ec; e++) {
      meta[e] = gb;
      meta[16 + e] = tb;
      gb += cnt[e];
      tb += (cnt[e] + 127) >> 7;
    }
    meta[8] = gb;
    meta[16 + 8] = tb;
  }
}

// ---------------- router: softmax -> top2 -> compact assignment lists --------
__global__ __launch_bounds__(256) void k_router(const float* __restrict__ h2,
                                                const float* __restrict__ rw,
                                                float* __restrict__ probs,
                                                int* __restrict__ idx,
                                                float* __restrict__ wt,
                                                int* __restrict__ cnt) {
  int gw = (blockIdx.x * 256 + threadIdx.x) >> 6;
  int lane = threadIdx.x & 63;
  if (gw >= Nc) return;
  const float* row = h2 + (size_t)gw * Cc;
  float acc[Ec] = {};
  for (int k = lane; k < Cc; k += 64) {
    float hv = row[k];
#pragma unroll
    for (int e = 0; e < Ec; e++) acc[e] += hv * rw[e * Cc + k];
  }
#pragma unroll
  for (int e = 0; e < Ec; e++) {
#pragma unroll
    for (int msk = 1; msk < 64; msk <<= 1) acc[e] += __shfl_xor(acc[e], msk);
  }
  if (lane == 0) {
    float mx = acc[0];
#pragma unroll
    for (int e = 1; e < Ec; e++) mx = fmaxf(mx, acc[e]);
    float p[Ec];
    float s = 0.f;
#pragma unroll
    for (int e = 0; e < Ec; e++) {
      p[e] = expf(acc[e] - mx);
      s += p[e];
    }
    float invs = 1.0f / s;
#pragma unroll
    for (int e = 0; e < Ec; e++) {
      p[e] *= invs;
      probs[(size_t)gw * Ec + e] = p[e];
    }
    int i0 = 0;
#pragma unroll
    for (int e = 1; e < Ec; e++)
      if (p[e] > p[i0]) i0 = e;
    int i1 = (i0 == 0) ? 1 : 0;
#pragma unroll
    for (int e = 0; e < Ec; e++)
      if (e != i0 && p[e] > p[i1]) i1 = e;
    float wsum = p[i0] + p[i1];
    int s0 = atomicAdd(&cnt[i0], 1);
    idx[i0 * Nc + s0] = gw;
    wt[i0 * Nc + s0] = p[i0] / wsum;
    int s1 = atomicAdd(&cnt[i1], 1);
    idx[i1 * Nc + s1] = gw;
    wt[i1 * Nc + s1] = p[i1] / wsum;
  }
}

__global__ __launch_bounds__(256) void k_aux(const float* __restrict__ probs,
                                             float* __restrict__ outp) {
  int tid = threadIdx.x;
  int lane = tid & 63, w = tid >> 6;
  float acc[Ec] = {};
  for (int n = tid; n < Nc; n += 256) {
#pragma unroll
    for (int e = 0; e < Ec; e++) acc[e] += probs[(size_t)n * Ec + e];
  }
#pragma unroll
  for (int e = 0; e < Ec; e++) {
#pragma unroll
    for (int msk = 1; msk < 64; msk <<= 1) acc[e] += __shfl_xor(acc[e], msk);
  }
  __shared__ float red[4][Ec];
  if (lane == 0) {
#pragma unroll
    for (int e = 0; e < Ec; e++) red[w][e] = acc[e];
  }
  __syncthreads();
  if (tid == 0) {
    float aux = 0.f;
#pragma unroll
    for (int e = 0; e < Ec; e++) {
      float tot = red[0][e] + red[1][e] + red[2][e] + red[3][e];
      float avg = tot * (1.0f / Nc);
      aux += avg * avg;
    }
    outp[0] = (float)Ec * aux;
  }
}

extern "C" void kernel_launch(void* const* d_in, const int* in_sizes, int n_in,
                              void* d_out, int out_size, void* d_ws, size_t ws_size,
                              hipStream_t stream) {
  const float* x      = (const float*)d_in[0];
  const float* ln1_w  = (const float*)d_in[1];
  const float* ln2_w  = (const float*)d_in[2];
  const float* conv_w = (const float*)d_in[3];
  const float* attn_w = (const float*)d_in[4];
  const float* proj_w = (const float*)d_in[5];
  const float* rout_w = (const float*)d_in[6];
  const float* ewv    = (const float*)d_in[7];
  const float* ewo    = (const float*)d_in[8];
  float* out = (float*)d_out;
  float* ws = (float*)d_ws;

  float* h    = ws + OFF_H;
  float* qkv  = ws + OFF_QKV;
  float* h2   = ws + OFF_H2;
  float* prob = ws + OFF_PROB;
  int*   idxp = (int*)(ws + OFF_IDX);
  float* wtp  = ws + OFF_WT;
  int*   cntp = (int*)(ws + OFF_CNT);
  int*   metap = (int*)(ws + OFF_META);
  unsigned short* wqh = (unsigned short*)(ws + OFF_WQH);
  unsigned short* wql = (unsigned short*)(ws + OFF_WQL);
  unsigned short* wph = (unsigned short*)(ws + OFF_WPH);
  unsigned short* wpl = (unsigned short*)(ws + OFF_WPL);
  unsigned short* hch = (unsigned short*)(ws + OFF_HCH);
  unsigned short* hcl = (unsigned short*)(ws + OFF_HCL);
  unsigned short* qhb = (unsigned short*)(ws + OFF_QHB);
  unsigned short* qlb = (unsigned short*)(ws + OFF_QLB);
  unsigned short* khb = (unsigned short*)(ws + OFF_KHB);
  unsigned short* klb = (unsigned short*)(ws + OFF_KLB);
  unsigned short* vhb = (unsigned short*)(ws + OFF_VHB);
  unsigned short* vlb = (unsigned short*)(ws + OFF_VLB);
  unsigned short* yh  = (unsigned short*)(ws + OFF_YH);
  unsigned short* yl  = (unsigned short*)(ws + OFF_YL);
  unsigned short* h2bf = (unsigned short*)(ws + OFF_H2BF);
  unsigned short* ehbf = (unsigned short*)(ws + OFF_EHBF);
  unsigned short* wvbf = (unsigned short*)(ws + OFF_WVBF);
  unsigned short* wobf = (unsigned short*)(ws + OFF_WOBF);

  // attention branch
  k_rmsnorm<<<Nc, 256, 0, stream>>>(x, ln1_w, h);
  k_conv_split<<<(Nc * Cc / 4) / 256, 256, 0, stream>>>(h, conv_w, hch, hcl);
  k_f2bsp<<<(QKVD * Cc / 4) / 256, 256, 0, stream>>>(attn_w, wqh, wql, QKVD * Cc);
  k_f2bsp<<<(Cc * Cc / 4) / 256, 256, 0, stream>>>(proj_w, wph, wpl, Cc * Cc);
  {
    dim3 g(QKVD / 128, Nc / 128);
    k_gemm_x3<0><<<g, 256, 0, stream>>>(hch, hcl, wqh, wql, qkv, nullptr, Nc, QKVD, Cc);
  }
  k_ropeln_q<<<(Nc * Hc * 64) / 256, 256, 0, stream>>>(qkv, qhb, qlb);
  k_ropeln_kv<<<(Nc * KVc * 64) / 256, 256, 0, stream>>>(qkv, khb, klb, vhb, vlb);
  k_attn2<<<dim3(Tc / 64, Hc, Bc), 256, 0, stream>>>(qhb, qlb, khb, klb, vhb, vlb, yh, yl);
  {
    dim3 g(Cc / 128, Nc / 128);
    k_gemm_x3<1><<<g, 256, 0, stream>>>(yh, yl, wph, wpl, out, x, Nc, Cc, Cc);
  }
  // MoE branch: router -> grouped single-launch expert GEMMs (fused silu)
  k_rmsnorm<<<Nc, 256, 0, stream>>>(out, ln2_w, h2);
  k_f2b<<<(Nc * Cc / 4) / 256, 256, 0, stream>>>(h2, h2bf, Nc * Cc);
  k_zcnt<<<1, 64, 0, stream>>>(cntp);
  k_router<<<Nc / 4, 256, 0, stream>>>(h2, rout_w, prob, idxp, wtp, cntp);
  k_meta<<<1, 64, 0, stream>>>(cntp, metap);
  k_aux<<<1, 256, 0, stream>>>(prob, out + (size_t)Nc * Cc);
  k_f2b<<<(Ec * 2 * Fc * Cc / 4) / 256, 256, 0, stream>>>(ewv, wvbf, Ec * 2 * Fc * Cc);
  k_f2b<<<(Ec * Cc * Fc / 4) / 256, 256, 0, stream>>>(ewo, wobf, Ec * Cc * Fc);
  k_moe_wv<<<dim3(Fc / 128, MAXTILES), 256, 0, stream>>>(h2bf, wvbf, ehbf, idxp, cntp, metap);
  k_moe_wo<<<dim3(Cc / 128, MAXTILES), 256, 0, stream>>>(ehbf, wobf, out, idxp, wtp, cntp,
                                                         metap);
}

// Round 10
// 590.994 us; speedup vs baseline: 1.0206x; 1.0206x over previous
//
#include <hip/hip_runtime.h>
#include <math.h>

namespace {
constexpr int Bc = 2, Tc = 2048, Cc = 1024, Hc = 16, KVc = 4, HDc = 64, Ec = 8, Fc = 1024;
constexpr int Nc = Bc * Tc;               // 4096 tokens
constexpr int QKVD = Cc + 2 * KVc * HDc;  // 1536
constexpr int GRP = Hc / KVc;             // 4
constexpr float RBASE = 50000.0f;
constexpr int MAXTILES = 72;              // worst-case sum of ceil(cnt[e]/128)

// workspace layout (floats) — peak ≤ 24M floats = 96 MB (proven footprint)
// ---- attention phase ----
constexpr size_t OFF_WQH = 0;                        // 0.75M (attn_w hi, bf16)
constexpr size_t OFF_WQL = 768u * 1024;              // 0.75M
constexpr size_t OFF_WPH = 1536u * 1024;             // 0.5M  (proj_w hi)
constexpr size_t OFF_WPL = 2048u * 1024;             // 0.5M
constexpr size_t OFF_H   = 2560u * 1024;             // 4M    (rmsnorm out; dead after conv)
constexpr size_t OFF_HCH = 6656u * 1024;             // 2M    (conv out hi, bf16)
constexpr size_t OFF_HCL = 8704u * 1024;             // 2M
constexpr size_t OFF_QKV = 10752u * 1024;            // 6M fp32
constexpr size_t OFF_QHB = 16896u * 1024;            // 2M floats = 4M bf16 (q hi, tiled)
constexpr size_t OFF_QLB = 18944u * 1024;            // 2M floats (q lo)
constexpr size_t OFF_KHB = 20992u * 1024;            // 0.5M floats (k hi, tiled swz)
constexpr size_t OFF_KLB = 21504u * 1024;            // 0.5M
constexpr size_t OFF_VHB = 22016u * 1024;            // 0.5M (vT hi, tiled swz)
constexpr size_t OFF_VLB = 22528u * 1024;            // 0.5M
constexpr size_t OFF_YH  = 2560u * 1024;             // 2M (attn out hi; over dead h)
constexpr size_t OFF_YL  = 4608u * 1024;             // 2M
// ---- MoE phase (attention buffers dead) ----
constexpr size_t OFF_H2   = 0;                       // 4M (h2 fp32)
constexpr size_t OFF_H2BF = 4u * 1024 * 1024;        // 2M floats = 4M bf16
constexpr size_t OFF_EHBF = 6u * 1024 * 1024;        // 4M floats = 8192 x 1024 bf16
constexpr size_t OFF_WVBF = 10u * 1024 * 1024;       // 8.4M floats
constexpr size_t OFF_WOBF = 18u * 1024 * 1024 + 512u * 1024;  // 4.2M floats
constexpr size_t OFF_PROB = 23u * 1024 * 1024;       // 32k floats
constexpr size_t OFF_IDX  = OFF_PROB + 32768;        // 32k ints (E x Nc)
constexpr size_t OFF_WT   = OFF_IDX + 32768;         // 32k floats
constexpr size_t OFF_CNT  = OFF_WT + 32768;          // 64 ints
constexpr size_t OFF_META = OFF_CNT + 64;            // 32 ints
}

typedef __attribute__((ext_vector_type(8))) short short8v;   // 8 bf16 (4 VGPRs)
typedef __attribute__((ext_vector_type(4))) short short4v;   // 4 bf16 (2 VGPRs)
typedef __attribute__((ext_vector_type(4))) float f32x4;

#define MF32(a, b, c) __builtin_amdgcn_mfma_f32_16x16x32_bf16((a), (b), (c), 0, 0, 0)
#define AS1 __attribute__((address_space(1)))
#define AS3 __attribute__((address_space(3)))

__device__ __forceinline__ unsigned short f2b1(float f) {
  union { float f; unsigned int u; } x;
  x.f = f;
  unsigned int r = (x.u + 0x7FFFu + ((x.u >> 16) & 1u)) >> 16;
  return (unsigned short)r;
}

__device__ __forceinline__ float b2f(unsigned short h) {
  union { unsigned int u; float f; } x;
  x.u = (unsigned int)h << 16;
  return x.f;
}

// split fp32 -> bf16 hi + bf16 lo (x ~= hi + lo, |err| ~ 2^-18 |x|)
__device__ __forceinline__ void split4(float4 v, short4v& hi, short4v& lo) {
  unsigned short h0 = f2b1(v.x), h1 = f2b1(v.y), h2 = f2b1(v.z), h3 = f2b1(v.w);
  hi = short4v{(short)h0, (short)h1, (short)h2, (short)h3};
  lo = short4v{(short)f2b1(v.x - b2f(h0)), (short)f2b1(v.y - b2f(h1)),
               (short)f2b1(v.z - b2f(h2)), (short)f2b1(v.w - b2f(h3))};
}

// ---------------- rmsnorm ----------------
__global__ __launch_bounds__(256) void k_rmsnorm(const float* __restrict__ in,
                                                 const float* __restrict__ w,
                                                 float* __restrict__ out) {
  int n = blockIdx.x;
  int tid = threadIdx.x;
  const float* row = in + (size_t)n * Cc;
  float v[4];
  float ss = 0.f;
#pragma unroll
  for (int i = 0; i < 4; i++) {
    v[i] = row[tid + i * 256];
    ss += v[i] * v[i];
  }
#pragma unroll
  for (int m = 1; m < 64; m <<= 1) ss += __shfl_xor(ss, m);
  __shared__ float red[4];
  if ((tid & 63) == 0) red[tid >> 6] = ss;
  __syncthreads();
  float tot = red[0] + red[1] + red[2] + red[3];
  float rs = rsqrtf(tot * (1.0f / Cc) + 1e-6f);
  float* orow = out + (size_t)n * Cc;
#pragma unroll
  for (int i = 0; i < 4; i++) orow[tid + i * 256] = v[i] * rs * w[tid + i * 256];
}

// ----- rmsnorm + bf16 copy + expert-counter zeroing (MoE-side, fused) -----
__global__ __launch_bounds__(256) void k_rmsnorm_bf(const float* __restrict__ in,
                                                    const float* __restrict__ w,
                                                    float* __restrict__ out,
                                                    unsigned short* __restrict__ outbf,
                                                    int* __restrict__ cnt) {
  if (blockIdx.x == 0 && threadIdx.x < 16) cnt[threadIdx.x] = 0;
  int n = blockIdx.x;
  int tid = threadIdx.x;
  const float* row = in + (size_t)n * Cc;
  float v[4];
  float ss = 0.f;
#pragma unroll
  for (int i = 0; i < 4; i++) {
    v[i] = row[tid + i * 256];
    ss += v[i] * v[i];
  }
#pragma unroll
  for (int m = 1; m < 64; m <<= 1) ss += __shfl_xor(ss, m);
  __shared__ float red[4];
  if ((tid & 63) == 0) red[tid >> 6] = ss;
  __syncthreads();
  float tot = red[0] + red[1] + red[2] + red[3];
  float rs = rsqrtf(tot * (1.0f / Cc) + 1e-6f);
  float* orow = out + (size_t)n * Cc;
  unsigned short* obf = outbf + (size_t)n * Cc;
#pragma unroll
  for (int i = 0; i < 4; i++) {
    float r = v[i] * rs * w[tid + i * 256];
    orow[tid + i * 256] = r;
    obf[tid + i * 256] = f2b1(r);
  }
}

// -------- causal depthwise conv1d, fused fp32->bf16 hi/lo split --------
__global__ __launch_bounds__(256) void k_conv_split(const float* __restrict__ h,
                                                    const float* __restrict__ cw,
                                                    unsigned short* __restrict__ oh,
                                                    unsigned short* __restrict__ ol) {
  int i4 = blockIdx.x * 256 + threadIdx.x;
  if (i4 >= Nc * Cc / 4) return;
  int idx = i4 * 4;
  int c = idx & (Cc - 1);
  int n = idx >> 10;
  int t = n & (Tc - 1);
  float4 z = make_float4(0.f, 0.f, 0.f, 0.f);
  float4 d2 = (t >= 2) ? *(const float4*)&h[idx - 2 * Cc] : z;
  float4 d1 = (t >= 1) ? *(const float4*)&h[idx - Cc] : z;
  float4 d0 = *(const float4*)&h[idx];
  float4 r;
  r.x = d2.x * cw[(c + 0) * 3] + d1.x * cw[(c + 0) * 3 + 1] + d0.x * cw[(c + 0) * 3 + 2];
  r.y = d2.y * cw[(c + 1) * 3] + d1.y * cw[(c + 1) * 3 + 1] + d0.y * cw[(c + 1) * 3 + 2];
  r.z = d2.z * cw[(c + 2) * 3] + d1.z * cw[(c + 2) * 3 + 1] + d0.z * cw[(c + 2) * 3 + 2];
  r.w = d2.w * cw[(c + 3) * 3] + d1.w * cw[(c + 3) * 3 + 1] + d0.w * cw[(c + 3) * 3 + 2];
  short4v hi, lo;
  split4(r, hi, lo);
  *(short4v*)&oh[idx] = hi;
  *(short4v*)&ol[idx] = lo;
}

// ---------------- fp32 -> bf16 hi/lo split (weights) ----------------
__global__ __launch_bounds__(256) void k_f2bsp(const float* __restrict__ in,
                                               unsigned short* __restrict__ oh,
                                               unsigned short* __restrict__ ol, int n) {
  int i = (blockIdx.x * 256 + threadIdx.x) * 4;
  if (i >= n) return;
  float4 v = *(const float4*)&in[i];
  short4v hi, lo;
  split4(v, hi, lo);
  *(short4v*)&oh[i] = hi;
  *(short4v*)&ol[i] = lo;
}

// ---------------- fp32 -> bf16 conversion ----------------
__global__ __launch_bounds__(256) void k_f2b(const float* __restrict__ in,
                                             unsigned short* __restrict__ outp, int n) {
  int i = (blockIdx.x * 256 + threadIdx.x) * 4;
  if (i >= n) return;
  float4 v = *(const float4*)&in[i];
  uint2 o;
  o.x = (unsigned int)f2b1(v.x) | ((unsigned int)f2b1(v.y) << 16);
  o.y = (unsigned int)f2b1(v.z) | ((unsigned int)f2b1(v.w) << 16);
  *(uint2*)&outp[i] = o;
}

// ------- bf16x3 MFMA GEMM: C = A.B^T with A,B split hi/lo (m97 structure) ----
// EPI 0: C = acc ; EPI 1: C = resid + acc
template <int EPI>
__global__ __launch_bounds__(256) void k_gemm_x3(const unsigned short* __restrict__ Ah,
                                                 const unsigned short* __restrict__ Al,
                                                 const unsigned short* __restrict__ Bh,
                                                 const unsigned short* __restrict__ Bl,
                                                 float* __restrict__ Cm,
                                                 const float* __restrict__ resid,
                                                 int M, int N, int K) {
  constexpr int BM = 128, BN = 128, BK = 32;
  __shared__ __align__(16) unsigned short lAh[BM * BK];
  __shared__ __align__(16) unsigned short lAl[BM * BK];
  __shared__ __align__(16) unsigned short lBh[BN * BK];
  __shared__ __align__(16) unsigned short lBl[BN * BK];
  int tid = threadIdx.x;
  int lane = tid & 63;
  int wave = tid >> 6;
  int wr = wave >> 1, wc = wave & 1;
  int m0 = blockIdx.y * BM, n0 = blockIdx.x * BN;

  f32x4 acc[4][4];
#pragma unroll
  for (int i = 0; i < 4; i++)
#pragma unroll
    for (int j = 0; j < 4; j++) acc[i][j] = (f32x4)0.f;

  int kf = (lane >> 4) * 8;
  int rl = lane & 15;

  for (int k0 = 0; k0 < K; k0 += BK) {
    __syncthreads();
#pragma unroll
    for (int j = 0; j < 2; j++) {
      int chunk = j * 256 + tid;
      int row = chunk >> 2;
      int cb = (chunk & 3) * 8;
      size_t aoff = (size_t)(m0 + row) * K + k0 + cb;
      size_t boff = (size_t)(n0 + row) * K + k0 + cb;
      __builtin_amdgcn_global_load_lds((const AS1 void*)(Ah + aoff),
                                       (AS3 void*)(&lAh[chunk * 8]), 16, 0, 0);
      __builtin_amdgcn_global_load_lds((const AS1 void*)(Al + aoff),
                                       (AS3 void*)(&lAl[chunk * 8]), 16, 0, 0);
      __builtin_amdgcn_global_load_lds((const AS1 void*)(Bh + boff),
                                       (AS3 void*)(&lBh[chunk * 8]), 16, 0, 0);
      __builtin_amdgcn_global_load_lds((const AS1 void*)(Bl + boff),
                                       (AS3 void*)(&lBl[chunk * 8]), 16, 0, 0);
    }
    asm volatile("s_waitcnt vmcnt(0)" ::: "memory");
    __syncthreads();

    short8v ah[4], al4[4], bh4[4], bl4[4];
#pragma unroll
    for (int i = 0; i < 4; i++) {
      int ro = (wr * 64 + i * 16 + rl) * BK + kf;
      ah[i] = *(const short8v*)&lAh[ro];
      al4[i] = *(const short8v*)&lAl[ro];
    }
#pragma unroll
    for (int j = 0; j < 4; j++) {
      int ro = (wc * 64 + j * 16 + rl) * BK + kf;
      bh4[j] = *(const short8v*)&lBh[ro];
      bl4[j] = *(const short8v*)&lBl[ro];
    }
#pragma unroll
    for (int i = 0; i < 4; i++)
#pragma unroll
      for (int j = 0; j < 4; j++) {
        acc[i][j] = MF32(ah[i], bh4[j], acc[i][j]);
        acc[i][j] = MF32(ah[i], bl4[j], acc[i][j]);
        acc[i][j] = MF32(al4[i], bh4[j], acc[i][j]);
      }
  }

  int cl = lane & 15;
  int rb = (lane >> 4) * 4;
#pragma unroll
  for (int i = 0; i < 4; i++) {
#pragma unroll
    for (int r = 0; r < 4; r++) {
      int m = m0 + wr * 64 + i * 16 + rb + r;
#pragma unroll
      for (int j = 0; j < 4; j++) {
        int n = n0 + wc * 64 + j * 16 + cl;
        size_t off = (size_t)m * N + n;
        if (EPI == 0) Cm[off] = acc[i][j][r];
        else Cm[off] = resid[off] + acc[i][j][r];
      }
    }
  }
}

// ------- grouped MoE up-proj + fused SwiGLU: all experts, one launch --------
__global__ __launch_bounds__(256) void k_moe_wv(const unsigned short* __restrict__ A,
                                                const unsigned short* __restrict__ Wv,
                                                unsigned short* __restrict__ Eh,
                                                const int* __restrict__ idx,
                                                const int* __restrict__ cnt,
                                                const int* __restrict__ meta) {
  constexpr int BK = 32;
  if ((int)blockIdx.y >= meta[16 + 8]) return;
  int e = 0;
#pragma unroll
  for (int i = 1; i < Ec; i++)
    if ((int)blockIdx.y >= meta[16 + i]) e = i;
  int lm = blockIdx.y - meta[16 + e];
  int count = cnt[e];
  int gb = meta[e];
  int m0 = lm * 128;
  int n0 = blockIdx.x * 128;

  __shared__ __align__(16) unsigned short lA[128 * BK];
  __shared__ __align__(16) unsigned short lBg[128 * BK];
  __shared__ __align__(16) unsigned short lBv[128 * BK];
  int tid = threadIdx.x;
  int lane = tid & 63;
  int wave = tid >> 6;
  int wr = wave >> 1, wc = wave & 1;

  const unsigned short* srcA[2];
  const unsigned short* srcG[2];
  const unsigned short* srcV[2];
#pragma unroll
  for (int j = 0; j < 2; j++) {
    int chunk = j * 256 + tid;
    int row = chunk >> 2, cb = (chunk & 3) * 8;
    int mrow = m0 + row;
    int tok = idx[e * Nc + (mrow < count ? mrow : count - 1)];
    srcA[j] = A + (size_t)tok * Cc + cb;
    const unsigned short* wbase = Wv + (size_t)e * 2 * Fc * Cc;
    srcG[j] = wbase + (size_t)(n0 + row) * Cc + cb;
    srcV[j] = wbase + (size_t)(Fc + n0 + row) * Cc + cb;
  }

  f32x4 accG[4][4], accV[4][4];
#pragma unroll
  for (int i = 0; i < 4; i++)
#pragma unroll
    for (int j = 0; j < 4; j++) {
      accG[i][j] = (f32x4)0.f;
      accV[i][j] = (f32x4)0.f;
    }

  int kf = (lane >> 4) * 8;
  int rl = lane & 15;

  for (int k0 = 0; k0 < Cc; k0 += BK) {
    __syncthreads();
#pragma unroll
    for (int j = 0; j < 2; j++) {
      int chunk = j * 256 + tid;
      __builtin_amdgcn_global_load_lds((const AS1 void*)(srcA[j] + k0),
                                       (AS3 void*)(&lA[chunk * 8]), 16, 0, 0);
      __builtin_amdgcn_global_load_lds((const AS1 void*)(srcG[j] + k0),
                                       (AS3 void*)(&lBg[chunk * 8]), 16, 0, 0);
      __builtin_amdgcn_global_load_lds((const AS1 void*)(srcV[j] + k0),
                                       (AS3 void*)(&lBv[chunk * 8]), 16, 0, 0);
    }
    asm volatile("s_waitcnt vmcnt(0)" ::: "memory");
    __syncthreads();

    short8v a[4], bg[4], bv[4];
#pragma unroll
    for (int i = 0; i < 4; i++)
      a[i] = *(const short8v*)&lA[(wr * 64 + i * 16 + rl) * BK + kf];
#pragma unroll
    for (int j = 0; j < 4; j++) {
      bg[j] = *(const short8v*)&lBg[(wc * 64 + j * 16 + rl) * BK + kf];
      bv[j] = *(const short8v*)&lBv[(wc * 64 + j * 16 + rl) * BK + kf];
    }
#pragma unroll
    for (int i = 0; i < 4; i++)
#pragma unroll
      for (int j = 0; j < 4; j++) {
        accG[i][j] = MF32(a[i], bg[j], accG[i][j]);
        accV[i][j] = MF32(a[i], bv[j], accV[i][j]);
      }
  }

  int cl = lane & 15;
  int rb = (lane >> 4) * 4;
#pragma unroll
  for (int i = 0; i < 4; i++) {
#pragma unroll
    for (int r = 0; r < 4; r++) {
      int m = m0 + wr * 64 + i * 16 + rb + r;
      if (m < count) {
        size_t gs = (size_t)(gb + m);
#pragma unroll
        for (int j = 0; j < 4; j++) {
          int n = n0 + wc * 64 + j * 16 + cl;
          float g = accG[i][j][r];
          float v = accV[i][j][r];
          Eh[gs * Fc + n] = f2b1(g / (1.0f + __expf(-g)) * v);
        }
      }
    }
  }
}

// ------- grouped MoE down-proj + weighted scatter: all experts, one launch ---
__global__ __launch_bounds__(256) void k_moe_wo(const unsigned short* __restrict__ Eh,
                                                const unsigned short* __restrict__ Wo,
                                                float* __restrict__ C,
                                                const int* __restrict__ idx,
                                                const float* __restrict__ wt,
                                                const int* __restrict__ cnt,
                                                const int* __restrict__ meta) {
  constexpr int BK = 32;
  if ((int)blockIdx.y >= meta[16 + 8]) return;
  int e = 0;
#pragma unroll
  for (int i = 1; i < Ec; i++)
    if ((int)blockIdx.y >= meta[16 + i]) e = i;
  int lm = blockIdx.y - meta[16 + e];
  int count = cnt[e];
  int gb = meta[e];
  int m0 = lm * 128;
  int n0 = blockIdx.x * 128;

  __shared__ __align__(16) unsigned short lA[128 * BK];
  __shared__ __align__(16) unsigned short lB[128 * BK];
  int tid = threadIdx.x;
  int lane = tid & 63;
  int wave = tid >> 6;
  int wr = wave >> 1, wc = wave & 1;

  f32x4 acc[4][4];
#pragma unroll
  for (int i = 0; i < 4; i++)
#pragma unroll
    for (int j = 0; j < 4; j++) acc[i][j] = (f32x4)0.f;

  int kf = (lane >> 4) * 8;
  int rl = lane & 15;

  for (int k0 = 0; k0 < Fc; k0 += BK) {
    __syncthreads();
#pragma unroll
    for (int j = 0; j < 2; j++) {
      int chunk = j * 256 + tid;
      int row = chunk >> 2;
      int cb = (chunk & 3) * 8;
      __builtin_amdgcn_global_load_lds(
          (const AS1 void*)(Eh + (size_t)(gb + m0 + row) * Fc + k0 + cb),
          (AS3 void*)(&lA[chunk * 8]), 16, 0, 0);
      __builtin_amdgcn_global_load_lds(
          (const AS1 void*)(Wo + (size_t)e * Cc * Fc + (size_t)(n0 + row) * Fc + k0 + cb),
          (AS3 void*)(&lB[chunk * 8]), 16, 0, 0);
    }
    asm volatile("s_waitcnt vmcnt(0)" ::: "memory");
    __syncthreads();

    short8v a[4], b[4];
#pragma unroll
    for (int i = 0; i < 4; i++)
      a[i] = *(const short8v*)&lA[(wr * 64 + i * 16 + rl) * BK + kf];
#pragma unroll
    for (int j = 0; j < 4; j++)
      b[j] = *(const short8v*)&lB[(wc * 64 + j * 16 + rl) * BK + kf];
#pragma unroll
    for (int i = 0; i < 4; i++)
#pragma unroll
      for (int j = 0; j < 4; j++)
        acc[i][j] = MF32(a[i], b[j], acc[i][j]);
  }

  int cl = lane & 15;
  int rb = (lane >> 4) * 4;
#pragma unroll
  for (int i = 0; i < 4; i++) {
#pragma unroll
    for (int r = 0; r < 4; r++) {
      int m = m0 + wr * 64 + i * 16 + rb + r;
      if (m < count) {
        int slot = e * Nc + m;
        int tok = idx[slot];
        float w = wt[slot];
#pragma unroll
        for (int j = 0; j < 4; j++) {
          int n = n0 + wc * 64 + j * 16 + cl;
          atomicAdd(&C[(size_t)tok * Cc + n], w * acc[i][j][r]);
        }
      }
    }
  }
}

// ---------------- RoPE + layernorm ----------------
__device__ __forceinline__ float rope_ln(float q, int lane, int t, float scale) {
  int j = lane & 31;
  float invf = powf(RBASE, -(float)j * (1.0f / 32.0f));
  float ang = (float)t * invf;
  float s, c;
  sincosf(ang, &s, &c);
  float p = __shfl_xor(q, 32);
  float rot = (lane < 32) ? -p : p;
  float qr = q * c + rot * s;
  float sum = qr, sq = qr * qr;
#pragma unroll
  for (int m = 1; m < 64; m <<= 1) {
    sum += __shfl_xor(sum, m);
    sq += __shfl_xor(sq, m);
  }
  float mean = sum * (1.0f / 64.0f);
  float var = sq * (1.0f / 64.0f) - mean * mean;
  return (qr - mean) * rsqrtf(var + 1e-5f) * scale;
}

// Q: bf16 hi/lo in pre-swizzled tile-blocked layout:
//   tile (64 rows x 64 d) at ((b*H+h)*32 + t/64)*4096; short off = row*64 + (d ^ ((row&7)<<3))
__global__ __launch_bounds__(256) void k_ropeln_q(const float* __restrict__ qkv,
                                                  unsigned short* __restrict__ qh,
                                                  unsigned short* __restrict__ ql) {
  int gw = (blockIdx.x * 256 + threadIdx.x) >> 6;
  int lane = threadIdx.x & 63;
  if (gw >= Nc * Hc) return;
  int h = gw & (Hc - 1);
  int n = gw / Hc;
  int t = n & (Tc - 1);
  int b = n / Tc;
  float q = qkv[(size_t)n * QKVD + h * HDc + lane];
  float o = rope_ln(q, lane, t, 0.125f);  // fold 1/sqrt(hd)
  int row = t & 63;
  size_t ob = (((size_t)(b * Hc + h)) * 32 + (t >> 6)) * 4096 + row * 64 +
              (lane ^ ((row & 7) << 3));
  unsigned short hi = f2b1(o);
  qh[ob] = hi;
  ql[ob] = f2b1(o - b2f(hi));
}

// K: same swizzled tile layout as Q. V: TRANSPOSED tile [64 d][64 key], swizzled:
//   short off = d*64 + (key ^ ((d&7)<<3)) — PV A-frags become plain b128 reads.
__global__ __launch_bounds__(256) void k_ropeln_kv(const float* __restrict__ qkv,
                                                   unsigned short* __restrict__ kh,
                                                   unsigned short* __restrict__ kl,
                                                   unsigned short* __restrict__ vh,
                                                   unsigned short* __restrict__ vl) {
  int gw = (blockIdx.x * 256 + threadIdx.x) >> 6;
  int lane = threadIdx.x & 63;
  if (gw >= Nc * KVc) return;
  int kv = gw & (KVc - 1);
  int n = gw / KVc;
  int t = n & (Tc - 1);
  int b = n / Tc;
  size_t base = (size_t)n * QKVD + Cc + kv * HDc;
  float kval = qkv[base + lane];
  float vval = qkv[base + KVc * HDc + lane];
  float o = rope_ln(kval, lane, t, 1.0f);
  int row = t & 63;  // key index within tile
  size_t tb = (((size_t)(b * KVc + kv)) * 32 + (t >> 6)) * 4096;
  size_t ko = tb + row * 64 + (lane ^ ((row & 7) << 3));
  unsigned short khi = f2b1(o);
  kh[ko] = khi;
  kl[ko] = f2b1(o - b2f(khi));
  // vT: d = lane (row of vT), key = row (column)
  size_t vo = tb + (size_t)lane * 64 + (row ^ ((lane & 7) << 3));
  unsigned short vhi = f2b1(vval);
  vh[vo] = vhi;
  vl[vo] = f2b1(vval - b2f(vhi));
}

// ---------------- flash attention, bf16x3 MFMA, swapped-operand S^T ---------
// BQ=64 (4 waves x 16 q), BK=64. Single-buffer 48KB (3 blocks/CU, r8 structure).
// PV now reads pre-transposed, swizzled vT via plain short8v loads (no tr_read).
__global__ __launch_bounds__(256, 3) void k_attn2(const unsigned short* __restrict__ Qh,
                                                  const unsigned short* __restrict__ Ql,
                                                  const unsigned short* __restrict__ Kht,
                                                  const unsigned short* __restrict__ Klt,
                                                  const unsigned short* __restrict__ Vht,
                                                  const unsigned short* __restrict__ Vlt,
                                                  unsigned short* __restrict__ Yh,
                                                  unsigned short* __restrict__ Yl) {
  __shared__ __align__(16) unsigned char smem[49152];
  constexpr unsigned QH = 0, QL = 8192, KH = 16384, KL = 24576, VB = 32768, PB = 0;
  int tid = threadIdx.x;
  int l = tid & 63, w = tid >> 6, g = l >> 4, q15 = l & 15;
  int qtile = gridDim.x - 1 - blockIdx.x;  // longest causal blocks dispatched first
  int hh = blockIdx.y, b = blockIdx.z;
  int kvh = hh >> 2;  // GQA
  size_t qtb = (((size_t)(b * Hc + hh)) * 32 + qtile) * 4096;
  size_t kvb = ((size_t)(b * KVc + kvh)) * 32 * 4096;

  // ---- stage Q (once) via async, pre-swizzled source ----
#pragma unroll
  for (int j = 0; j < 2; j++) {
    int chunk = j * 256 + tid;
    __builtin_amdgcn_global_load_lds((const AS1 void*)(Qh + qtb + chunk * 8),
                                     (AS3 void*)(smem + QH + chunk * 16), 16, 0, 0);
    __builtin_amdgcn_global_load_lds((const AS1 void*)(Ql + qtb + chunk * 8),
                                     (AS3 void*)(smem + QL + chunk * 16), 16, 0, 0);
  }
  asm volatile("s_waitcnt vmcnt(0)" ::: "memory");
  __syncthreads();
  unsigned qsw = (unsigned)((q15 & 7) << 4);
  unsigned qro = (unsigned)((w * 16 + q15) * 128);
  short8v qhf[2], qlf[2];
  qhf[0] = *(const short8v*)(smem + QH + qro + ((16 * g) ^ qsw));
  qhf[1] = *(const short8v*)(smem + QH + qro + ((64 + 16 * g) ^ qsw));
  qlf[0] = *(const short8v*)(smem + QL + qro + ((16 * g) ^ qsw));
  qlf[1] = *(const short8v*)(smem + QL + qro + ((64 + 16 * g) ^ qsw));

  f32x4 o[4];
#pragma unroll
  for (int dt = 0; dt < 4; dt++) o[dt] = (f32x4)0.f;
  float m = -1e30f, lsum = 0.f;
  int qloc = w * 16 + q15;

  for (int kt = 0; kt <= qtile; ++kt) {
    __syncthreads();  // prior-iter LDS reads done before overwrite
    size_t ktb = kvb + (size_t)kt * 4096;
#pragma unroll
    for (int j = 0; j < 2; j++) {
      int chunk = j * 256 + tid;
      __builtin_amdgcn_global_load_lds((const AS1 void*)(Kht + ktb + chunk * 8),
                                       (AS3 void*)(smem + KH + chunk * 16), 16, 0, 0);
      __builtin_amdgcn_global_load_lds((const AS1 void*)(Klt + ktb + chunk * 8),
                                       (AS3 void*)(smem + KL + chunk * 16), 16, 0, 0);
      __builtin_amdgcn_global_load_lds((const AS1 void*)(Vht + ktb + chunk * 8),
                                       (AS3 void*)(smem + VB + chunk * 16), 16, 0, 0);
      __builtin_amdgcn_global_load_lds((const AS1 void*)(Vlt + ktb + chunk * 8),
                                       (AS3 void*)(smem + VB + 8192 + chunk * 16), 16, 0, 0);
    }
    asm volatile("s_waitcnt vmcnt(0)" ::: "memory");
    __syncthreads();
    const bool diag = (kt == qtile);

    // ---- S^T = K·Q^T (3-term bf16 split), per wave: [64 keys][16 q] ----
    f32x4 sv[4];
#pragma unroll
    for (int s = 0; s < 4; ++s) {
      unsigned ro = (unsigned)((s * 16 + q15) * 128);
      short8v kh0 = *(const short8v*)(smem + KH + ro + ((16 * g) ^ qsw));
      short8v kh1 = *(const short8v*)(smem + KH + ro + ((64 + 16 * g) ^ qsw));
      short8v kl0 = *(const short8v*)(smem + KL + ro + ((16 * g) ^ qsw));
      short8v kl1 = *(const short8v*)(smem + KL + ro + ((64 + 16 * g) ^ qsw));
      f32x4 a = (f32x4)0.f;
      a = MF32(kh0, qhf[0], a);
      a = MF32(kh1, qhf[1], a);
      a = MF32(kh0, qlf[0], a);
      a = MF32(kh1, qlf[1], a);
      a = MF32(kl0, qhf[0], a);
      a = MF32(kl1, qhf[1], a);
      sv[s] = a;
    }
    // ---- causal mask + online softmax ----
    float mx = -1e30f;
#pragma unroll
    for (int s = 0; s < 4; ++s)
#pragma unroll
      for (int r = 0; r < 4; ++r) {
        if (diag && (s * 16 + g * 4 + r) > qloc) sv[s][r] = -1e30f;
        mx = fmaxf(mx, sv[s][r]);
      }
    mx = fmaxf(mx, __shfl_xor(mx, 16));
    mx = fmaxf(mx, __shfl_xor(mx, 32));
    float mnew = fmaxf(m, mx);
    float alpha = __expf(m - mnew);
    float p[4][4];
    float ps = 0.f;
#pragma unroll
    for (int s = 0; s < 4; ++s)
#pragma unroll
      for (int r = 0; r < 4; ++r) {
        p[s][r] = __expf(sv[s][r] - mnew);
        ps += p[s][r];
      }
    ps += __shfl_xor(ps, 16);
    ps += __shfl_xor(ps, 32);
    lsum = lsum * alpha + ps;
    m = mnew;
#pragma unroll
    for (int dt = 0; dt < 4; dt++) o[dt] *= alpha;
    // ---- P -> bf16 hi/lo, bounce through per-wave LDS ----
#pragma unroll
    for (int s = 0; s < 4; ++s) {
      unsigned short h0 = f2b1(p[s][0]), h1 = f2b1(p[s][1]), h2 = f2b1(p[s][2]),
                     h3 = f2b1(p[s][3]);
      short4v ph = short4v{(short)h0, (short)h1, (short)h2, (short)h3};
      short4v pl = short4v{(short)f2b1(p[s][0] - b2f(h0)), (short)f2b1(p[s][1] - b2f(h1)),
                           (short)f2b1(p[s][2] - b2f(h2)), (short)f2b1(p[s][3] - b2f(h3))};
      unsigned pb = (unsigned)(PB + w * 4096 + q15 * 128 +
                               (((unsigned)(s * 32 + 8 * g)) ^ qsw));
      *(short4v*)(smem + pb) = ph;
      *(short4v*)(smem + pb + 2048) = pl;
    }
    asm volatile("" ::: "memory");  // order P writes before reads (same wave)
    // ---- O^T += V^T·P^T (3-term), vT A-frags via plain swizzled b128 ----
#pragma unroll
    for (int kk = 0; kk < 2; ++kk) {
      unsigned pq = (unsigned)(PB + w * 4096 + q15 * 128 +
                               (((unsigned)(kk * 64 + 16 * g)) ^ qsw));
      short8v ph8 = *(const short8v*)(smem + pq);
      short8v pl8 = *(const short8v*)(smem + pq + 2048);
      unsigned koff = (unsigned)(kk * 64 + g * 16);  // byte offset of lane's key window
#pragma unroll
      for (int dt = 0; dt < 4; ++dt) {
        unsigned off = VB + (unsigned)((dt * 16 + q15) * 128) + (koff ^ qsw);
        short8v vh8 = *(const short8v*)(smem + off);
        short8v vl8 = *(const short8v*)(smem + off + 8192);
        o[dt] = MF32(vh8, ph8, o[dt]);
        o[dt] = MF32(vh8, pl8, o[dt]);
        o[dt] = MF32(vl8, ph8, o[dt]);
      }
    }
  }
  // ---- epilogue: write y as bf16 hi/lo (feeds bf16x3 proj GEMM) ----
  float inv = 1.0f / lsum;
  size_t ybase = ((size_t)(b * Tc + qtile * 64 + qloc)) * Cc + hh * 64;
#pragma unroll
  for (int dt = 0; dt < 4; dt++) {
    float4 s4 = make_float4(o[dt][0] * inv, o[dt][1] * inv, o[dt][2] * inv, o[dt][3] * inv);
    short4v hi, lo;
    split4(s4, hi, lo);
    *(short4v*)&Yh[ybase + dt * 16 + 4 * g] = hi;
    *(short4v*)&Yl[ybase + dt * 16 + 4 * g] = lo;
  }
}

// ---------------- prefix sums: gbase + tilebase ----------------
__global__ void k_meta(const int* __restrict__ cnt, int* __restrict__ meta) {
  if (threadIdx.x == 0) {
    int gb = 0, tb = 0;
    for (int e = 0; e < Ec; e++) {
      meta[e] = gb;
      meta[16 + e] = tb;
      gb += cnt[e];
      tb += (cnt[e] + 127) >> 7;
    }
    meta[8] = gb;
    meta[16 + 8] = tb;
  }
}

// ---------------- router: softmax -> top2 -> compact assignment lists --------
__global__ __launch_bounds__(256) void k_router(const float* __restrict__ h2,
                                                const float* __restrict__ rw,
                                                float* __restrict__ probs,
                                                int* __restrict__ idx,
                                                float* __restrict__ wt,
                                                int* __restrict__ cnt) {
  int gw = (blockIdx.x * 256 + threadIdx.x) >> 6;
  int lane = threadIdx.x & 63;
  if (gw >= Nc) return;
  const float* row = h2 + (size_t)gw * Cc;
  float acc[Ec] = {};
  for (int k = lane; k < Cc; k += 64) {
    float hv = row[k];
#pragma unroll
    for (int e = 0; e < Ec; e++) acc[e] += hv * rw[e * Cc + k];
  }
#pragma unroll
  for (int e = 0; e < Ec; e++) {
#pragma unroll
    for (int msk = 1; msk < 64; msk <<= 1) acc[e] += __shfl_xor(acc[e], msk);
  }
  if (lane == 0) {
    float mx = acc[0];
#pragma unroll
    for (int e = 1; e < Ec; e++) mx = fmaxf(mx, acc[e]);
    float p[Ec];
    float s = 0.f;
#pragma unroll
    for (int e = 0; e < Ec; e++) {
      p[e] = expf(acc[e] - mx);
      s += p[e];
    }
    float invs = 1.0f / s;
#pragma unroll
    for (int e = 0; e < Ec; e++) {
      p[e] *= invs;
      probs[(size_t)gw * Ec + e] = p[e];
    }
    int i0 = 0;
#pragma unroll
    for (int e = 1; e < Ec; e++)
      if (p[e] > p[i0]) i0 = e;
    int i1 = (i0 == 0) ? 1 : 0;
#pragma unroll
    for (int e = 0; e < Ec; e++)
      if (e != i0 && p[e] > p[i1]) i1 = e;
    float wsum = p[i0] + p[i1];
    int s0 = atomicAdd(&cnt[i0], 1);
    idx[i0 * Nc + s0] = gw;
    wt[i0 * Nc + s0] = p[i0] / wsum;
    int s1 = atomicAdd(&cnt[i1], 1);
    idx[i1 * Nc + s1] = gw;
    wt[i1 * Nc + s1] = p[i1] / wsum;
  }
}

__global__ __launch_bounds__(256) void k_aux(const float* __restrict__ probs,
                                             float* __restrict__ outp) {
  int tid = threadIdx.x;
  int lane = tid & 63, w = tid >> 6;
  float acc[Ec] = {};
  for (int n = tid; n < Nc; n += 256) {
#pragma unroll
    for (int e = 0; e < Ec; e++) acc[e] += probs[(size_t)n * Ec + e];
  }
#pragma unroll
  for (int e = 0; e < Ec; e++) {
#pragma unroll
    for (int msk = 1; msk < 64; msk <<= 1) acc[e] += __shfl_xor(acc[e], msk);
  }
  __shared__ float red[4][Ec];
  if (lane == 0) {
#pragma unroll
    for (int e = 0; e < Ec; e++) red[w][e] = acc[e];
  }
  __syncthreads();
  if (tid == 0) {
    float aux = 0.f;
#pragma unroll
    for (int e = 0; e < Ec; e++) {
      float tot = red[0][e] + red[1][e] + red[2][e] + red[3][e];
      float avg = tot * (1.0f / Nc);
      aux += avg * avg;
    }
    outp[0] = (float)Ec * aux;
  }
}

extern "C" void kernel_launch(void* const* d_in, const int* in_sizes, int n_in,
                              void* d_out, int out_size, void* d_ws, size_t ws_size,
                              hipStream_t stream) {
  const float* x      = (const float*)d_in[0];
  const float* ln1_w  = (const float*)d_in[1];
  const float* ln2_w  = (const float*)d_in[2];
  const float* conv_w = (const float*)d_in[3];
  const float* attn_w = (const float*)d_in[4];
  const float* proj_w = (const float*)d_in[5];
  const float* rout_w = (const float*)d_in[6];
  const float* ewv    = (const float*)d_in[7];
  const float* ewo    = (const float*)d_in[8];
  float* out = (float*)d_out;
  float* ws = (float*)d_ws;

  float* h    = ws + OFF_H;
  float* qkv  = ws + OFF_QKV;
  float* h2   = ws + OFF_H2;
  float* prob = ws + OFF_PROB;
  int*   idxp = (int*)(ws + OFF_IDX);
  float* wtp  = ws + OFF_WT;
  int*   cntp = (int*)(ws + OFF_CNT);
  int*   metap = (int*)(ws + OFF_META);
  unsigned short* wqh = (unsigned short*)(ws + OFF_WQH);
  unsigned short* wql = (unsigned short*)(ws + OFF_WQL);
  unsigned short* wph = (unsigned short*)(ws + OFF_WPH);
  unsigned short* wpl = (unsigned short*)(ws + OFF_WPL);
  unsigned short* hch = (unsigned short*)(ws + OFF_HCH);
  unsigned short* hcl = (unsigned short*)(ws + OFF_HCL);
  unsigned short* qhb = (unsigned short*)(ws + OFF_QHB);
  unsigned short* qlb = (unsigned short*)(ws + OFF_QLB);
  unsigned short* khb = (unsigned short*)(ws + OFF_KHB);
  unsigned short* klb = (unsigned short*)(ws + OFF_KLB);
  unsigned short* vhb = (unsigned short*)(ws + OFF_VHB);
  unsigned short* vlb = (unsigned short*)(ws + OFF_VLB);
  unsigned short* yh  = (unsigned short*)(ws + OFF_YH);
  unsigned short* yl  = (unsigned short*)(ws + OFF_YL);
  unsigned short* h2bf = (unsigned short*)(ws + OFF_H2BF);
  unsigned short* ehbf = (unsigned short*)(ws + OFF_EHBF);
  unsigned short* wvbf = (unsigned short*)(ws + OFF_WVBF);
  unsigned short* wobf = (unsigned short*)(ws + OFF_WOBF);

  // attention branch
  k_rmsnorm<<<Nc, 256, 0, stream>>>(x, ln1_w, h);
  k_conv_split<<<(Nc * Cc / 4) / 256, 256, 0, stream>>>(h, conv_w, hch, hcl);
  k_f2bsp<<<(QKVD * Cc / 4) / 256, 256, 0, stream>>>(attn_w, wqh, wql, QKVD * Cc);
  k_f2bsp<<<(Cc * Cc / 4) / 256, 256, 0, stream>>>(proj_w, wph, wpl, Cc * Cc);
  {
    dim3 g(QKVD / 128, Nc / 128);
    k_gemm_x3<0><<<g, 256, 0, stream>>>(hch, hcl, wqh, wql, qkv, nullptr, Nc, QKVD, Cc);
  }
  k_ropeln_q<<<(Nc * Hc * 64) / 256, 256, 0, stream>>>(qkv, qhb, qlb);
  k_ropeln_kv<<<(Nc * KVc * 64) / 256, 256, 0, stream>>>(qkv, khb, klb, vhb, vlb);
  k_attn2<<<dim3(Tc / 64, Hc, Bc), 256, 0, stream>>>(qhb, qlb, khb, klb, vhb, vlb, yh, yl);
  {
    dim3 g(Cc / 128, Nc / 128);
    k_gemm_x3<1><<<g, 256, 0, stream>>>(yh, yl, wph, wpl, out, x, Nc, Cc, Cc);
  }
  // MoE branch: router -> grouped single-launch expert GEMMs (fused silu)
  k_rmsnorm_bf<<<Nc, 256, 0, stream>>>(out, ln2_w, h2, h2bf, cntp);
  k_router<<<Nc / 4, 256, 0, stream>>>(h2, rout_w, prob, idxp, wtp, cntp);
  k_meta<<<1, 64, 0, stream>>>(cntp, metap);
  k_aux<<<1, 256, 0, stream>>>(prob, out + (size_t)Nc * Cc);
  k_f2b<<<(Ec * 2 * Fc * Cc / 4) / 256, 256, 0, stream>>>(ewv, wvbf, Ec * 2 * Fc * Cc);
  k_f2b<<<(Ec * Cc * Fc / 4) / 256, 256, 0, stream>>>(ewo, wobf, Ec * Cc * Fc);
  k_moe_wv<<<dim3(Fc / 128, MAXTILES), 256, 0, stream>>>(h2bf, wvbf, ehbf, idxp, cntp, metap);
  k_moe_wo<<<dim3(Cc / 128, MAXTILES), 256, 0, stream>>>(ehbf, wobf, out, idxp, wtp, cntp,
                                                         metap);
}

// Round 11
// 538.086 us; speedup vs baseline: 1.1209x; 1.0983x over previous
//
#include <hip/hip_runtime.h>
#include <math.h>

namespace {
constexpr int Bc = 2, Tc = 2048, Cc = 1024, Hc = 16, KVc = 4, HDc = 64, Ec = 8, Fc = 1024;
constexpr int Nc = Bc * Tc;               // 4096 tokens
constexpr int QKVD = Cc + 2 * KVc * HDc;  // 1536
constexpr int GRP = Hc / KVc;             // 4
constexpr float RBASE = 50000.0f;
constexpr int MAXTILES = 72;              // worst-case sum of ceil(cnt[e]/128)

// workspace layout (floats) — peak ≤ 24M floats = 96 MB (proven footprint)
// ---- attention phase ----
constexpr size_t OFF_WQH = 0;                        // 0.75M (attn_w hi, bf16)
constexpr size_t OFF_WQL = 768u * 1024;              // 0.75M
constexpr size_t OFF_WPH = 1536u * 1024;             // 0.5M  (proj_w hi)
constexpr size_t OFF_WPL = 2048u * 1024;             // 0.5M
constexpr size_t OFF_H   = 2560u * 1024;             // 4M    (rmsnorm out; dead after conv)
constexpr size_t OFF_HCH = 6656u * 1024;             // 2M    (conv out hi, bf16)
constexpr size_t OFF_HCL = 8704u * 1024;             // 2M
constexpr size_t OFF_QKV = 10752u * 1024;            // 6M fp32
constexpr size_t OFF_QHB = 16896u * 1024;            // 2M floats = 4M bf16 (q hi, tiled)
constexpr size_t OFF_QLB = 18944u * 1024;            // 2M floats (q lo)
constexpr size_t OFF_KHB = 20992u * 1024;            // 0.5M floats (k hi, tiled swz)
constexpr size_t OFF_KLB = 21504u * 1024;            // 0.5M
constexpr size_t OFF_VHB = 22016u * 1024;            // 0.5M (vT hi, tiled swz)
constexpr size_t OFF_VLB = 22528u * 1024;            // 0.5M
constexpr size_t OFF_YH  = 2560u * 1024;             // 2M (attn out hi; over dead h)
constexpr size_t OFF_YL  = 4608u * 1024;             // 2M
// ---- MoE phase (attention buffers dead) ----
constexpr size_t OFF_H2   = 0;                       // 4M (h2 fp32)
constexpr size_t OFF_H2BF = 4u * 1024 * 1024;        // 2M floats = 4M bf16
constexpr size_t OFF_EHBF = 6u * 1024 * 1024;        // 4M floats = 8192 x 1024 bf16
constexpr size_t OFF_WVBF = 10u * 1024 * 1024;       // 8.4M floats
constexpr size_t OFF_WOBF = 18u * 1024 * 1024 + 512u * 1024;  // 4.2M floats
constexpr size_t OFF_PROB = 23u * 1024 * 1024;       // 32k floats
constexpr size_t OFF_IDX  = OFF_PROB + 32768;        // 32k ints (E x Nc)
constexpr size_t OFF_WT   = OFF_IDX + 32768;         // 32k floats
constexpr size_t OFF_CNT  = OFF_WT + 32768;          // 64 ints
constexpr size_t OFF_META = OFF_CNT + 64;            // 32 ints
}

typedef __attribute__((ext_vector_type(8))) short short8v;   // 8 bf16 (4 VGPRs)
typedef __attribute__((ext_vector_type(4))) short short4v;   // 4 bf16 (2 VGPRs)
typedef __attribute__((ext_vector_type(4))) float f32x4;

#define MF32(a, b, c) __builtin_amdgcn_mfma_f32_16x16x32_bf16((a), (b), (c), 0, 0, 0)
#define AS1 __attribute__((address_space(1)))
#define AS3 __attribute__((address_space(3)))

__device__ __forceinline__ unsigned short f2b1(float f) {
  union { float f; unsigned int u; } x;
  x.f = f;
  unsigned int r = (x.u + 0x7FFFu + ((x.u >> 16) & 1u)) >> 16;
  return (unsigned short)r;
}

__device__ __forceinline__ float b2f(unsigned short h) {
  union { unsigned int u; float f; } x;
  x.u = (unsigned int)h << 16;
  return x.f;
}

// split fp32 -> bf16 hi + bf16 lo (x ~= hi + lo, |err| ~ 2^-18 |x|)
__device__ __forceinline__ void split4(float4 v, short4v& hi, short4v& lo) {
  unsigned short h0 = f2b1(v.x), h1 = f2b1(v.y), h2 = f2b1(v.z), h3 = f2b1(v.w);
  hi = short4v{(short)h0, (short)h1, (short)h2, (short)h3};
  lo = short4v{(short)f2b1(v.x - b2f(h0)), (short)f2b1(v.y - b2f(h1)),
               (short)f2b1(v.z - b2f(h2)), (short)f2b1(v.w - b2f(h3))};
}

// ---------------- rmsnorm ----------------
__global__ __launch_bounds__(256) void k_rmsnorm(const float* __restrict__ in,
                                                 const float* __restrict__ w,
                                                 float* __restrict__ out) {
  int n = blockIdx.x;
  int tid = threadIdx.x;
  const float* row = in + (size_t)n * Cc;
  float v[4];
  float ss = 0.f;
#pragma unroll
  for (int i = 0; i < 4; i++) {
    v[i] = row[tid + i * 256];
    ss += v[i] * v[i];
  }
#pragma unroll
  for (int m = 1; m < 64; m <<= 1) ss += __shfl_xor(ss, m);
  __shared__ float red[4];
  if ((tid & 63) == 0) red[tid >> 6] = ss;
  __syncthreads();
  float tot = red[0] + red[1] + red[2] + red[3];
  float rs = rsqrtf(tot * (1.0f / Cc) + 1e-6f);
  float* orow = out + (size_t)n * Cc;
#pragma unroll
  for (int i = 0; i < 4; i++) orow[tid + i * 256] = v[i] * rs * w[tid + i * 256];
}

// ----- rmsnorm + bf16 copy + expert-counter zeroing (MoE-side, fused) -----
__global__ __launch_bounds__(256) void k_rmsnorm_bf(const float* __restrict__ in,
                                                    const float* __restrict__ w,
                                                    float* __restrict__ out,
                                                    unsigned short* __restrict__ outbf,
                                                    int* __restrict__ cnt) {
  if (blockIdx.x == 0 && threadIdx.x < 16) cnt[threadIdx.x] = 0;
  int n = blockIdx.x;
  int tid = threadIdx.x;
  const float* row = in + (size_t)n * Cc;
  float v[4];
  float ss = 0.f;
#pragma unroll
  for (int i = 0; i < 4; i++) {
    v[i] = row[tid + i * 256];
    ss += v[i] * v[i];
  }
#pragma unroll
  for (int m = 1; m < 64; m <<= 1) ss += __shfl_xor(ss, m);
  __shared__ float red[4];
  if ((tid & 63) == 0) red[tid >> 6] = ss;
  __syncthreads();
  float tot = red[0] + red[1] + red[2] + red[3];
  float rs = rsqrtf(tot * (1.0f / Cc) + 1e-6f);
  float* orow = out + (size_t)n * Cc;
  unsigned short* obf = outbf + (size_t)n * Cc;
#pragma unroll
  for (int i = 0; i < 4; i++) {
    float r = v[i] * rs * w[tid + i * 256];
    orow[tid + i * 256] = r;
    obf[tid + i * 256] = f2b1(r);
  }
}

// -------- causal depthwise conv1d, fused fp32->bf16 hi/lo split --------
__global__ __launch_bounds__(256) void k_conv_split(const float* __restrict__ h,
                                                    const float* __restrict__ cw,
                                                    unsigned short* __restrict__ oh,
                                                    unsigned short* __restrict__ ol) {
  int i4 = blockIdx.x * 256 + threadIdx.x;
  if (i4 >= Nc * Cc / 4) return;
  int idx = i4 * 4;
  int c = idx & (Cc - 1);
  int n = idx >> 10;
  int t = n & (Tc - 1);
  float4 z = make_float4(0.f, 0.f, 0.f, 0.f);
  float4 d2 = (t >= 2) ? *(const float4*)&h[idx - 2 * Cc] : z;
  float4 d1 = (t >= 1) ? *(const float4*)&h[idx - Cc] : z;
  float4 d0 = *(const float4*)&h[idx];
  float4 r;
  r.x = d2.x * cw[(c + 0) * 3] + d1.x * cw[(c + 0) * 3 + 1] + d0.x * cw[(c + 0) * 3 + 2];
  r.y = d2.y * cw[(c + 1) * 3] + d1.y * cw[(c + 1) * 3 + 1] + d0.y * cw[(c + 1) * 3 + 2];
  r.z = d2.z * cw[(c + 2) * 3] + d1.z * cw[(c + 2) * 3 + 1] + d0.z * cw[(c + 2) * 3 + 2];
  r.w = d2.w * cw[(c + 3) * 3] + d1.w * cw[(c + 3) * 3 + 1] + d0.w * cw[(c + 3) * 3 + 2];
  short4v hi, lo;
  split4(r, hi, lo);
  *(short4v*)&oh[idx] = hi;
  *(short4v*)&ol[idx] = lo;
}

// ---------------- fp32 -> bf16 hi/lo split (weights) ----------------
__global__ __launch_bounds__(256) void k_f2bsp(const float* __restrict__ in,
                                               unsigned short* __restrict__ oh,
                                               unsigned short* __restrict__ ol, int n) {
  int i = (blockIdx.x * 256 + threadIdx.x) * 4;
  if (i >= n) return;
  float4 v = *(const float4*)&in[i];
  short4v hi, lo;
  split4(v, hi, lo);
  *(short4v*)&oh[i] = hi;
  *(short4v*)&ol[i] = lo;
}

// ---------------- fp32 -> bf16 conversion ----------------
__global__ __launch_bounds__(256) void k_f2b(const float* __restrict__ in,
                                             unsigned short* __restrict__ outp, int n) {
  int i = (blockIdx.x * 256 + threadIdx.x) * 4;
  if (i >= n) return;
  float4 v = *(const float4*)&in[i];
  uint2 o;
  o.x = (unsigned int)f2b1(v.x) | ((unsigned int)f2b1(v.y) << 16);
  o.y = (unsigned int)f2b1(v.z) | ((unsigned int)f2b1(v.w) << 16);
  *(uint2*)&outp[i] = o;
}

// ------- bf16x3 MFMA GEMM: C = A.B^T with A,B split hi/lo (m97 structure) ----
// EPI 0: C = acc ; EPI 1: C = resid + acc
template <int EPI>
__global__ __launch_bounds__(256) void k_gemm_x3(const unsigned short* __restrict__ Ah,
                                                 const unsigned short* __restrict__ Al,
                                                 const unsigned short* __restrict__ Bh,
                                                 const unsigned short* __restrict__ Bl,
                                                 float* __restrict__ Cm,
                                                 const float* __restrict__ resid,
                                                 int M, int N, int K) {
  constexpr int BM = 128, BN = 128, BK = 32;
  __shared__ __align__(16) unsigned short lAh[BM * BK];
  __shared__ __align__(16) unsigned short lAl[BM * BK];
  __shared__ __align__(16) unsigned short lBh[BN * BK];
  __shared__ __align__(16) unsigned short lBl[BN * BK];
  int tid = threadIdx.x;
  int lane = tid & 63;
  int wave = tid >> 6;
  int wr = wave >> 1, wc = wave & 1;
  int m0 = blockIdx.y * BM, n0 = blockIdx.x * BN;

  f32x4 acc[4][4];
#pragma unroll
  for (int i = 0; i < 4; i++)
#pragma unroll
    for (int j = 0; j < 4; j++) acc[i][j] = (f32x4)0.f;

  int kf = (lane >> 4) * 8;
  int rl = lane & 15;

  for (int k0 = 0; k0 < K; k0 += BK) {
    __syncthreads();
#pragma unroll
    for (int j = 0; j < 2; j++) {
      int chunk = j * 256 + tid;
      int row = chunk >> 2;
      int cb = (chunk & 3) * 8;
      size_t aoff = (size_t)(m0 + row) * K + k0 + cb;
      size_t boff = (size_t)(n0 + row) * K + k0 + cb;
      __builtin_amdgcn_global_load_lds((const AS1 void*)(Ah + aoff),
                                       (AS3 void*)(&lAh[chunk * 8]), 16, 0, 0);
      __builtin_amdgcn_global_load_lds((const AS1 void*)(Al + aoff),
                                       (AS3 void*)(&lAl[chunk * 8]), 16, 0, 0);
      __builtin_amdgcn_global_load_lds((const AS1 void*)(Bh + boff),
                                       (AS3 void*)(&lBh[chunk * 8]), 16, 0, 0);
      __builtin_amdgcn_global_load_lds((const AS1 void*)(Bl + boff),
                                       (AS3 void*)(&lBl[chunk * 8]), 16, 0, 0);
    }
    asm volatile("s_waitcnt vmcnt(0)" ::: "memory");
    __syncthreads();

    short8v ah[4], al4[4], bh4[4], bl4[4];
#pragma unroll
    for (int i = 0; i < 4; i++) {
      int ro = (wr * 64 + i * 16 + rl) * BK + kf;
      ah[i] = *(const short8v*)&lAh[ro];
      al4[i] = *(const short8v*)&lAl[ro];
    }
#pragma unroll
    for (int j = 0; j < 4; j++) {
      int ro = (wc * 64 + j * 16 + rl) * BK + kf;
      bh4[j] = *(const short8v*)&lBh[ro];
      bl4[j] = *(const short8v*)&lBl[ro];
    }
#pragma unroll
    for (int i = 0; i < 4; i++)
#pragma unroll
      for (int j = 0; j < 4; j++) {
        acc[i][j] = MF32(ah[i], bh4[j], acc[i][j]);
        acc[i][j] = MF32(ah[i], bl4[j], acc[i][j]);
        acc[i][j] = MF32(al4[i], bh4[j], acc[i][j]);
      }
  }

  int cl = lane & 15;
  int rb = (lane >> 4) * 4;
#pragma unroll
  for (int i = 0; i < 4; i++) {
#pragma unroll
    for (int r = 0; r < 4; r++) {
      int m = m0 + wr * 64 + i * 16 + rb + r;
#pragma unroll
      for (int j = 0; j < 4; j++) {
        int n = n0 + wc * 64 + j * 16 + cl;
        size_t off = (size_t)m * N + n;
        if (EPI == 0) Cm[off] = acc[i][j][r];
        else Cm[off] = resid[off] + acc[i][j][r];
      }
    }
  }
}

// ------- grouped MoE up-proj + fused SwiGLU: all experts, one launch --------
__global__ __launch_bounds__(256) void k_moe_wv(const unsigned short* __restrict__ A,
                                                const unsigned short* __restrict__ Wv,
                                                unsigned short* __restrict__ Eh,
                                                const int* __restrict__ idx,
                                                const int* __restrict__ cnt,
                                                const int* __restrict__ meta) {
  constexpr int BK = 32;
  if ((int)blockIdx.y >= meta[16 + 8]) return;
  int e = 0;
#pragma unroll
  for (int i = 1; i < Ec; i++)
    if ((int)blockIdx.y >= meta[16 + i]) e = i;
  int lm = blockIdx.y - meta[16 + e];
  int count = cnt[e];
  int gb = meta[e];
  int m0 = lm * 128;
  int n0 = blockIdx.x * 128;

  __shared__ __align__(16) unsigned short lA[128 * BK];
  __shared__ __align__(16) unsigned short lBg[128 * BK];
  __shared__ __align__(16) unsigned short lBv[128 * BK];
  int tid = threadIdx.x;
  int lane = tid & 63;
  int wave = tid >> 6;
  int wr = wave >> 1, wc = wave & 1;

  const unsigned short* srcA[2];
  const unsigned short* srcG[2];
  const unsigned short* srcV[2];
#pragma unroll
  for (int j = 0; j < 2; j++) {
    int chunk = j * 256 + tid;
    int row = chunk >> 2, cb = (chunk & 3) * 8;
    int mrow = m0 + row;
    int tok = idx[e * Nc + (mrow < count ? mrow : count - 1)];
    srcA[j] = A + (size_t)tok * Cc + cb;
    const unsigned short* wbase = Wv + (size_t)e * 2 * Fc * Cc;
    srcG[j] = wbase + (size_t)(n0 + row) * Cc + cb;
    srcV[j] = wbase + (size_t)(Fc + n0 + row) * Cc + cb;
  }

  f32x4 accG[4][4], accV[4][4];
#pragma unroll
  for (int i = 0; i < 4; i++)
#pragma unroll
    for (int j = 0; j < 4; j++) {
      accG[i][j] = (f32x4)0.f;
      accV[i][j] = (f32x4)0.f;
    }

  int kf = (lane >> 4) * 8;
  int rl = lane & 15;

  for (int k0 = 0; k0 < Cc; k0 += BK) {
    __syncthreads();
#pragma unroll
    for (int j = 0; j < 2; j++) {
      int chunk = j * 256 + tid;
      __builtin_amdgcn_global_load_lds((const AS1 void*)(srcA[j] + k0),
                                       (AS3 void*)(&lA[chunk * 8]), 16, 0, 0);
      __builtin_amdgcn_global_load_lds((const AS1 void*)(srcG[j] + k0),
                                       (AS3 void*)(&lBg[chunk * 8]), 16, 0, 0);
      __builtin_amdgcn_global_load_lds((const AS1 void*)(srcV[j] + k0),
                                       (AS3 void*)(&lBv[chunk * 8]), 16, 0, 0);
    }
    asm volatile("s_waitcnt vmcnt(0)" ::: "memory");
    __syncthreads();

    short8v a[4], bg[4], bv[4];
#pragma unroll
    for (int i = 0; i < 4; i++)
      a[i] = *(const short8v*)&lA[(wr * 64 + i * 16 + rl) * BK + kf];
#pragma unroll
    for (int j = 0; j < 4; j++) {
      bg[j] = *(const short8v*)&lBg[(wc * 64 + j * 16 + rl) * BK + kf];
      bv[j] = *(const short8v*)&lBv[(wc * 64 + j * 16 + rl) * BK + kf];
    }
#pragma unroll
    for (int i = 0; i < 4; i++)
#pragma unroll
      for (int j = 0; j < 4; j++) {
        accG[i][j] = MF32(a[i], bg[j], accG[i][j]);
        accV[i][j] = MF32(a[i], bv[j], accV[i][j]);
      }
  }

  int cl = lane & 15;
  int rb = (lane >> 4) * 4;
#pragma unroll
  for (int i = 0; i < 4; i++) {
#pragma unroll
    for (int r = 0; r < 4; r++) {
      int m = m0 + wr * 64 + i * 16 + rb + r;
      if (m < count) {
        size_t gs = (size_t)(gb + m);
#pragma unroll
        for (int j = 0; j < 4; j++) {
          int n = n0 + wc * 64 + j * 16 + cl;
          float g = accG[i][j][r];
          float v = accV[i][j][r];
          Eh[gs * Fc + n] = f2b1(g / (1.0f + __expf(-g)) * v);
        }
      }
    }
  }
}

// ------- grouped MoE down-proj + weighted scatter: all experts, one launch ---
__global__ __launch_bounds__(256) void k_moe_wo(const unsigned short* __restrict__ Eh,
                                                const unsigned short* __restrict__ Wo,
                                                float* __restrict__ C,
                                                const int* __restrict__ idx,
                                                const float* __restrict__ wt,
                                                const int* __restrict__ cnt,
                                                const int* __restrict__ meta) {
  constexpr int BK = 32;
  if ((int)blockIdx.y >= meta[16 + 8]) return;
  int e = 0;
#pragma unroll
  for (int i = 1; i < Ec; i++)
    if ((int)blockIdx.y >= meta[16 + i]) e = i;
  int lm = blockIdx.y - meta[16 + e];
  int count = cnt[e];
  int gb = meta[e];
  int m0 = lm * 128;
  int n0 = blockIdx.x * 128;

  __shared__ __align__(16) unsigned short lA[128 * BK];
  __shared__ __align__(16) unsigned short lB[128 * BK];
  int tid = threadIdx.x;
  int lane = tid & 63;
  int wave = tid >> 6;
  int wr = wave >> 1, wc = wave & 1;

  f32x4 acc[4][4];
#pragma unroll
  for (int i = 0; i < 4; i++)
#pragma unroll
    for (int j = 0; j < 4; j++) acc[i][j] = (f32x4)0.f;

  int kf = (lane >> 4) * 8;
  int rl = lane & 15;

  for (int k0 = 0; k0 < Fc; k0 += BK) {
    __syncthreads();
#pragma unroll
    for (int j = 0; j < 2; j++) {
      int chunk = j * 256 + tid;
      int row = chunk >> 2;
      int cb = (chunk & 3) * 8;
      __builtin_amdgcn_global_load_lds(
          (const AS1 void*)(Eh + (size_t)(gb + m0 + row) * Fc + k0 + cb),
          (AS3 void*)(&lA[chunk * 8]), 16, 0, 0);
      __builtin_amdgcn_global_load_lds(
          (const AS1 void*)(Wo + (size_t)e * Cc * Fc + (size_t)(n0 + row) * Fc + k0 + cb),
          (AS3 void*)(&lB[chunk * 8]), 16, 0, 0);
    }
    asm volatile("s_waitcnt vmcnt(0)" ::: "memory");
    __syncthreads();

    short8v a[4], b[4];
#pragma unroll
    for (int i = 0; i < 4; i++)
      a[i] = *(const short8v*)&lA[(wr * 64 + i * 16 + rl) * BK + kf];
#pragma unroll
    for (int j = 0; j < 4; j++)
      b[j] = *(const short8v*)&lB[(wc * 64 + j * 16 + rl) * BK + kf];
#pragma unroll
    for (int i = 0; i < 4; i++)
#pragma unroll
      for (int j = 0; j < 4; j++)
        acc[i][j] = MF32(a[i], b[j], acc[i][j]);
  }

  int cl = lane & 15;
  int rb = (lane >> 4) * 4;
#pragma unroll
  for (int i = 0; i < 4; i++) {
#pragma unroll
    for (int r = 0; r < 4; r++) {
      int m = m0 + wr * 64 + i * 16 + rb + r;
      if (m < count) {
        int slot = e * Nc + m;
        int tok = idx[slot];
        float w = wt[slot];
#pragma unroll
        for (int j = 0; j < 4; j++) {
          int n = n0 + wc * 64 + j * 16 + cl;
          atomicAdd(&C[(size_t)tok * Cc + n], w * acc[i][j][r]);
        }
      }
    }
  }
}

// ---------------- RoPE + layernorm ----------------
__device__ __forceinline__ float rope_ln(float q, int lane, int t, float scale) {
  int j = lane & 31;
  float invf = powf(RBASE, -(float)j * (1.0f / 32.0f));
  float ang = (float)t * invf;
  float s, c;
  sincosf(ang, &s, &c);
  float p = __shfl_xor(q, 32);
  float rot = (lane < 32) ? -p : p;
  float qr = q * c + rot * s;
  float sum = qr, sq = qr * qr;
#pragma unroll
  for (int m = 1; m < 64; m <<= 1) {
    sum += __shfl_xor(sum, m);
    sq += __shfl_xor(sq, m);
  }
  float mean = sum * (1.0f / 64.0f);
  float var = sq * (1.0f / 64.0f) - mean * mean;
  return (qr - mean) * rsqrtf(var + 1e-5f) * scale;
}

// Q: bf16 hi/lo in pre-swizzled tile-blocked layout:
//   tile (64 rows x 64 d) at ((b*H+h)*32 + t/64)*4096; short off = row*64 + (d ^ ((row&7)<<3))
__global__ __launch_bounds__(256) void k_ropeln_q(const float* __restrict__ qkv,
                                                  unsigned short* __restrict__ qh,
                                                  unsigned short* __restrict__ ql) {
  int gw = (blockIdx.x * 256 + threadIdx.x) >> 6;
  int lane = threadIdx.x & 63;
  if (gw >= Nc * Hc) return;
  int h = gw & (Hc - 1);
  int n = gw / Hc;
  int t = n & (Tc - 1);
  int b = n / Tc;
  float q = qkv[(size_t)n * QKVD + h * HDc + lane];
  float o = rope_ln(q, lane, t, 0.125f);  // fold 1/sqrt(hd)
  int row = t & 63;
  size_t ob = (((size_t)(b * Hc + h)) * 32 + (t >> 6)) * 4096 + row * 64 +
              (lane ^ ((row & 7) << 3));
  unsigned short hi = f2b1(o);
  qh[ob] = hi;
  ql[ob] = f2b1(o - b2f(hi));
}

// K: same swizzled tile layout as Q. V: TRANSPOSED tile [64 d][64 key], swizzled:
//   short off = d*64 + (key ^ ((d&7)<<3)) — PV A-frags become plain b128 reads.
__global__ __launch_bounds__(256) void k_ropeln_kv(const float* __restrict__ qkv,
                                                   unsigned short* __restrict__ kh,
                                                   unsigned short* __restrict__ kl,
                                                   unsigned short* __restrict__ vh,
                                                   unsigned short* __restrict__ vl) {
  int gw = (blockIdx.x * 256 + threadIdx.x) >> 6;
  int lane = threadIdx.x & 63;
  if (gw >= Nc * KVc) return;
  int kv = gw & (KVc - 1);
  int n = gw / KVc;
  int t = n & (Tc - 1);
  int b = n / Tc;
  size_t base = (size_t)n * QKVD + Cc + kv * HDc;
  float kval = qkv[base + lane];
  float vval = qkv[base + KVc * HDc + lane];
  float o = rope_ln(kval, lane, t, 1.0f);
  int row = t & 63;  // key index within tile
  size_t tb = (((size_t)(b * KVc + kv)) * 32 + (t >> 6)) * 4096;
  size_t ko = tb + row * 64 + (lane ^ ((row & 7) << 3));
  unsigned short khi = f2b1(o);
  kh[ko] = khi;
  kl[ko] = f2b1(o - b2f(khi));
  // vT: d = lane (row of vT), key = row (column)
  size_t vo = tb + (size_t)lane * 64 + (row ^ ((lane & 7) << 3));
  unsigned short vhi = f2b1(vval);
  vh[vo] = vhi;
  vl[vo] = f2b1(vval - b2f(vhi));
}

// ---------------- flash attention, bf16x3 MFMA, swapped-operand S^T ---------
// BQ=64 (4 waves x 16 q), BK=64. Single-buffer 48KB (3 blocks/CU).
// CAUSAL WORK PAIRING: each block handles qtiles {63-bx, bx} -> uniform 65
// tile-units per block, fixing the 64:1 load imbalance (Occupancy 13.8%).
__global__ __launch_bounds__(256, 3) void k_attn2(const unsigned short* __restrict__ Qh,
                                                  const unsigned short* __restrict__ Ql,
                                                  const unsigned short* __restrict__ Kht,
                                                  const unsigned short* __restrict__ Klt,
                                                  const unsigned short* __restrict__ Vht,
                                                  const unsigned short* __restrict__ Vlt,
                                                  unsigned short* __restrict__ Yh,
                                                  unsigned short* __restrict__ Yl) {
  __shared__ __align__(16) unsigned char smem[49152];
  constexpr unsigned QH = 0, QL = 8192, KH = 16384, KL = 24576, VB = 32768, PB = 0;
  int tid = threadIdx.x;
  int l = tid & 63, w = tid >> 6, g = l >> 4, q15 = l & 15;
  int bx = blockIdx.x;  // 0..31
  int hh = blockIdx.y, b = blockIdx.z;
  int kvh = hh >> 2;  // GQA
  size_t kvb = ((size_t)(b * KVc + kvh)) * 32 * 4096;
  unsigned qsw = (unsigned)((q15 & 7) << 4);
  unsigned qro = (unsigned)((w * 16 + q15) * 128);
  int qloc = w * 16 + q15;

  for (int which = 0; which < 2; ++which) {
    int qtile = which == 0 ? (Tc / 64 - 1 - bx) : bx;  // long half first
    size_t qtb = (((size_t)(b * Hc + hh)) * 32 + qtile) * 4096;
    __syncthreads();  // prior pass done with P/Q LDS region
    // ---- stage Q via async, pre-swizzled source ----
#pragma unroll
    for (int j = 0; j < 2; j++) {
      int chunk = j * 256 + tid;
      __builtin_amdgcn_global_load_lds((const AS1 void*)(Qh + qtb + chunk * 8),
                                       (AS3 void*)(smem + QH + chunk * 16), 16, 0, 0);
      __builtin_amdgcn_global_load_lds((const AS1 void*)(Ql + qtb + chunk * 8),
                                       (AS3 void*)(smem + QL + chunk * 16), 16, 0, 0);
    }
    asm volatile("s_waitcnt vmcnt(0)" ::: "memory");
    __syncthreads();
    short8v qhf[2], qlf[2];
    qhf[0] = *(const short8v*)(smem + QH + qro + ((16 * g) ^ qsw));
    qhf[1] = *(const short8v*)(smem + QH + qro + ((64 + 16 * g) ^ qsw));
    qlf[0] = *(const short8v*)(smem + QL + qro + ((16 * g) ^ qsw));
    qlf[1] = *(const short8v*)(smem + QL + qro + ((64 + 16 * g) ^ qsw));

    f32x4 o[4];
#pragma unroll
    for (int dt = 0; dt < 4; dt++) o[dt] = (f32x4)0.f;
    float m = -1e30f, lsum = 0.f;

    for (int kt = 0; kt <= qtile; ++kt) {
      __syncthreads();  // prior-iter LDS reads done before overwrite
      size_t ktb = kvb + (size_t)kt * 4096;
#pragma unroll
      for (int j = 0; j < 2; j++) {
        int chunk = j * 256 + tid;
        __builtin_amdgcn_global_load_lds((const AS1 void*)(Kht + ktb + chunk * 8),
                                         (AS3 void*)(smem + KH + chunk * 16), 16, 0, 0);
        __builtin_amdgcn_global_load_lds((const AS1 void*)(Klt + ktb + chunk * 8),
                                         (AS3 void*)(smem + KL + chunk * 16), 16, 0, 0);
        __builtin_amdgcn_global_load_lds((const AS1 void*)(Vht + ktb + chunk * 8),
                                         (AS3 void*)(smem + VB + chunk * 16), 16, 0, 0);
        __builtin_amdgcn_global_load_lds((const AS1 void*)(Vlt + ktb + chunk * 8),
                                         (AS3 void*)(smem + VB + 8192 + chunk * 16), 16, 0,
                                         0);
      }
      asm volatile("s_waitcnt vmcnt(0)" ::: "memory");
      __syncthreads();
      const bool diag = (kt == qtile);

      // ---- S^T = K·Q^T (3-term bf16 split), per wave: [64 keys][16 q] ----
      f32x4 sv[4];
#pragma unroll
      for (int s = 0; s < 4; ++s) {
        unsigned ro = (unsigned)((s * 16 + q15) * 128);
        short8v kh0 = *(const short8v*)(smem + KH + ro + ((16 * g) ^ qsw));
        short8v kh1 = *(const short8v*)(smem + KH + ro + ((64 + 16 * g) ^ qsw));
        short8v kl0 = *(const short8v*)(smem + KL + ro + ((16 * g) ^ qsw));
        short8v kl1 = *(const short8v*)(smem + KL + ro + ((64 + 16 * g) ^ qsw));
        f32x4 a = (f32x4)0.f;
        a = MF32(kh0, qhf[0], a);
        a = MF32(kh1, qhf[1], a);
        a = MF32(kh0, qlf[0], a);
        a = MF32(kh1, qlf[1], a);
        a = MF32(kl0, qhf[0], a);
        a = MF32(kl1, qhf[1], a);
        sv[s] = a;
      }
      // ---- causal mask + online softmax ----
      float mx = -1e30f;
#pragma unroll
      for (int s = 0; s < 4; ++s)
#pragma unroll
        for (int r = 0; r < 4; ++r) {
          if (diag && (s * 16 + g * 4 + r) > qloc) sv[s][r] = -1e30f;
          mx = fmaxf(mx, sv[s][r]);
        }
      mx = fmaxf(mx, __shfl_xor(mx, 16));
      mx = fmaxf(mx, __shfl_xor(mx, 32));
      float mnew = fmaxf(m, mx);
      float alpha = __expf(m - mnew);
      float p[4][4];
      float ps = 0.f;
#pragma unroll
      for (int s = 0; s < 4; ++s)
#pragma unroll
        for (int r = 0; r < 4; ++r) {
          p[s][r] = __expf(sv[s][r] - mnew);
          ps += p[s][r];
        }
      ps += __shfl_xor(ps, 16);
      ps += __shfl_xor(ps, 32);
      lsum = lsum * alpha + ps;
      m = mnew;
#pragma unroll
      for (int dt = 0; dt < 4; dt++) o[dt] *= alpha;
      // ---- P -> bf16 hi/lo, bounce through per-wave LDS ----
#pragma unroll
      for (int s = 0; s < 4; ++s) {
        unsigned short h0 = f2b1(p[s][0]), h1 = f2b1(p[s][1]), h2 = f2b1(p[s][2]),
                       h3 = f2b1(p[s][3]);
        short4v ph = short4v{(short)h0, (short)h1, (short)h2, (short)h3};
        short4v pl = short4v{(short)f2b1(p[s][0] - b2f(h0)), (short)f2b1(p[s][1] - b2f(h1)),
                             (short)f2b1(p[s][2] - b2f(h2)), (short)f2b1(p[s][3] - b2f(h3))};
        unsigned pb = (unsigned)(PB + w * 4096 + q15 * 128 +
                                 (((unsigned)(s * 32 + 8 * g)) ^ qsw));
        *(short4v*)(smem + pb) = ph;
        *(short4v*)(smem + pb + 2048) = pl;
      }
      asm volatile("" ::: "memory");  // order P writes before reads (same wave)
      // ---- O^T += V^T·P^T (3-term), vT A-frags via plain swizzled b128 ----
#pragma unroll
      for (int kk = 0; kk < 2; ++kk) {
        unsigned pq = (unsigned)(PB + w * 4096 + q15 * 128 +
                                 (((unsigned)(kk * 64 + 16 * g)) ^ qsw));
        short8v ph8 = *(const short8v*)(smem + pq);
        short8v pl8 = *(const short8v*)(smem + pq + 2048);
        unsigned koff = (unsigned)(kk * 64 + g * 16);
#pragma unroll
        for (int dt = 0; dt < 4; ++dt) {
          unsigned off = VB + (unsigned)((dt * 16 + q15) * 128) + (koff ^ qsw);
          short8v vh8 = *(const short8v*)(smem + off);
          short8v vl8 = *(const short8v*)(smem + off + 8192);
          o[dt] = MF32(vh8, ph8, o[dt]);
          o[dt] = MF32(vh8, pl8, o[dt]);
          o[dt] = MF32(vl8, ph8, o[dt]);
        }
      }
    }
    // ---- epilogue: write y as bf16 hi/lo (feeds bf16x3 proj GEMM) ----
    float inv = 1.0f / lsum;
    size_t ybase = ((size_t)(b * Tc + qtile * 64 + qloc)) * Cc + hh * 64;
#pragma unroll
    for (int dt = 0; dt < 4; dt++) {
      float4 s4 = make_float4(o[dt][0] * inv, o[dt][1] * inv, o[dt][2] * inv,
                              o[dt][3] * inv);
      short4v hi, lo;
      split4(s4, hi, lo);
      *(short4v*)&Yh[ybase + dt * 16 + 4 * g] = hi;
      *(short4v*)&Yl[ybase + dt * 16 + 4 * g] = lo;
    }
  }
}

// ---------------- prefix sums: gbase + tilebase ----------------
__global__ void k_meta(const int* __restrict__ cnt, int* __restrict__ meta) {
  if (threadIdx.x == 0) {
    int gb = 0, tb = 0;
    for (int e = 0; e < Ec; e++) {
      meta[e] = gb;
      meta[16 + e] = tb;
      gb += cnt[e];
      tb += (cnt[e] + 127) >> 7;
    }
    meta[8] = gb;
    meta[16 + 8] = tb;
  }
}

// ---------------- router: softmax -> top2 -> compact assignment lists --------
__global__ __launch_bounds__(256) void k_router(const float* __restrict__ h2,
                                                const float* __restrict__ rw,
                                                float* __restrict__ probs,
                                                int* __restrict__ idx,
                                                float* __restrict__ wt,
                                                int* __restrict__ cnt) {
  int gw = (blockIdx.x * 256 + threadIdx.x) >> 6;
  int lane = threadIdx.x & 63;
  if (gw >= Nc) return;
  const float* row = h2 + (size_t)gw * Cc;
  float acc[Ec] = {};
  for (int k = lane; k < Cc; k += 64) {
    float hv = row[k];
#pragma unroll
    for (int e = 0; e < Ec; e++) acc[e] += hv * rw[e * Cc + k];
  }
#pragma unroll
  for (int e = 0; e < Ec; e++) {
#pragma unroll
    for (int msk = 1; msk < 64; msk <<= 1) acc[e] += __shfl_xor(acc[e], msk);
  }
  if (lane == 0) {
    float mx = acc[0];
#pragma unroll
    for (int e = 1; e < Ec; e++) mx = fmaxf(mx, acc[e]);
    float p[Ec];
    float s = 0.f;
#pragma unroll
    for (int e = 0; e < Ec; e++) {
      p[e] = expf(acc[e] - mx);
      s += p[e];
    }
    float invs = 1.0f / s;
#pragma unroll
    for (int e = 0; e < Ec; e++) {
      p[e] *= invs;
      probs[(size_t)gw * Ec + e] = p[e];
    }
    int i0 = 0;
#pragma unroll
    for (int e = 1; e < Ec; e++)
      if (p[e] > p[i0]) i0 = e;
    int i1 = (i0 == 0) ? 1 : 0;
#pragma unroll
    for (int e = 0; e < Ec; e++)
      if (e != i0 && p[e] > p[i1]) i1 = e;
    float wsum = p[i0] + p[i1];
    int s0 = atomicAdd(&cnt[i0], 1);
    idx[i0 * Nc + s0] = gw;
    wt[i0 * Nc + s0] = p[i0] / wsum;
    int s1 = atomicAdd(&cnt[i1], 1);
    idx[i1 * Nc + s1] = gw;
    wt[i1 * Nc + s1] = p[i1] / wsum;
  }
}

__global__ __launch_bounds__(256) void k_aux(const float* __restrict__ probs,
                                             float* __restrict__ outp) {
  int tid = threadIdx.x;
  int lane = tid & 63, w = tid >> 6;
  float acc[Ec] = {};
  for (int n = tid; n < Nc; n += 256) {
#pragma unroll
    for (int e = 0; e < Ec; e++) acc[e] += probs[(size_t)n * Ec + e];
  }
#pragma unroll
  for (int e = 0; e < Ec; e++) {
#pragma unroll
    for (int msk = 1; msk < 64; msk <<= 1) acc[e] += __shfl_xor(acc[e], msk);
  }
  __shared__ float red[4][Ec];
  if (lane == 0) {
#pragma unroll
    for (int e = 0; e < Ec; e++) red[w][e] = acc[e];
  }
  __syncthreads();
  if (tid == 0) {
    float aux = 0.f;
#pragma unroll
    for (int e = 0; e < Ec; e++) {
      float tot = red[0][e] + red[1][e] + red[2][e] + red[3][e];
      float avg = tot * (1.0f / Nc);
      aux += avg * avg;
    }
    outp[0] = (float)Ec * aux;
  }
}

extern "C" void kernel_launch(void* const* d_in, const int* in_sizes, int n_in,
                              void* d_out, int out_size, void* d_ws, size_t ws_size,
                              hipStream_t stream) {
  const float* x      = (const float*)d_in[0];
  const float* ln1_w  = (const float*)d_in[1];
  const float* ln2_w  = (const float*)d_in[2];
  const float* conv_w = (const float*)d_in[3];
  const float* attn_w = (const float*)d_in[4];
  const float* proj_w = (const float*)d_in[5];
  const float* rout_w = (const float*)d_in[6];
  const float* ewv    = (const float*)d_in[7];
  const float* ewo    = (const float*)d_in[8];
  float* out = (float*)d_out;
  float* ws = (float*)d_ws;

  float* h    = ws + OFF_H;
  float* qkv  = ws + OFF_QKV;
  float* h2   = ws + OFF_H2;
  float* prob = ws + OFF_PROB;
  int*   idxp = (int*)(ws + OFF_IDX);
  float* wtp  = ws + OFF_WT;
  int*   cntp = (int*)(ws + OFF_CNT);
  int*   metap = (int*)(ws + OFF_META);
  unsigned short* wqh = (unsigned short*)(ws + OFF_WQH);
  unsigned short* wql = (unsigned short*)(ws + OFF_WQL);
  unsigned short* wph = (unsigned short*)(ws + OFF_WPH);
  unsigned short* wpl = (unsigned short*)(ws + OFF_WPL);
  unsigned short* hch = (unsigned short*)(ws + OFF_HCH);
  unsigned short* hcl = (unsigned short*)(ws + OFF_HCL);
  unsigned short* qhb = (unsigned short*)(ws + OFF_QHB);
  unsigned short* qlb = (unsigned short*)(ws + OFF_QLB);
  unsigned short* khb = (unsigned short*)(ws + OFF_KHB);
  unsigned short* klb = (unsigned short*)(ws + OFF_KLB);
  unsigned short* vhb = (unsigned short*)(ws + OFF_VHB);
  unsigned short* vlb = (unsigned short*)(ws + OFF_VLB);
  unsigned short* yh  = (unsigned short*)(ws + OFF_YH);
  unsigned short* yl  = (unsigned short*)(ws + OFF_YL);
  unsigned short* h2bf = (unsigned short*)(ws + OFF_H2BF);
  unsigned short* ehbf = (unsigned short*)(ws + OFF_EHBF);
  unsigned short* wvbf = (unsigned short*)(ws + OFF_WVBF);
  unsigned short* wobf = (unsigned short*)(ws + OFF_WOBF);

  // attention branch
  k_rmsnorm<<<Nc, 256, 0, stream>>>(x, ln1_w, h);
  k_conv_split<<<(Nc * Cc / 4) / 256, 256, 0, stream>>>(h, conv_w, hch, hcl);
  k_f2bsp<<<(QKVD * Cc / 4) / 256, 256, 0, stream>>>(attn_w, wqh, wql, QKVD * Cc);
  k_f2bsp<<<(Cc * Cc / 4) / 256, 256, 0, stream>>>(proj_w, wph, wpl, Cc * Cc);
  {
    dim3 g(QKVD / 128, Nc / 128);
    k_gemm_x3<0><<<g, 256, 0, stream>>>(hch, hcl, wqh, wql, qkv, nullptr, Nc, QKVD, Cc);
  }
  k_ropeln_q<<<(Nc * Hc * 64) / 256, 256, 0, stream>>>(qkv, qhb, qlb);
  k_ropeln_kv<<<(Nc * KVc * 64) / 256, 256, 0, stream>>>(qkv, khb, klb, vhb, vlb);
  k_attn2<<<dim3(Tc / 128, Hc, Bc), 256, 0, stream>>>(qhb, qlb, khb, klb, vhb, vlb, yh, yl);
  {
    dim3 g(Cc / 128, Nc / 128);
    k_gemm_x3<1><<<g, 256, 0, stream>>>(yh, yl, wph, wpl, out, x, Nc, Cc, Cc);
  }
  // MoE branch: router -> grouped single-launch expert GEMMs (fused silu)
  k_rmsnorm_bf<<<Nc, 256, 0, stream>>>(out, ln2_w, h2, h2bf, cntp);
  k_router<<<Nc / 4, 256, 0, stream>>>(h2, rout_w, prob, idxp, wtp, cntp);
  k_meta<<<1, 64, 0, stream>>>(cntp, metap);
  k_aux<<<1, 256, 0, stream>>>(prob, out + (size_t)Nc * Cc);
  k_f2b<<<(Ec * 2 * Fc * Cc / 4) / 256, 256, 0, stream>>>(ewv, wvbf, Ec * 2 * Fc * Cc);
  k_f2b<<<(Ec * Cc * Fc / 4) / 256, 256, 0, stream>>>(ewo, wobf, Ec * Cc * Fc);
  k_moe_wv<<<dim3(Fc / 128, MAXTILES), 256, 0, stream>>>(h2bf, wvbf, ehbf, idxp, cntp, metap);
  k_moe_wo<<<dim3(Cc / 128, MAXTILES), 256, 0, stream>>>(ehbf, wobf, out, idxp, wtp, cntp,
                                                         metap);
}

// Round 12
// 509.151 us; speedup vs baseline: 1.1846x; 1.0568x over previous
//
#include <hip/hip_runtime.h>
#include <math.h>

namespace {
constexpr int Bc = 2, Tc = 2048, Cc = 1024, Hc = 16, KVc = 4, HDc = 64, Ec = 8, Fc = 1024;
constexpr int Nc = Bc * Tc;               // 4096 tokens
constexpr int QKVD = Cc + 2 * KVc * HDc;  // 1536
constexpr int GRP = Hc / KVc;             // 4
constexpr float RBASE = 50000.0f;
constexpr int MAXTILES = 72;              // worst-case sum of ceil(cnt[e]/128)

// workspace layout (floats) — peak ≤ 24M floats = 96 MB (proven footprint)
// ---- attention phase ----
constexpr size_t OFF_WQH = 0;                        // 0.75M (attn_w hi, bf16)
constexpr size_t OFF_WQL = 768u * 1024;              // 0.75M
constexpr size_t OFF_WPH = 1536u * 1024;             // 0.5M  (proj_w hi)
constexpr size_t OFF_WPL = 2048u * 1024;             // 0.5M
constexpr size_t OFF_H   = 2560u * 1024;             // 4M    (rmsnorm out; dead after conv)
constexpr size_t OFF_HCH = 6656u * 1024;             // 2M    (conv out hi, bf16)
constexpr size_t OFF_HCL = 8704u * 1024;             // 2M
constexpr size_t OFF_QKV = 10752u * 1024;            // 6M fp32
constexpr size_t OFF_QHB = 16896u * 1024;            // 2M floats = 4M bf16 (q hi, tiled)
constexpr size_t OFF_QLB = 18944u * 1024;            // 2M floats (q lo)
constexpr size_t OFF_KHB = 20992u * 1024;            // 0.5M floats (k hi, tiled swz)
constexpr size_t OFF_KLB = 21504u * 1024;            // 0.5M
constexpr size_t OFF_VHB = 22016u * 1024;            // 0.5M (vT hi, tiled swz)
constexpr size_t OFF_VLB = 22528u * 1024;            // 0.5M
constexpr size_t OFF_YH  = 2560u * 1024;             // 2M (attn out hi; over dead h)
constexpr size_t OFF_YL  = 4608u * 1024;             // 2M
// ---- MoE phase (attention buffers dead) ----
constexpr size_t OFF_H2   = 0;                       // 4M (h2 fp32)
constexpr size_t OFF_H2BF = 4u * 1024 * 1024;        // 2M floats = 4M bf16
constexpr size_t OFF_EHBF = 6u * 1024 * 1024;        // 4M floats = 8192 x 1024 bf16
constexpr size_t OFF_WVBF = 10u * 1024 * 1024;       // 8.4M floats
constexpr size_t OFF_WOBF = 18u * 1024 * 1024 + 512u * 1024;  // 4.2M floats
constexpr size_t OFF_PROB = 23u * 1024 * 1024;       // 32k floats
constexpr size_t OFF_IDX  = OFF_PROB + 32768;        // 32k ints (E x Nc)
constexpr size_t OFF_WT   = OFF_IDX + 32768;         // 32k floats
constexpr size_t OFF_CNT  = OFF_WT + 32768;          // 64 ints
constexpr size_t OFF_META = OFF_CNT + 64;            // 32 ints
}

typedef __attribute__((ext_vector_type(8))) short short8v;   // 8 bf16 (4 VGPRs)
typedef __attribute__((ext_vector_type(4))) short short4v;   // 4 bf16 (2 VGPRs)
typedef __attribute__((ext_vector_type(4))) float f32x4;

#define MF32(a, b, c) __builtin_amdgcn_mfma_f32_16x16x32_bf16((a), (b), (c), 0, 0, 0)
#define AS1 __attribute__((address_space(1)))
#define AS3 __attribute__((address_space(3)))

__device__ __forceinline__ unsigned short f2b1(float f) {
  union { float f; unsigned int u; } x;
  x.f = f;
  unsigned int r = (x.u + 0x7FFFu + ((x.u >> 16) & 1u)) >> 16;
  return (unsigned short)r;
}

__device__ __forceinline__ float b2f(unsigned short h) {
  union { unsigned int u; float f; } x;
  x.u = (unsigned int)h << 16;
  return x.f;
}

// split fp32 -> bf16 hi + bf16 lo (x ~= hi + lo, |err| ~ 2^-18 |x|)
__device__ __forceinline__ void split4(float4 v, short4v& hi, short4v& lo) {
  unsigned short h0 = f2b1(v.x), h1 = f2b1(v.y), h2 = f2b1(v.z), h3 = f2b1(v.w);
  hi = short4v{(short)h0, (short)h1, (short)h2, (short)h3};
  lo = short4v{(short)f2b1(v.x - b2f(h0)), (short)f2b1(v.y - b2f(h1)),
               (short)f2b1(v.z - b2f(h2)), (short)f2b1(v.w - b2f(h3))};
}

// ---------------- rmsnorm ----------------
__global__ __launch_bounds__(256) void k_rmsnorm(const float* __restrict__ in,
                                                 const float* __restrict__ w,
                                                 float* __restrict__ out) {
  int n = blockIdx.x;
  int tid = threadIdx.x;
  const float* row = in + (size_t)n * Cc;
  float v[4];
  float ss = 0.f;
#pragma unroll
  for (int i = 0; i < 4; i++) {
    v[i] = row[tid + i * 256];
    ss += v[i] * v[i];
  }
#pragma unroll
  for (int m = 1; m < 64; m <<= 1) ss += __shfl_xor(ss, m);
  __shared__ float red[4];
  if ((tid & 63) == 0) red[tid >> 6] = ss;
  __syncthreads();
  float tot = red[0] + red[1] + red[2] + red[3];
  float rs = rsqrtf(tot * (1.0f / Cc) + 1e-6f);
  float* orow = out + (size_t)n * Cc;
#pragma unroll
  for (int i = 0; i < 4; i++) orow[tid + i * 256] = v[i] * rs * w[tid + i * 256];
}

// ----- rmsnorm + bf16 copy + expert-counter zeroing (MoE-side, fused) -----
__global__ __launch_bounds__(256) void k_rmsnorm_bf(const float* __restrict__ in,
                                                    const float* __restrict__ w,
                                                    float* __restrict__ out,
                                                    unsigned short* __restrict__ outbf,
                                                    int* __restrict__ cnt) {
  if (blockIdx.x == 0 && threadIdx.x < 16) cnt[threadIdx.x] = 0;
  int n = blockIdx.x;
  int tid = threadIdx.x;
  const float* row = in + (size_t)n * Cc;
  float v[4];
  float ss = 0.f;
#pragma unroll
  for (int i = 0; i < 4; i++) {
    v[i] = row[tid + i * 256];
    ss += v[i] * v[i];
  }
#pragma unroll
  for (int m = 1; m < 64; m <<= 1) ss += __shfl_xor(ss, m);
  __shared__ float red[4];
  if ((tid & 63) == 0) red[tid >> 6] = ss;
  __syncthreads();
  float tot = red[0] + red[1] + red[2] + red[3];
  float rs = rsqrtf(tot * (1.0f / Cc) + 1e-6f);
  float* orow = out + (size_t)n * Cc;
  unsigned short* obf = outbf + (size_t)n * Cc;
#pragma unroll
  for (int i = 0; i < 4; i++) {
    float r = v[i] * rs * w[tid + i * 256];
    orow[tid + i * 256] = r;
    obf[tid + i * 256] = f2b1(r);
  }
}

// -------- causal depthwise conv1d, fused fp32->bf16 hi/lo split --------
__global__ __launch_bounds__(256) void k_conv_split(const float* __restrict__ h,
                                                    const float* __restrict__ cw,
                                                    unsigned short* __restrict__ oh,
                                                    unsigned short* __restrict__ ol) {
  int i4 = blockIdx.x * 256 + threadIdx.x;
  if (i4 >= Nc * Cc / 4) return;
  int idx = i4 * 4;
  int c = idx & (Cc - 1);
  int n = idx >> 10;
  int t = n & (Tc - 1);
  float4 z = make_float4(0.f, 0.f, 0.f, 0.f);
  float4 d2 = (t >= 2) ? *(const float4*)&h[idx - 2 * Cc] : z;
  float4 d1 = (t >= 1) ? *(const float4*)&h[idx - Cc] : z;
  float4 d0 = *(const float4*)&h[idx];
  float4 r;
  r.x = d2.x * cw[(c + 0) * 3] + d1.x * cw[(c + 0) * 3 + 1] + d0.x * cw[(c + 0) * 3 + 2];
  r.y = d2.y * cw[(c + 1) * 3] + d1.y * cw[(c + 1) * 3 + 1] + d0.y * cw[(c + 1) * 3 + 2];
  r.z = d2.z * cw[(c + 2) * 3] + d1.z * cw[(c + 2) * 3 + 1] + d0.z * cw[(c + 2) * 3 + 2];
  r.w = d2.w * cw[(c + 3) * 3] + d1.w * cw[(c + 3) * 3 + 1] + d0.w * cw[(c + 3) * 3 + 2];
  short4v hi, lo;
  split4(r, hi, lo);
  *(short4v*)&oh[idx] = hi;
  *(short4v*)&ol[idx] = lo;
}

// ---------------- fp32 -> bf16 hi/lo split (weights) ----------------
__global__ __launch_bounds__(256) void k_f2bsp(const float* __restrict__ in,
                                               unsigned short* __restrict__ oh,
                                               unsigned short* __restrict__ ol, int n) {
  int i = (blockIdx.x * 256 + threadIdx.x) * 4;
  if (i >= n) return;
  float4 v = *(const float4*)&in[i];
  short4v hi, lo;
  split4(v, hi, lo);
  *(short4v*)&oh[i] = hi;
  *(short4v*)&ol[i] = lo;
}

// ---------------- fp32 -> bf16 conversion ----------------
__global__ __launch_bounds__(256) void k_f2b(const float* __restrict__ in,
                                             unsigned short* __restrict__ outp, int n) {
  int i = (blockIdx.x * 256 + threadIdx.x) * 4;
  if (i >= n) return;
  float4 v = *(const float4*)&in[i];
  uint2 o;
  o.x = (unsigned int)f2b1(v.x) | ((unsigned int)f2b1(v.y) << 16);
  o.y = (unsigned int)f2b1(v.z) | ((unsigned int)f2b1(v.w) << 16);
  *(uint2*)&outp[i] = o;
}

// ------- bf16x3 MFMA GEMM: C = A.B^T with A,B split hi/lo (m97 structure) ----
// EPI 0: C = acc ; EPI 1: C = resid + acc
template <int EPI>
__global__ __launch_bounds__(256) void k_gemm_x3(const unsigned short* __restrict__ Ah,
                                                 const unsigned short* __restrict__ Al,
                                                 const unsigned short* __restrict__ Bh,
                                                 const unsigned short* __restrict__ Bl,
                                                 float* __restrict__ Cm,
                                                 const float* __restrict__ resid,
                                                 int M, int N, int K) {
  constexpr int BM = 128, BN = 128, BK = 32;
  __shared__ __align__(16) unsigned short lAh[BM * BK];
  __shared__ __align__(16) unsigned short lAl[BM * BK];
  __shared__ __align__(16) unsigned short lBh[BN * BK];
  __shared__ __align__(16) unsigned short lBl[BN * BK];
  int tid = threadIdx.x;
  int lane = tid & 63;
  int wave = tid >> 6;
  int wr = wave >> 1, wc = wave & 1;
  int m0 = blockIdx.y * BM, n0 = blockIdx.x * BN;

  f32x4 acc[4][4];
#pragma unroll
  for (int i = 0; i < 4; i++)
#pragma unroll
    for (int j = 0; j < 4; j++) acc[i][j] = (f32x4)0.f;

  int kf = (lane >> 4) * 8;
  int rl = lane & 15;

  for (int k0 = 0; k0 < K; k0 += BK) {
    __syncthreads();
#pragma unroll
    for (int j = 0; j < 2; j++) {
      int chunk = j * 256 + tid;
      int row = chunk >> 2;
      int cb = (chunk & 3) * 8;
      size_t aoff = (size_t)(m0 + row) * K + k0 + cb;
      size_t boff = (size_t)(n0 + row) * K + k0 + cb;
      __builtin_amdgcn_global_load_lds((const AS1 void*)(Ah + aoff),
                                       (AS3 void*)(&lAh[chunk * 8]), 16, 0, 0);
      __builtin_amdgcn_global_load_lds((const AS1 void*)(Al + aoff),
                                       (AS3 void*)(&lAl[chunk * 8]), 16, 0, 0);
      __builtin_amdgcn_global_load_lds((const AS1 void*)(Bh + boff),
                                       (AS3 void*)(&lBh[chunk * 8]), 16, 0, 0);
      __builtin_amdgcn_global_load_lds((const AS1 void*)(Bl + boff),
                                       (AS3 void*)(&lBl[chunk * 8]), 16, 0, 0);
    }
    asm volatile("s_waitcnt vmcnt(0)" ::: "memory");
    __syncthreads();

    short8v ah[4], al4[4], bh4[4], bl4[4];
#pragma unroll
    for (int i = 0; i < 4; i++) {
      int ro = (wr * 64 + i * 16 + rl) * BK + kf;
      ah[i] = *(const short8v*)&lAh[ro];
      al4[i] = *(const short8v*)&lAl[ro];
    }
#pragma unroll
    for (int j = 0; j < 4; j++) {
      int ro = (wc * 64 + j * 16 + rl) * BK + kf;
      bh4[j] = *(const short8v*)&lBh[ro];
      bl4[j] = *(const short8v*)&lBl[ro];
    }
#pragma unroll
    for (int i = 0; i < 4; i++)
#pragma unroll
      for (int j = 0; j < 4; j++) {
        acc[i][j] = MF32(ah[i], bh4[j], acc[i][j]);
        acc[i][j] = MF32(ah[i], bl4[j], acc[i][j]);
        acc[i][j] = MF32(al4[i], bh4[j], acc[i][j]);
      }
  }

  int cl = lane & 15;
  int rb = (lane >> 4) * 4;
#pragma unroll
  for (int i = 0; i < 4; i++) {
#pragma unroll
    for (int r = 0; r < 4; r++) {
      int m = m0 + wr * 64 + i * 16 + rb + r;
#pragma unroll
      for (int j = 0; j < 4; j++) {
        int n = n0 + wc * 64 + j * 16 + cl;
        size_t off = (size_t)m * N + n;
        if (EPI == 0) Cm[off] = acc[i][j][r];
        else Cm[off] = resid[off] + acc[i][j][r];
      }
    }
  }
}

// ------- grouped MoE up-proj + fused SwiGLU: all experts, one launch --------
// BN=64 (gate + val 64 cols each): halves accumulator VGPR (164 -> ~120) to
// fix the 8% occupancy cliff; K-order and operands per output unchanged.
__global__ __launch_bounds__(256) void k_moe_wv(const unsigned short* __restrict__ A,
                                                const unsigned short* __restrict__ Wv,
                                                unsigned short* __restrict__ Eh,
                                                const int* __restrict__ idx,
                                                const int* __restrict__ cnt,
                                                const int* __restrict__ meta) {
  constexpr int BK = 32;
  if ((int)blockIdx.y >= meta[16 + 8]) return;
  int e = 0;
#pragma unroll
  for (int i = 1; i < Ec; i++)
    if ((int)blockIdx.y >= meta[16 + i]) e = i;
  int lm = blockIdx.y - meta[16 + e];
  int count = cnt[e];
  int gb = meta[e];
  int m0 = lm * 128;
  int n0 = blockIdx.x * 64;

  __shared__ __align__(16) unsigned short lA[128 * BK];   // 8 KB
  __shared__ __align__(16) unsigned short lBg[64 * BK];   // 4 KB
  __shared__ __align__(16) unsigned short lBv[64 * BK];   // 4 KB
  int tid = threadIdx.x;
  int lane = tid & 63;
  int wave = tid >> 6;
  int wr = wave >> 1, wc = wave & 1;  // wave tile: 64 rows x 32 cols

  const unsigned short* srcA[2];
  const unsigned short* srcG;
  const unsigned short* srcV;
#pragma unroll
  for (int j = 0; j < 2; j++) {
    int chunk = j * 256 + tid;
    int row = chunk >> 2, cb = (chunk & 3) * 8;
    int mrow = m0 + row;
    int tok = idx[e * Nc + (mrow < count ? mrow : count - 1)];
    srcA[j] = A + (size_t)tok * Cc + cb;
  }
  {
    int row = tid >> 2, cb = (tid & 3) * 8;
    const unsigned short* wbase = Wv + (size_t)e * 2 * Fc * Cc;
    srcG = wbase + (size_t)(n0 + row) * Cc + cb;
    srcV = wbase + (size_t)(Fc + n0 + row) * Cc + cb;
  }

  f32x4 accG[4][2], accV[4][2];
#pragma unroll
  for (int i = 0; i < 4; i++)
#pragma unroll
    for (int j = 0; j < 2; j++) {
      accG[i][j] = (f32x4)0.f;
      accV[i][j] = (f32x4)0.f;
    }

  int kf = (lane >> 4) * 8;
  int rl = lane & 15;

  for (int k0 = 0; k0 < Cc; k0 += BK) {
    __syncthreads();
#pragma unroll
    for (int j = 0; j < 2; j++) {
      int chunk = j * 256 + tid;
      __builtin_amdgcn_global_load_lds((const AS1 void*)(srcA[j] + k0),
                                       (AS3 void*)(&lA[chunk * 8]), 16, 0, 0);
    }
    __builtin_amdgcn_global_load_lds((const AS1 void*)(srcG + k0),
                                     (AS3 void*)(&lBg[tid * 8]), 16, 0, 0);
    __builtin_amdgcn_global_load_lds((const AS1 void*)(srcV + k0),
                                     (AS3 void*)(&lBv[tid * 8]), 16, 0, 0);
    asm volatile("s_waitcnt vmcnt(0)" ::: "memory");
    __syncthreads();

    short8v a[4], bg[2], bv[2];
#pragma unroll
    for (int i = 0; i < 4; i++)
      a[i] = *(const short8v*)&lA[(wr * 64 + i * 16 + rl) * BK + kf];
#pragma unroll
    for (int j = 0; j < 2; j++) {
      bg[j] = *(const short8v*)&lBg[(wc * 32 + j * 16 + rl) * BK + kf];
      bv[j] = *(const short8v*)&lBv[(wc * 32 + j * 16 + rl) * BK + kf];
    }
#pragma unroll
    for (int i = 0; i < 4; i++)
#pragma unroll
      for (int j = 0; j < 2; j++) {
        accG[i][j] = MF32(a[i], bg[j], accG[i][j]);
        accV[i][j] = MF32(a[i], bv[j], accV[i][j]);
      }
  }

  int cl = lane & 15;
  int rb = (lane >> 4) * 4;
#pragma unroll
  for (int i = 0; i < 4; i++) {
#pragma unroll
    for (int r = 0; r < 4; r++) {
      int m = m0 + wr * 64 + i * 16 + rb + r;
      if (m < count) {
        size_t gs = (size_t)(gb + m);
#pragma unroll
        for (int j = 0; j < 2; j++) {
          int n = n0 + wc * 32 + j * 16 + cl;
          float g = accG[i][j][r];
          float v = accV[i][j][r];
          Eh[gs * Fc + n] = f2b1(g / (1.0f + __expf(-g)) * v);
        }
      }
    }
  }
}

// ------- grouped MoE down-proj + weighted scatter: all experts, one launch ---
__global__ __launch_bounds__(256) void k_moe_wo(const unsigned short* __restrict__ Eh,
                                                const unsigned short* __restrict__ Wo,
                                                float* __restrict__ C,
                                                const int* __restrict__ idx,
                                                const float* __restrict__ wt,
                                                const int* __restrict__ cnt,
                                                const int* __restrict__ meta) {
  constexpr int BK = 32;
  if ((int)blockIdx.y >= meta[16 + 8]) return;
  int e = 0;
#pragma unroll
  for (int i = 1; i < Ec; i++)
    if ((int)blockIdx.y >= meta[16 + i]) e = i;
  int lm = blockIdx.y - meta[16 + e];
  int count = cnt[e];
  int gb = meta[e];
  int m0 = lm * 128;
  int n0 = blockIdx.x * 128;

  __shared__ __align__(16) unsigned short lA[128 * BK];
  __shared__ __align__(16) unsigned short lB[128 * BK];
  int tid = threadIdx.x;
  int lane = tid & 63;
  int wave = tid >> 6;
  int wr = wave >> 1, wc = wave & 1;

  f32x4 acc[4][4];
#pragma unroll
  for (int i = 0; i < 4; i++)
#pragma unroll
    for (int j = 0; j < 4; j++) acc[i][j] = (f32x4)0.f;

  int kf = (lane >> 4) * 8;
  int rl = lane & 15;

  for (int k0 = 0; k0 < Fc; k0 += BK) {
    __syncthreads();
#pragma unroll
    for (int j = 0; j < 2; j++) {
      int chunk = j * 256 + tid;
      int row = chunk >> 2;
      int cb = (chunk & 3) * 8;
      __builtin_amdgcn_global_load_lds(
          (const AS1 void*)(Eh + (size_t)(gb + m0 + row) * Fc + k0 + cb),
          (AS3 void*)(&lA[chunk * 8]), 16, 0, 0);
      __builtin_amdgcn_global_load_lds(
          (const AS1 void*)(Wo + (size_t)e * Cc * Fc + (size_t)(n0 + row) * Fc + k0 + cb),
          (AS3 void*)(&lB[chunk * 8]), 16, 0, 0);
    }
    asm volatile("s_waitcnt vmcnt(0)" ::: "memory");
    __syncthreads();

    short8v a[4], b[4];
#pragma unroll
    for (int i = 0; i < 4; i++)
      a[i] = *(const short8v*)&lA[(wr * 64 + i * 16 + rl) * BK + kf];
#pragma unroll
    for (int j = 0; j < 4; j++)
      b[j] = *(const short8v*)&lB[(wc * 64 + j * 16 + rl) * BK + kf];
#pragma unroll
    for (int i = 0; i < 4; i++)
#pragma unroll
      for (int j = 0; j < 4; j++)
        acc[i][j] = MF32(a[i], b[j], acc[i][j]);
  }

  int cl = lane & 15;
  int rb = (lane >> 4) * 4;
#pragma unroll
  for (int i = 0; i < 4; i++) {
#pragma unroll
    for (int r = 0; r < 4; r++) {
      int m = m0 + wr * 64 + i * 16 + rb + r;
      if (m < count) {
        int slot = e * Nc + m;
        int tok = idx[slot];
        float w = wt[slot];
#pragma unroll
        for (int j = 0; j < 4; j++) {
          int n = n0 + wc * 64 + j * 16 + cl;
          atomicAdd(&C[(size_t)tok * Cc + n], w * acc[i][j][r]);
        }
      }
    }
  }
}

// ---------------- RoPE + layernorm ----------------
__device__ __forceinline__ float rope_ln(float q, int lane, int t, float scale) {
  int j = lane & 31;
  float invf = powf(RBASE, -(float)j * (1.0f / 32.0f));
  float ang = (float)t * invf;
  float s, c;
  sincosf(ang, &s, &c);
  float p = __shfl_xor(q, 32);
  float rot = (lane < 32) ? -p : p;
  float qr = q * c + rot * s;
  float sum = qr, sq = qr * qr;
#pragma unroll
  for (int m = 1; m < 64; m <<= 1) {
    sum += __shfl_xor(sum, m);
    sq += __shfl_xor(sq, m);
  }
  float mean = sum * (1.0f / 64.0f);
  float var = sq * (1.0f / 64.0f) - mean * mean;
  return (qr - mean) * rsqrtf(var + 1e-5f) * scale;
}

// Q: bf16 hi/lo in pre-swizzled tile-blocked layout:
//   tile (64 rows x 64 d) at ((b*H+h)*32 + t/64)*4096; short off = row*64 + (d ^ ((row&7)<<3))
__global__ __launch_bounds__(256) void k_ropeln_q(const float* __restrict__ qkv,
                                                  unsigned short* __restrict__ qh,
                                                  unsigned short* __restrict__ ql) {
  int gw = (blockIdx.x * 256 + threadIdx.x) >> 6;
  int lane = threadIdx.x & 63;
  if (gw >= Nc * Hc) return;
  int h = gw & (Hc - 1);
  int n = gw / Hc;
  int t = n & (Tc - 1);
  int b = n / Tc;
  float q = qkv[(size_t)n * QKVD + h * HDc + lane];
  float o = rope_ln(q, lane, t, 0.125f);  // fold 1/sqrt(hd)
  int row = t & 63;
  size_t ob = (((size_t)(b * Hc + h)) * 32 + (t >> 6)) * 4096 + row * 64 +
              (lane ^ ((row & 7) << 3));
  unsigned short hi = f2b1(o);
  qh[ob] = hi;
  ql[ob] = f2b1(o - b2f(hi));
}

// K: same swizzled tile layout as Q. V: TRANSPOSED tile [64 d][64 key], swizzled:
//   short off = d*64 + (key ^ ((d&7)<<3)) — PV A-frags become plain b128 reads.
__global__ __launch_bounds__(256) void k_ropeln_kv(const float* __restrict__ qkv,
                                                   unsigned short* __restrict__ kh,
                                                   unsigned short* __restrict__ kl,
                                                   unsigned short* __restrict__ vh,
                                                   unsigned short* __restrict__ vl) {
  int gw = (blockIdx.x * 256 + threadIdx.x) >> 6;
  int lane = threadIdx.x & 63;
  if (gw >= Nc * KVc) return;
  int kv = gw & (KVc - 1);
  int n = gw / KVc;
  int t = n & (Tc - 1);
  int b = n / Tc;
  size_t base = (size_t)n * QKVD + Cc + kv * HDc;
  float kval = qkv[base + lane];
  float vval = qkv[base + KVc * HDc + lane];
  float o = rope_ln(kval, lane, t, 1.0f);
  int row = t & 63;  // key index within tile
  size_t tb = (((size_t)(b * KVc + kv)) * 32 + (t >> 6)) * 4096;
  size_t ko = tb + row * 64 + (lane ^ ((row & 7) << 3));
  unsigned short khi = f2b1(o);
  kh[ko] = khi;
  kl[ko] = f2b1(o - b2f(khi));
  // vT: d = lane (row of vT), key = row (column)
  size_t vo = tb + (size_t)lane * 64 + (row ^ ((lane & 7) << 3));
  unsigned short vhi = f2b1(vval);
  vh[vo] = vhi;
  vl[vo] = f2b1(vval - b2f(vhi));
}

// ---------------- flash attention, bf16x3 MFMA, swapped-operand S^T ---------
// BQ=64 (4 waves x 16 q), BK=64. Single-buffer 48KB (3 blocks/CU).
// CAUSAL WORK PAIRING: each block handles qtiles {63-bx, bx} -> uniform 65
// tile-units per block (verified r11: 591->538).
__global__ __launch_bounds__(256, 3) void k_attn2(const unsigned short* __restrict__ Qh,
                                                  const unsigned short* __restrict__ Ql,
                                                  const unsigned short* __restrict__ Kht,
                                                  const unsigned short* __restrict__ Klt,
                                                  const unsigned short* __restrict__ Vht,
                                                  const unsigned short* __restrict__ Vlt,
                                                  unsigned short* __restrict__ Yh,
                                                  unsigned short* __restrict__ Yl) {
  __shared__ __align__(16) unsigned char smem[49152];
  constexpr unsigned QH = 0, QL = 8192, KH = 16384, KL = 24576, VB = 32768, PB = 0;
  int tid = threadIdx.x;
  int l = tid & 63, w = tid >> 6, g = l >> 4, q15 = l & 15;
  int bx = blockIdx.x;  // 0..31
  int hh = blockIdx.y, b = blockIdx.z;
  int kvh = hh >> 2;  // GQA
  size_t kvb = ((size_t)(b * KVc + kvh)) * 32 * 4096;
  unsigned qsw = (unsigned)((q15 & 7) << 4);
  unsigned qro = (unsigned)((w * 16 + q15) * 128);
  int qloc = w * 16 + q15;

  for (int which = 0; which < 2; ++which) {
    int qtile = which == 0 ? (Tc / 64 - 1 - bx) : bx;  // long half first
    size_t qtb = (((size_t)(b * Hc + hh)) * 32 + qtile) * 4096;
    __syncthreads();  // prior pass done with P/Q LDS region
    // ---- stage Q via async, pre-swizzled source ----
#pragma unroll
    for (int j = 0; j < 2; j++) {
      int chunk = j * 256 + tid;
      __builtin_amdgcn_global_load_lds((const AS1 void*)(Qh + qtb + chunk * 8),
                                       (AS3 void*)(smem + QH + chunk * 16), 16, 0, 0);
      __builtin_amdgcn_global_load_lds((const AS1 void*)(Ql + qtb + chunk * 8),
                                       (AS3 void*)(smem + QL + chunk * 16), 16, 0, 0);
    }
    asm volatile("s_waitcnt vmcnt(0)" ::: "memory");
    __syncthreads();
    short8v qhf[2], qlf[2];
    qhf[0] = *(const short8v*)(smem + QH + qro + ((16 * g) ^ qsw));
    qhf[1] = *(const short8v*)(smem + QH + qro + ((64 + 16 * g) ^ qsw));
    qlf[0] = *(const short8v*)(smem + QL + qro + ((16 * g) ^ qsw));
    qlf[1] = *(const short8v*)(smem + QL + qro + ((64 + 16 * g) ^ qsw));

    f32x4 o[4];
#pragma unroll
    for (int dt = 0; dt < 4; dt++) o[dt] = (f32x4)0.f;
    float m = -1e30f, lsum = 0.f;

    for (int kt = 0; kt <= qtile; ++kt) {
      __syncthreads();  // prior-iter LDS reads done before overwrite
      size_t ktb = kvb + (size_t)kt * 4096;
#pragma unroll
      for (int j = 0; j < 2; j++) {
        int chunk = j * 256 + tid;
        __builtin_amdgcn_global_load_lds((const AS1 void*)(Kht + ktb + chunk * 8),
                                         (AS3 void*)(smem + KH + chunk * 16), 16, 0, 0);
        __builtin_amdgcn_global_load_lds((const AS1 void*)(Klt + ktb + chunk * 8),
                                         (AS3 void*)(smem + KL + chunk * 16), 16, 0, 0);
        __builtin_amdgcn_global_load_lds((const AS1 void*)(Vht + ktb + chunk * 8),
                                         (AS3 void*)(smem + VB + chunk * 16), 16, 0, 0);
        __builtin_amdgcn_global_load_lds((const AS1 void*)(Vlt + ktb + chunk * 8),
                                         (AS3 void*)(smem + VB + 8192 + chunk * 16), 16, 0,
                                         0);
      }
      asm volatile("s_waitcnt vmcnt(0)" ::: "memory");
      __syncthreads();
      const bool diag = (kt == qtile);

      // ---- S^T = K·Q^T (3-term bf16 split), per wave: [64 keys][16 q] ----
      f32x4 sv[4];
#pragma unroll
      for (int s = 0; s < 4; ++s) {
        unsigned ro = (unsigned)((s * 16 + q15) * 128);
        short8v kh0 = *(const short8v*)(smem + KH + ro + ((16 * g) ^ qsw));
        short8v kh1 = *(const short8v*)(smem + KH + ro + ((64 + 16 * g) ^ qsw));
        short8v kl0 = *(const short8v*)(smem + KL + ro + ((16 * g) ^ qsw));
        short8v kl1 = *(const short8v*)(smem + KL + ro + ((64 + 16 * g) ^ qsw));
        f32x4 a = (f32x4)0.f;
        a = MF32(kh0, qhf[0], a);
        a = MF32(kh1, qhf[1], a);
        a = MF32(kh0, qlf[0], a);
        a = MF32(kh1, qlf[1], a);
        a = MF32(kl0, qhf[0], a);
        a = MF32(kl1, qhf[1], a);
        sv[s] = a;
      }
      // ---- causal mask + online softmax ----
      float mx = -1e30f;
#pragma unroll
      for (int s = 0; s < 4; ++s)
#pragma unroll
        for (int r = 0; r < 4; ++r) {
          if (diag && (s * 16 + g * 4 + r) > qloc) sv[s][r] = -1e30f;
          mx = fmaxf(mx, sv[s][r]);
        }
      mx = fmaxf(mx, __shfl_xor(mx, 16));
      mx = fmaxf(mx, __shfl_xor(mx, 32));
      float mnew = fmaxf(m, mx);
      float alpha = __expf(m - mnew);
      float p[4][4];
      float ps = 0.f;
#pragma unroll
      for (int s = 0; s < 4; ++s)
#pragma unroll
        for (int r = 0; r < 4; ++r) {
          p[s][r] = __expf(sv[s][r] - mnew);
          ps += p[s][r];
        }
      ps += __shfl_xor(ps, 16);
      ps += __shfl_xor(ps, 32);
      lsum = lsum * alpha + ps;
      m = mnew;
#pragma unroll
      for (int dt = 0; dt < 4; dt++) o[dt] *= alpha;
      // ---- P -> bf16 hi/lo, bounce through per-wave LDS ----
#pragma unroll
      for (int s = 0; s < 4; ++s) {
        unsigned short h0 = f2b1(p[s][0]), h1 = f2b1(p[s][1]), h2 = f2b1(p[s][2]),
                       h3 = f2b1(p[s][3]);
        short4v ph = short4v{(short)h0, (short)h1, (short)h2, (short)h3};
        short4v pl = short4v{(short)f2b1(p[s][0] - b2f(h0)), (short)f2b1(p[s][1] - b2f(h1)),
                             (short)f2b1(p[s][2] - b2f(h2)), (short)f2b1(p[s][3] - b2f(h3))};
        unsigned pb = (unsigned)(PB + w * 4096 + q15 * 128 +
                                 (((unsigned)(s * 32 + 8 * g)) ^ qsw));
        *(short4v*)(smem + pb) = ph;
        *(short4v*)(smem + pb + 2048) = pl;
      }
      asm volatile("" ::: "memory");  // order P writes before reads (same wave)
      // ---- O^T += V^T·P^T (3-term), vT A-frags via plain swizzled b128 ----
#pragma unroll
      for (int kk = 0; kk < 2; ++kk) {
        unsigned pq = (unsigned)(PB + w * 4096 + q15 * 128 +
                                 (((unsigned)(kk * 64 + 16 * g)) ^ qsw));
        short8v ph8 = *(const short8v*)(smem + pq);
        short8v pl8 = *(const short8v*)(smem + pq + 2048);
        unsigned koff = (unsigned)(kk * 64 + g * 16);
#pragma unroll
        for (int dt = 0; dt < 4; ++dt) {
          unsigned off = VB + (unsigned)((dt * 16 + q15) * 128) + (koff ^ qsw);
          short8v vh8 = *(const short8v*)(smem + off);
          short8v vl8 = *(const short8v*)(smem + off + 8192);
          o[dt] = MF32(vh8, ph8, o[dt]);
          o[dt] = MF32(vh8, pl8, o[dt]);
          o[dt] = MF32(vl8, ph8, o[dt]);
        }
      }
    }
    // ---- epilogue: write y as bf16 hi/lo (feeds bf16x3 proj GEMM) ----
    float inv = 1.0f / lsum;
    size_t ybase = ((size_t)(b * Tc + qtile * 64 + qloc)) * Cc + hh * 64;
#pragma unroll
    for (int dt = 0; dt < 4; dt++) {
      float4 s4 = make_float4(o[dt][0] * inv, o[dt][1] * inv, o[dt][2] * inv,
                              o[dt][3] * inv);
      short4v hi, lo;
      split4(s4, hi, lo);
      *(short4v*)&Yh[ybase + dt * 16 + 4 * g] = hi;
      *(short4v*)&Yl[ybase + dt * 16 + 4 * g] = lo;
    }
  }
}

// ---------------- prefix sums: gbase + tilebase ----------------
__global__ void k_meta(const int* __restrict__ cnt, int* __restrict__ meta) {
  if (threadIdx.x == 0) {
    int gb = 0, tb = 0;
    for (int e = 0; e < Ec; e++) {
      meta[e] = gb;
      meta[16 + e] = tb;
      gb += cnt[e];
      tb += (cnt[e] + 127) >> 7;
    }
    meta[8] = gb;
    meta[16 + 8] = tb;
  }
}

// ---------------- router: softmax -> top2 -> compact assignment lists --------
__global__ __launch_bounds__(256) void k_router(const float* __restrict__ h2,
                                                const float* __restrict__ rw,
                                                float* __restrict__ probs,
                                                int* __restrict__ idx,
                                                float* __restrict__ wt,
                                                int* __restrict__ cnt) {
  int gw = (blockIdx.x * 256 + threadIdx.x) >> 6;
  int lane = threadIdx.x & 63;
  if (gw >= Nc) return;
  const float* row = h2 + (size_t)gw * Cc;
  float acc[Ec] = {};
  for (int k = lane; k < Cc; k += 64) {
    float hv = row[k];
#pragma unroll
    for (int e = 0; e < Ec; e++) acc[e] += hv * rw[e * Cc + k];
  }
#pragma unroll
  for (int e = 0; e < Ec; e++) {
#pragma unroll
    for (int msk = 1; msk < 64; msk <<= 1) acc[e] += __shfl_xor(acc[e], msk);
  }
  if (lane == 0) {
    float mx = acc[0];
#pragma unroll
    for (int e = 1; e < Ec; e++) mx = fmaxf(mx, acc[e]);
    float p[Ec];
    float s = 0.f;
#pragma unroll
    for (int e = 0; e < Ec; e++) {
      p[e] = expf(acc[e] - mx);
      s += p[e];
    }
    float invs = 1.0f / s;
#pragma unroll
    for (int e = 0; e < Ec; e++) {
      p[e] *= invs;
      probs[(size_t)gw * Ec + e] = p[e];
    }
    int i0 = 0;
#pragma unroll
    for (int e = 1; e < Ec; e++)
      if (p[e] > p[i0]) i0 = e;
    int i1 = (i0 == 0) ? 1 : 0;
#pragma unroll
    for (int e = 0; e < Ec; e++)
      if (e != i0 && p[e] > p[i1]) i1 = e;
    float wsum = p[i0] + p[i1];
    int s0 = atomicAdd(&cnt[i0], 1);
    idx[i0 * Nc + s0] = gw;
    wt[i0 * Nc + s0] = p[i0] / wsum;
    int s1 = atomicAdd(&cnt[i1], 1);
    idx[i1 * Nc + s1] = gw;
    wt[i1 * Nc + s1] = p[i1] / wsum;
  }
}

__global__ __launch_bounds__(256) void k_aux(const float* __restrict__ probs,
                                             float* __restrict__ outp) {
  int tid = threadIdx.x;
  int lane = tid & 63, w = tid >> 6;
  float acc[Ec] = {};
  for (int n = tid; n < Nc; n += 256) {
#pragma unroll
    for (int e = 0; e < Ec; e++) acc[e] += probs[(size_t)n * Ec + e];
  }
#pragma unroll
  for (int e = 0; e < Ec; e++) {
#pragma unroll
    for (int msk = 1; msk < 64; msk <<= 1) acc[e] += __shfl_xor(acc[e], msk);
  }
  __shared__ float red[4][Ec];
  if (lane == 0) {
#pragma unroll
    for (int e = 0; e < Ec; e++) red[w][e] = acc[e];
  }
  __syncthreads();
  if (tid == 0) {
    float aux = 0.f;
#pragma unroll
    for (int e = 0; e < Ec; e++) {
      float tot = red[0][e] + red[1][e] + red[2][e] + red[3][e];
      float avg = tot * (1.0f / Nc);
      aux += avg * avg;
    }
    outp[0] = (float)Ec * aux;
  }
}

extern "C" void kernel_launch(void* const* d_in, const int* in_sizes, int n_in,
                              void* d_out, int out_size, void* d_ws, size_t ws_size,
                              hipStream_t stream) {
  const float* x      = (const float*)d_in[0];
  const float* ln1_w  = (const float*)d_in[1];
  const float* ln2_w  = (const float*)d_in[2];
  const float* conv_w = (const float*)d_in[3];
  const float* attn_w = (const float*)d_in[4];
  const float* proj_w = (const float*)d_in[5];
  const float* rout_w = (const float*)d_in[6];
  const float* ewv    = (const float*)d_in[7];
  const float* ewo    = (const float*)d_in[8];
  float* out = (float*)d_out;
  float* ws = (float*)d_ws;

  float* h    = ws + OFF_H;
  float* qkv  = ws + OFF_QKV;
  float* h2   = ws + OFF_H2;
  float* prob = ws + OFF_PROB;
  int*   idxp = (int*)(ws + OFF_IDX);
  float* wtp  = ws + OFF_WT;
  int*   cntp = (int*)(ws + OFF_CNT);
  int*   metap = (int*)(ws + OFF_META);
  unsigned short* wqh = (unsigned short*)(ws + OFF_WQH);
  unsigned short* wql = (unsigned short*)(ws + OFF_WQL);
  unsigned short* wph = (unsigned short*)(ws + OFF_WPH);
  unsigned short* wpl = (unsigned short*)(ws + OFF_WPL);
  unsigned short* hch = (unsigned short*)(ws + OFF_HCH);
  unsigned short* hcl = (unsigned short*)(ws + OFF_HCL);
  unsigned short* qhb = (unsigned short*)(ws + OFF_QHB);
  unsigned short* qlb = (unsigned short*)(ws + OFF_QLB);
  unsigned short* khb = (unsigned short*)(ws + OFF_KHB);
  unsigned short* klb = (unsigned short*)(ws + OFF_KLB);
  unsigned short* vhb = (unsigned short*)(ws + OFF_VHB);
  unsigned short* vlb = (unsigned short*)(ws + OFF_VLB);
  unsigned short* yh  = (unsigned short*)(ws + OFF_YH);
  unsigned short* yl  = (unsigned short*)(ws + OFF_YL);
  unsigned short* h2bf = (unsigned short*)(ws + OFF_H2BF);
  unsigned short* ehbf = (unsigned short*)(ws + OFF_EHBF);
  unsigned short* wvbf = (unsigned short*)(ws + OFF_WVBF);
  unsigned short* wobf = (unsigned short*)(ws + OFF_WOBF);

  // attention branch
  k_rmsnorm<<<Nc, 256, 0, stream>>>(x, ln1_w, h);
  k_conv_split<<<(Nc * Cc / 4) / 256, 256, 0, stream>>>(h, conv_w, hch, hcl);
  k_f2bsp<<<(QKVD * Cc / 4) / 256, 256, 0, stream>>>(attn_w, wqh, wql, QKVD * Cc);
  k_f2bsp<<<(Cc * Cc / 4) / 256, 256, 0, stream>>>(proj_w, wph, wpl, Cc * Cc);
  {
    dim3 g(QKVD / 128, Nc / 128);
    k_gemm_x3<0><<<g, 256, 0, stream>>>(hch, hcl, wqh, wql, qkv, nullptr, Nc, QKVD, Cc);
  }
  k_ropeln_q<<<(Nc * Hc * 64) / 256, 256, 0, stream>>>(qkv, qhb, qlb);
  k_ropeln_kv<<<(Nc * KVc * 64) / 256, 256, 0, stream>>>(qkv, khb, klb, vhb, vlb);
  k_attn2<<<dim3(Tc / 128, Hc, Bc), 256, 0, stream>>>(qhb, qlb, khb, klb, vhb, vlb, yh, yl);
  {
    dim3 g(Cc / 128, Nc / 128);
    k_gemm_x3<1><<<g, 256, 0, stream>>>(yh, yl, wph, wpl, out, x, Nc, Cc, Cc);
  }
  // MoE branch: router -> grouped single-launch expert GEMMs (fused silu)
  k_rmsnorm_bf<<<Nc, 256, 0, stream>>>(out, ln2_w, h2, h2bf, cntp);
  k_router<<<Nc / 4, 256, 0, stream>>>(h2, rout_w, prob, idxp, wtp, cntp);
  k_meta<<<1, 64, 0, stream>>>(cntp, metap);
  k_aux<<<1, 256, 0, stream>>>(prob, out + (size_t)Nc * Cc);
  k_f2b<<<(Ec * 2 * Fc * Cc / 4) / 256, 256, 0, stream>>>(ewv, wvbf, Ec * 2 * Fc * Cc);
  k_f2b<<<(Ec * Cc * Fc / 4) / 256, 256, 0, stream>>>(ewo, wobf, Ec * Cc * Fc);
  k_moe_wv<<<dim3(Fc / 64, MAXTILES), 256, 0, stream>>>(h2bf, wvbf, ehbf, idxp, cntp, metap);
  k_moe_wo<<<dim3(Cc / 128, MAXTILES), 256, 0, stream>>>(ehbf, wobf, out, idxp, wtp, cntp,
                                                         metap);
}

// Round 13
// 428.285 us; speedup vs baseline: 1.4083x; 1.1888x over previous
//
#include <hip/hip_runtime.h>
#include <math.h>

namespace {
constexpr int Bc = 2, Tc = 2048, Cc = 1024, Hc = 16, KVc = 4, HDc = 64, Ec = 8, Fc = 1024;
constexpr int Nc = Bc * Tc;               // 4096 tokens
constexpr int QKVD = Cc + 2 * KVc * HDc;  // 1536
constexpr int GRP = Hc / KVc;             // 4
constexpr float RBASE = 50000.0f;
constexpr int MAXTILES = 72;              // worst-case sum of ceil(cnt[e]/128)

// workspace layout (floats) — peak ≤ 24M floats = 96 MB (proven footprint)
// ---- attention phase ----
constexpr size_t OFF_WQH = 0;                        // 0.75M (attn_w hi, bf16)
constexpr size_t OFF_WQL = 768u * 1024;              // 0.75M
constexpr size_t OFF_WPH = 1536u * 1024;             // 0.5M  (proj_w hi)
constexpr size_t OFF_WPL = 2048u * 1024;             // 0.5M
constexpr size_t OFF_H   = 2560u * 1024;             // 4M    (rmsnorm out; dead after conv)
constexpr size_t OFF_HCH = 6656u * 1024;             // 2M    (conv out hi, bf16)
constexpr size_t OFF_HCL = 8704u * 1024;             // 2M
constexpr size_t OFF_QKV = 10752u * 1024;            // 6M fp32
constexpr size_t OFF_QHB = 16896u * 1024;            // 2M floats = 4M bf16 (q hi, tiled)
constexpr size_t OFF_QLB = 18944u * 1024;            // 2M floats (q lo)
constexpr size_t OFF_KHB = 20992u * 1024;            // 0.5M floats (k hi, tiled swz)
constexpr size_t OFF_KLB = 21504u * 1024;            // 0.5M
constexpr size_t OFF_VHB = 22016u * 1024;            // 0.5M (vT hi, tiled swz)
constexpr size_t OFF_VLB = 22528u * 1024;            // 0.5M
constexpr size_t OFF_YH  = 2560u * 1024;             // 2M (attn out hi; over dead h)
constexpr size_t OFF_YL  = 4608u * 1024;             // 2M
// ---- MoE phase (attention buffers dead) ----
constexpr size_t OFF_H2   = 0;                       // 4M (h2 fp32)
constexpr size_t OFF_H2BF = 4u * 1024 * 1024;        // 2M floats = 4M bf16
constexpr size_t OFF_EHBF = 6u * 1024 * 1024;        // 4M floats = 8192 x 1024 bf16
constexpr size_t OFF_WVBF = 10u * 1024 * 1024;       // 8.4M floats
constexpr size_t OFF_WOBF = 18u * 1024 * 1024 + 512u * 1024;  // 4.2M floats
constexpr size_t OFF_PROB = 23u * 1024 * 1024;       // 32k floats
constexpr size_t OFF_IDX  = OFF_PROB + 32768;        // 32k ints (E x Nc)
constexpr size_t OFF_WT   = OFF_IDX + 32768;         // 32k floats
constexpr size_t OFF_CNT  = OFF_WT + 32768;          // 256 ints (cnt[e*32], 1 line/expert)
constexpr size_t OFF_META = OFF_CNT + 256;           // 32 ints
}

typedef __attribute__((ext_vector_type(8))) short short8v;   // 8 bf16 (4 VGPRs)
typedef __attribute__((ext_vector_type(4))) short short4v;   // 4 bf16 (2 VGPRs)
typedef __attribute__((ext_vector_type(4))) float f32x4;

#define MF32(a, b, c) __builtin_amdgcn_mfma_f32_16x16x32_bf16((a), (b), (c), 0, 0, 0)
#define AS1 __attribute__((address_space(1)))
#define AS3 __attribute__((address_space(3)))

__device__ __forceinline__ unsigned short f2b1(float f) {
  union { float f; unsigned int u; } x;
  x.f = f;
  unsigned int r = (x.u + 0x7FFFu + ((x.u >> 16) & 1u)) >> 16;
  return (unsigned short)r;
}

__device__ __forceinline__ float b2f(unsigned short h) {
  union { unsigned int u; float f; } x;
  x.u = (unsigned int)h << 16;
  return x.f;
}

// split fp32 -> bf16 hi + bf16 lo (x ~= hi + lo, |err| ~ 2^-18 |x|)
__device__ __forceinline__ void split4(float4 v, short4v& hi, short4v& lo) {
  unsigned short h0 = f2b1(v.x), h1 = f2b1(v.y), h2 = f2b1(v.z), h3 = f2b1(v.w);
  hi = short4v{(short)h0, (short)h1, (short)h2, (short)h3};
  lo = short4v{(short)f2b1(v.x - b2f(h0)), (short)f2b1(v.y - b2f(h1)),
               (short)f2b1(v.z - b2f(h2)), (short)f2b1(v.w - b2f(h3))};
}

// ---------------- rmsnorm ----------------
__global__ __launch_bounds__(256) void k_rmsnorm(const float* __restrict__ in,
                                                 const float* __restrict__ w,
                                                 float* __restrict__ out) {
  int n = blockIdx.x;
  int tid = threadIdx.x;
  const float* row = in + (size_t)n * Cc;
  float v[4];
  float ss = 0.f;
#pragma unroll
  for (int i = 0; i < 4; i++) {
    v[i] = row[tid + i * 256];
    ss += v[i] * v[i];
  }
#pragma unroll
  for (int m = 1; m < 64; m <<= 1) ss += __shfl_xor(ss, m);
  __shared__ float red[4];
  if ((tid & 63) == 0) red[tid >> 6] = ss;
  __syncthreads();
  float tot = red[0] + red[1] + red[2] + red[3];
  float rs = rsqrtf(tot * (1.0f / Cc) + 1e-6f);
  float* orow = out + (size_t)n * Cc;
#pragma unroll
  for (int i = 0; i < 4; i++) orow[tid + i * 256] = v[i] * rs * w[tid + i * 256];
}

// ----- rmsnorm + bf16 copy + expert-counter zeroing (MoE-side, fused) -----
__global__ __launch_bounds__(256) void k_rmsnorm_bf(const float* __restrict__ in,
                                                    const float* __restrict__ w,
                                                    float* __restrict__ out,
                                                    unsigned short* __restrict__ outbf,
                                                    int* __restrict__ cnt) {
  if (blockIdx.x == 0) cnt[threadIdx.x] = 0;  // 256 ints: 8 experts x 32-int stride
  int n = blockIdx.x;
  int tid = threadIdx.x;
  const float* row = in + (size_t)n * Cc;
  float v[4];
  float ss = 0.f;
#pragma unroll
  for (int i = 0; i < 4; i++) {
    v[i] = row[tid + i * 256];
    ss += v[i] * v[i];
  }
#pragma unroll
  for (int m = 1; m < 64; m <<= 1) ss += __shfl_xor(ss, m);
  __shared__ float red[4];
  if ((tid & 63) == 0) red[tid >> 6] = ss;
  __syncthreads();
  float tot = red[0] + red[1] + red[2] + red[3];
  float rs = rsqrtf(tot * (1.0f / Cc) + 1e-6f);
  float* orow = out + (size_t)n * Cc;
  unsigned short* obf = outbf + (size_t)n * Cc;
#pragma unroll
  for (int i = 0; i < 4; i++) {
    float r = v[i] * rs * w[tid + i * 256];
    orow[tid + i * 256] = r;
    obf[tid + i * 256] = f2b1(r);
  }
}

// -------- causal depthwise conv1d, fused fp32->bf16 hi/lo split --------
__global__ __launch_bounds__(256) void k_conv_split(const float* __restrict__ h,
                                                    const float* __restrict__ cw,
                                                    unsigned short* __restrict__ oh,
                                                    unsigned short* __restrict__ ol) {
  int i4 = blockIdx.x * 256 + threadIdx.x;
  if (i4 >= Nc * Cc / 4) return;
  int idx = i4 * 4;
  int c = idx & (Cc - 1);
  int n = idx >> 10;
  int t = n & (Tc - 1);
  float4 z = make_float4(0.f, 0.f, 0.f, 0.f);
  float4 d2 = (t >= 2) ? *(const float4*)&h[idx - 2 * Cc] : z;
  float4 d1 = (t >= 1) ? *(const float4*)&h[idx - Cc] : z;
  float4 d0 = *(const float4*)&h[idx];
  float4 r;
  r.x = d2.x * cw[(c + 0) * 3] + d1.x * cw[(c + 0) * 3 + 1] + d0.x * cw[(c + 0) * 3 + 2];
  r.y = d2.y * cw[(c + 1) * 3] + d1.y * cw[(c + 1) * 3 + 1] + d0.y * cw[(c + 1) * 3 + 2];
  r.z = d2.z * cw[(c + 2) * 3] + d1.z * cw[(c + 2) * 3 + 1] + d0.z * cw[(c + 2) * 3 + 2];
  r.w = d2.w * cw[(c + 3) * 3] + d1.w * cw[(c + 3) * 3 + 1] + d0.w * cw[(c + 3) * 3 + 2];
  short4v hi, lo;
  split4(r, hi, lo);
  *(short4v*)&oh[idx] = hi;
  *(short4v*)&ol[idx] = lo;
}

// ---------------- fp32 -> bf16 hi/lo split (weights) ----------------
__global__ __launch_bounds__(256) void k_f2bsp(const float* __restrict__ in,
                                               unsigned short* __restrict__ oh,
                                               unsigned short* __restrict__ ol, int n) {
  int i = (blockIdx.x * 256 + threadIdx.x) * 4;
  if (i >= n) return;
  float4 v = *(const float4*)&in[i];
  short4v hi, lo;
  split4(v, hi, lo);
  *(short4v*)&oh[i] = hi;
  *(short4v*)&ol[i] = lo;
}

// ---------------- fp32 -> bf16 conversion ----------------
__global__ __launch_bounds__(256) void k_f2b(const float* __restrict__ in,
                                             unsigned short* __restrict__ outp, int n) {
  int i = (blockIdx.x * 256 + threadIdx.x) * 4;
  if (i >= n) return;
  float4 v = *(const float4*)&in[i];
  uint2 o;
  o.x = (unsigned int)f2b1(v.x) | ((unsigned int)f2b1(v.y) << 16);
  o.y = (unsigned int)f2b1(v.z) | ((unsigned int)f2b1(v.w) << 16);
  *(uint2*)&outp[i] = o;
}

// ------- bf16x3 MFMA GEMM: C = A.B^T with A,B split hi/lo (m97 structure) ----
// EPI 0: C = acc ; EPI 1: C = resid + acc
template <int EPI>
__global__ __launch_bounds__(256) void k_gemm_x3(const unsigned short* __restrict__ Ah,
                                                 const unsigned short* __restrict__ Al,
                                                 const unsigned short* __restrict__ Bh,
                                                 const unsigned short* __restrict__ Bl,
                                                 float* __restrict__ Cm,
                                                 const float* __restrict__ resid,
                                                 int M, int N, int K) {
  constexpr int BM = 128, BN = 128, BK = 32;
  __shared__ __align__(16) unsigned short lAh[BM * BK];
  __shared__ __align__(16) unsigned short lAl[BM * BK];
  __shared__ __align__(16) unsigned short lBh[BN * BK];
  __shared__ __align__(16) unsigned short lBl[BN * BK];
  int tid = threadIdx.x;
  int lane = tid & 63;
  int wave = tid >> 6;
  int wr = wave >> 1, wc = wave & 1;
  int m0 = blockIdx.y * BM, n0 = blockIdx.x * BN;

  f32x4 acc[4][4];
#pragma unroll
  for (int i = 0; i < 4; i++)
#pragma unroll
    for (int j = 0; j < 4; j++) acc[i][j] = (f32x4)0.f;

  int kf = (lane >> 4) * 8;
  int rl = lane & 15;

  for (int k0 = 0; k0 < K; k0 += BK) {
    __syncthreads();
#pragma unroll
    for (int j = 0; j < 2; j++) {
      int chunk = j * 256 + tid;
      int row = chunk >> 2;
      int cb = (chunk & 3) * 8;
      size_t aoff = (size_t)(m0 + row) * K + k0 + cb;
      size_t boff = (size_t)(n0 + row) * K + k0 + cb;
      __builtin_amdgcn_global_load_lds((const AS1 void*)(Ah + aoff),
                                       (AS3 void*)(&lAh[chunk * 8]), 16, 0, 0);
      __builtin_amdgcn_global_load_lds((const AS1 void*)(Al + aoff),
                                       (AS3 void*)(&lAl[chunk * 8]), 16, 0, 0);
      __builtin_amdgcn_global_load_lds((const AS1 void*)(Bh + boff),
                                       (AS3 void*)(&lBh[chunk * 8]), 16, 0, 0);
      __builtin_amdgcn_global_load_lds((const AS1 void*)(Bl + boff),
                                       (AS3 void*)(&lBl[chunk * 8]), 16, 0, 0);
    }
    asm volatile("s_waitcnt vmcnt(0)" ::: "memory");
    __syncthreads();

    short8v ah[4], al4[4], bh4[4], bl4[4];
#pragma unroll
    for (int i = 0; i < 4; i++) {
      int ro = (wr * 64 + i * 16 + rl) * BK + kf;
      ah[i] = *(const short8v*)&lAh[ro];
      al4[i] = *(const short8v*)&lAl[ro];
    }
#pragma unroll
    for (int j = 0; j < 4; j++) {
      int ro = (wc * 64 + j * 16 + rl) * BK + kf;
      bh4[j] = *(const short8v*)&lBh[ro];
      bl4[j] = *(const short8v*)&lBl[ro];
    }
#pragma unroll
    for (int i = 0; i < 4; i++)
#pragma unroll
      for (int j = 0; j < 4; j++) {
        acc[i][j] = MF32(ah[i], bh4[j], acc[i][j]);
        acc[i][j] = MF32(ah[i], bl4[j], acc[i][j]);
        acc[i][j] = MF32(al4[i], bh4[j], acc[i][j]);
      }
  }

  int cl = lane & 15;
  int rb = (lane >> 4) * 4;
#pragma unroll
  for (int i = 0; i < 4; i++) {
#pragma unroll
    for (int r = 0; r < 4; r++) {
      int m = m0 + wr * 64 + i * 16 + rb + r;
#pragma unroll
      for (int j = 0; j < 4; j++) {
        int n = n0 + wc * 64 + j * 16 + cl;
        size_t off = (size_t)m * N + n;
        if (EPI == 0) Cm[off] = acc[i][j][r];
        else Cm[off] = resid[off] + acc[i][j][r];
      }
    }
  }
}

// ------- grouped MoE up-proj + fused SwiGLU: all experts, one launch --------
// BN=64 (verified r12: occupancy fix, 538->509)
__global__ __launch_bounds__(256) void k_moe_wv(const unsigned short* __restrict__ A,
                                                const unsigned short* __restrict__ Wv,
                                                unsigned short* __restrict__ Eh,
                                                const int* __restrict__ idx,
                                                const int* __restrict__ cnt,
                                                const int* __restrict__ meta) {
  constexpr int BK = 32;
  if ((int)blockIdx.y >= meta[16 + 8]) return;
  int e = 0;
#pragma unroll
  for (int i = 1; i < Ec; i++)
    if ((int)blockIdx.y >= meta[16 + i]) e = i;
  int lm = blockIdx.y - meta[16 + e];
  int count = cnt[e * 32];
  int gb = meta[e];
  int m0 = lm * 128;
  int n0 = blockIdx.x * 64;

  __shared__ __align__(16) unsigned short lA[128 * BK];   // 8 KB
  __shared__ __align__(16) unsigned short lBg[64 * BK];   // 4 KB
  __shared__ __align__(16) unsigned short lBv[64 * BK];   // 4 KB
  int tid = threadIdx.x;
  int lane = tid & 63;
  int wave = tid >> 6;
  int wr = wave >> 1, wc = wave & 1;  // wave tile: 64 rows x 32 cols

  const unsigned short* srcA[2];
  const unsigned short* srcG;
  const unsigned short* srcV;
#pragma unroll
  for (int j = 0; j < 2; j++) {
    int chunk = j * 256 + tid;
    int row = chunk >> 2, cb = (chunk & 3) * 8;
    int mrow = m0 + row;
    int tok = idx[e * Nc + (mrow < count ? mrow : count - 1)];
    srcA[j] = A + (size_t)tok * Cc + cb;
  }
  {
    int row = tid >> 2, cb = (tid & 3) * 8;
    const unsigned short* wbase = Wv + (size_t)e * 2 * Fc * Cc;
    srcG = wbase + (size_t)(n0 + row) * Cc + cb;
    srcV = wbase + (size_t)(Fc + n0 + row) * Cc + cb;
  }

  f32x4 accG[4][2], accV[4][2];
#pragma unroll
  for (int i = 0; i < 4; i++)
#pragma unroll
    for (int j = 0; j < 2; j++) {
      accG[i][j] = (f32x4)0.f;
      accV[i][j] = (f32x4)0.f;
    }

  int kf = (lane >> 4) * 8;
  int rl = lane & 15;

  for (int k0 = 0; k0 < Cc; k0 += BK) {
    __syncthreads();
#pragma unroll
    for (int j = 0; j < 2; j++) {
      int chunk = j * 256 + tid;
      __builtin_amdgcn_global_load_lds((const AS1 void*)(srcA[j] + k0),
                                       (AS3 void*)(&lA[chunk * 8]), 16, 0, 0);
    }
    __builtin_amdgcn_global_load_lds((const AS1 void*)(srcG + k0),
                                     (AS3 void*)(&lBg[tid * 8]), 16, 0, 0);
    __builtin_amdgcn_global_load_lds((const AS1 void*)(srcV + k0),
                                     (AS3 void*)(&lBv[tid * 8]), 16, 0, 0);
    asm volatile("s_waitcnt vmcnt(0)" ::: "memory");
    __syncthreads();

    short8v a[4], bg[2], bv[2];
#pragma unroll
    for (int i = 0; i < 4; i++)
      a[i] = *(const short8v*)&lA[(wr * 64 + i * 16 + rl) * BK + kf];
#pragma unroll
    for (int j = 0; j < 2; j++) {
      bg[j] = *(const short8v*)&lBg[(wc * 32 + j * 16 + rl) * BK + kf];
      bv[j] = *(const short8v*)&lBv[(wc * 32 + j * 16 + rl) * BK + kf];
    }
#pragma unroll
    for (int i = 0; i < 4; i++)
#pragma unroll
      for (int j = 0; j < 2; j++) {
        accG[i][j] = MF32(a[i], bg[j], accG[i][j]);
        accV[i][j] = MF32(a[i], bv[j], accV[i][j]);
      }
  }

  int cl = lane & 15;
  int rb = (lane >> 4) * 4;
#pragma unroll
  for (int i = 0; i < 4; i++) {
#pragma unroll
    for (int r = 0; r < 4; r++) {
      int m = m0 + wr * 64 + i * 16 + rb + r;
      if (m < count) {
        size_t gs = (size_t)(gb + m);
#pragma unroll
        for (int j = 0; j < 2; j++) {
          int n = n0 + wc * 32 + j * 16 + cl;
          float g = accG[i][j][r];
          float v = accV[i][j][r];
          Eh[gs * Fc + n] = f2b1(g / (1.0f + __expf(-g)) * v);
        }
      }
    }
  }
}

// ------- grouped MoE down-proj + weighted scatter: all experts, one launch ---
__global__ __launch_bounds__(256) void k_moe_wo(const unsigned short* __restrict__ Eh,
                                                const unsigned short* __restrict__ Wo,
                                                float* __restrict__ C,
                                                const int* __restrict__ idx,
                                                const float* __restrict__ wt,
                                                const int* __restrict__ cnt,
                                                const int* __restrict__ meta) {
  constexpr int BK = 32;
  if ((int)blockIdx.y >= meta[16 + 8]) return;
  int e = 0;
#pragma unroll
  for (int i = 1; i < Ec; i++)
    if ((int)blockIdx.y >= meta[16 + i]) e = i;
  int lm = blockIdx.y - meta[16 + e];
  int count = cnt[e * 32];
  int gb = meta[e];
  int m0 = lm * 128;
  int n0 = blockIdx.x * 128;

  __shared__ __align__(16) unsigned short lA[128 * BK];
  __shared__ __align__(16) unsigned short lB[128 * BK];
  int tid = threadIdx.x;
  int lane = tid & 63;
  int wave = tid >> 6;
  int wr = wave >> 1, wc = wave & 1;

  f32x4 acc[4][4];
#pragma unroll
  for (int i = 0; i < 4; i++)
#pragma unroll
    for (int j = 0; j < 4; j++) acc[i][j] = (f32x4)0.f;

  int kf = (lane >> 4) * 8;
  int rl = lane & 15;

  for (int k0 = 0; k0 < Fc; k0 += BK) {
    __syncthreads();
#pragma unroll
    for (int j = 0; j < 2; j++) {
      int chunk = j * 256 + tid;
      int row = chunk >> 2;
      int cb = (chunk & 3) * 8;
      __builtin_amdgcn_global_load_lds(
          (const AS1 void*)(Eh + (size_t)(gb + m0 + row) * Fc + k0 + cb),
          (AS3 void*)(&lA[chunk * 8]), 16, 0, 0);
      __builtin_amdgcn_global_load_lds(
          (const AS1 void*)(Wo + (size_t)e * Cc * Fc + (size_t)(n0 + row) * Fc + k0 + cb),
          (AS3 void*)(&lB[chunk * 8]), 16, 0, 0);
    }
    asm volatile("s_waitcnt vmcnt(0)" ::: "memory");
    __syncthreads();

    short8v a[4], b[4];
#pragma unroll
    for (int i = 0; i < 4; i++)
      a[i] = *(const short8v*)&lA[(wr * 64 + i * 16 + rl) * BK + kf];
#pragma unroll
    for (int j = 0; j < 4; j++)
      b[j] = *(const short8v*)&lB[(wc * 64 + j * 16 + rl) * BK + kf];
#pragma unroll
    for (int i = 0; i < 4; i++)
#pragma unroll
      for (int j = 0; j < 4; j++)
        acc[i][j] = MF32(a[i], b[j], acc[i][j]);
  }

  int cl = lane & 15;
  int rb = (lane >> 4) * 4;
#pragma unroll
  for (int i = 0; i < 4; i++) {
#pragma unroll
    for (int r = 0; r < 4; r++) {
      int m = m0 + wr * 64 + i * 16 + rb + r;
      if (m < count) {
        int slot = e * Nc + m;
        int tok = idx[slot];
        float w = wt[slot];
#pragma unroll
        for (int j = 0; j < 4; j++) {
          int n = n0 + wc * 64 + j * 16 + cl;
          atomicAdd(&C[(size_t)tok * Cc + n], w * acc[i][j][r]);
        }
      }
    }
  }
}

// ---------------- RoPE + layernorm ----------------
__device__ __forceinline__ float rope_ln(float q, int lane, int t, float scale) {
  int j = lane & 31;
  float invf = powf(RBASE, -(float)j * (1.0f / 32.0f));
  float ang = (float)t * invf;
  float s, c;
  sincosf(ang, &s, &c);
  float p = __shfl_xor(q, 32);
  float rot = (lane < 32) ? -p : p;
  float qr = q * c + rot * s;
  float sum = qr, sq = qr * qr;
#pragma unroll
  for (int m = 1; m < 64; m <<= 1) {
    sum += __shfl_xor(sum, m);
    sq += __shfl_xor(sq, m);
  }
  float mean = sum * (1.0f / 64.0f);
  float var = sq * (1.0f / 64.0f) - mean * mean;
  return (qr - mean) * rsqrtf(var + 1e-5f) * scale;
}

// Q: bf16 hi/lo in pre-swizzled tile-blocked layout:
//   tile (64 rows x 64 d) at ((b*H+h)*32 + t/64)*4096; short off = row*64 + (d ^ ((row&7)<<3))
__global__ __launch_bounds__(256) void k_ropeln_q(const float* __restrict__ qkv,
                                                  unsigned short* __restrict__ qh,
                                                  unsigned short* __restrict__ ql) {
  int gw = (blockIdx.x * 256 + threadIdx.x) >> 6;
  int lane = threadIdx.x & 63;
  if (gw >= Nc * Hc) return;
  int h = gw & (Hc - 1);
  int n = gw / Hc;
  int t = n & (Tc - 1);
  int b = n / Tc;
  float q = qkv[(size_t)n * QKVD + h * HDc + lane];
  float o = rope_ln(q, lane, t, 0.125f);  // fold 1/sqrt(hd)
  int row = t & 63;
  size_t ob = (((size_t)(b * Hc + h)) * 32 + (t >> 6)) * 4096 + row * 64 +
              (lane ^ ((row & 7) << 3));
  unsigned short hi = f2b1(o);
  qh[ob] = hi;
  ql[ob] = f2b1(o - b2f(hi));
}

// K: same swizzled tile layout as Q. V: TRANSPOSED tile [64 d][64 key], swizzled:
//   short off = d*64 + (key ^ ((d&7)<<3)) — PV A-frags become plain b128 reads.
__global__ __launch_bounds__(256) void k_ropeln_kv(const float* __restrict__ qkv,
                                                   unsigned short* __restrict__ kh,
                                                   unsigned short* __restrict__ kl,
                                                   unsigned short* __restrict__ vh,
                                                   unsigned short* __restrict__ vl) {
  int gw = (blockIdx.x * 256 + threadIdx.x) >> 6;
  int lane = threadIdx.x & 63;
  if (gw >= Nc * KVc) return;
  int kv = gw & (KVc - 1);
  int n = gw / KVc;
  int t = n & (Tc - 1);
  int b = n / Tc;
  size_t base = (size_t)n * QKVD + Cc + kv * HDc;
  float kval = qkv[base + lane];
  float vval = qkv[base + KVc * HDc + lane];
  float o = rope_ln(kval, lane, t, 1.0f);
  int row = t & 63;  // key index within tile
  size_t tb = (((size_t)(b * KVc + kv)) * 32 + (t >> 6)) * 4096;
  size_t ko = tb + row * 64 + (lane ^ ((row & 7) << 3));
  unsigned short khi = f2b1(o);
  kh[ko] = khi;
  kl[ko] = f2b1(o - b2f(khi));
  // vT: d = lane (row of vT), key = row (column)
  size_t vo = tb + (size_t)lane * 64 + (row ^ ((lane & 7) << 3));
  unsigned short vhi = f2b1(vval);
  vh[vo] = vhi;
  vl[vo] = f2b1(vval - b2f(vhi));
}

// ---------------- flash attention, bf16x3 MFMA, swapped-operand S^T ---------
// BQ=64 (4 waves x 16 q), BK=64. Single-buffer 48KB (3 blocks/CU).
// CAUSAL WORK PAIRING: each block handles qtiles {63-bx, bx} -> uniform 65
// tile-units per block (verified r11: 591->538).
__global__ __launch_bounds__(256, 3) void k_attn2(const unsigned short* __restrict__ Qh,
                                                  const unsigned short* __restrict__ Ql,
                                                  const unsigned short* __restrict__ Kht,
                                                  const unsigned short* __restrict__ Klt,
                                                  const unsigned short* __restrict__ Vht,
                                                  const unsigned short* __restrict__ Vlt,
                                                  unsigned short* __restrict__ Yh,
                                                  unsigned short* __restrict__ Yl) {
  __shared__ __align__(16) unsigned char smem[49152];
  constexpr unsigned QH = 0, QL = 8192, KH = 16384, KL = 24576, VB = 32768, PB = 0;
  int tid = threadIdx.x;
  int l = tid & 63, w = tid >> 6, g = l >> 4, q15 = l & 15;
  int bx = blockIdx.x;  // 0..31
  int hh = blockIdx.y, b = blockIdx.z;
  int kvh = hh >> 2;  // GQA
  size_t kvb = ((size_t)(b * KVc + kvh)) * 32 * 4096;
  unsigned qsw = (unsigned)((q15 & 7) << 4);
  unsigned qro = (unsigned)((w * 16 + q15) * 128);
  int qloc = w * 16 + q15;

  for (int which = 0; which < 2; ++which) {
    int qtile = which == 0 ? (Tc / 64 - 1 - bx) : bx;  // long half first
    size_t qtb = (((size_t)(b * Hc + hh)) * 32 + qtile) * 4096;
    __syncthreads();  // prior pass done with P/Q LDS region
    // ---- stage Q via async, pre-swizzled source ----
#pragma unroll
    for (int j = 0; j < 2; j++) {
      int chunk = j * 256 + tid;
      __builtin_amdgcn_global_load_lds((const AS1 void*)(Qh + qtb + chunk * 8),
                                       (AS3 void*)(smem + QH + chunk * 16), 16, 0, 0);
      __builtin_amdgcn_global_load_lds((const AS1 void*)(Ql + qtb + chunk * 8),
                                       (AS3 void*)(smem + QL + chunk * 16), 16, 0, 0);
    }
    asm volatile("s_waitcnt vmcnt(0)" ::: "memory");
    __syncthreads();
    short8v qhf[2], qlf[2];
    qhf[0] = *(const short8v*)(smem + QH + qro + ((16 * g) ^ qsw));
    qhf[1] = *(const short8v*)(smem + QH + qro + ((64 + 16 * g) ^ qsw));
    qlf[0] = *(const short8v*)(smem + QL + qro + ((16 * g) ^ qsw));
    qlf[1] = *(const short8v*)(smem + QL + qro + ((64 + 16 * g) ^ qsw));

    f32x4 o[4];
#pragma unroll
    for (int dt = 0; dt < 4; dt++) o[dt] = (f32x4)0.f;
    float m = -1e30f, lsum = 0.f;

    for (int kt = 0; kt <= qtile; ++kt) {
      __syncthreads();  // prior-iter LDS reads done before overwrite
      size_t ktb = kvb + (size_t)kt * 4096;
#pragma unroll
      for (int j = 0; j < 2; j++) {
        int chunk = j * 256 + tid;
        __builtin_amdgcn_global_load_lds((const AS1 void*)(Kht + ktb + chunk * 8),
                                         (AS3 void*)(smem + KH + chunk * 16), 16, 0, 0);
        __builtin_amdgcn_global_load_lds((const AS1 void*)(Klt + ktb + chunk * 8),
                                         (AS3 void*)(smem + KL + chunk * 16), 16, 0, 0);
        __builtin_amdgcn_global_load_lds((const AS1 void*)(Vht + ktb + chunk * 8),
                                         (AS3 void*)(smem + VB + chunk * 16), 16, 0, 0);
        __builtin_amdgcn_global_load_lds((const AS1 void*)(Vlt + ktb + chunk * 8),
                                         (AS3 void*)(smem + VB + 8192 + chunk * 16), 16, 0,
                                         0);
      }
      asm volatile("s_waitcnt vmcnt(0)" ::: "memory");
      __syncthreads();
      const bool diag = (kt == qtile);

      // ---- S^T = K·Q^T (3-term bf16 split), per wave: [64 keys][16 q] ----
      f32x4 sv[4];
#pragma unroll
      for (int s = 0; s < 4; ++s) {
        unsigned ro = (unsigned)((s * 16 + q15) * 128);
        short8v kh0 = *(const short8v*)(smem + KH + ro + ((16 * g) ^ qsw));
        short8v kh1 = *(const short8v*)(smem + KH + ro + ((64 + 16 * g) ^ qsw));
        short8v kl0 = *(const short8v*)(smem + KL + ro + ((16 * g) ^ qsw));
        short8v kl1 = *(const short8v*)(smem + KL + ro + ((64 + 16 * g) ^ qsw));
        f32x4 a = (f32x4)0.f;
        a = MF32(kh0, qhf[0], a);
        a = MF32(kh1, qhf[1], a);
        a = MF32(kh0, qlf[0], a);
        a = MF32(kh1, qlf[1], a);
        a = MF32(kl0, qhf[0], a);
        a = MF32(kl1, qhf[1], a);
        sv[s] = a;
      }
      // ---- causal mask + online softmax ----
      float mx = -1e30f;
#pragma unroll
      for (int s = 0; s < 4; ++s)
#pragma unroll
        for (int r = 0; r < 4; ++r) {
          if (diag && (s * 16 + g * 4 + r) > qloc) sv[s][r] = -1e30f;
          mx = fmaxf(mx, sv[s][r]);
        }
      mx = fmaxf(mx, __shfl_xor(mx, 16));
      mx = fmaxf(mx, __shfl_xor(mx, 32));
      float mnew = fmaxf(m, mx);
      float alpha = __expf(m - mnew);
      float p[4][4];
      float ps = 0.f;
#pragma unroll
      for (int s = 0; s < 4; ++s)
#pragma unroll
        for (int r = 0; r < 4; ++r) {
          p[s][r] = __expf(sv[s][r] - mnew);
          ps += p[s][r];
        }
      ps += __shfl_xor(ps, 16);
      ps += __shfl_xor(ps, 32);
      lsum = lsum * alpha + ps;
      m = mnew;
#pragma unroll
      for (int dt = 0; dt < 4; dt++) o[dt] *= alpha;
      // ---- P -> bf16 hi/lo, bounce through per-wave LDS ----
#pragma unroll
      for (int s = 0; s < 4; ++s) {
        unsigned short h0 = f2b1(p[s][0]), h1 = f2b1(p[s][1]), h2 = f2b1(p[s][2]),
                       h3 = f2b1(p[s][3]);
        short4v ph = short4v{(short)h0, (short)h1, (short)h2, (short)h3};
        short4v pl = short4v{(short)f2b1(p[s][0] - b2f(h0)), (short)f2b1(p[s][1] - b2f(h1)),
                             (short)f2b1(p[s][2] - b2f(h2)), (short)f2b1(p[s][3] - b2f(h3))};
        unsigned pb = (unsigned)(PB + w * 4096 + q15 * 128 +
                                 (((unsigned)(s * 32 + 8 * g)) ^ qsw));
        *(short4v*)(smem + pb) = ph;
        *(short4v*)(smem + pb + 2048) = pl;
      }
      asm volatile("" ::: "memory");  // order P writes before reads (same wave)
      // ---- O^T += V^T·P^T (3-term), vT A-frags via plain swizzled b128 ----
#pragma unroll
      for (int kk = 0; kk < 2; ++kk) {
        unsigned pq = (unsigned)(PB + w * 4096 + q15 * 128 +
                                 (((unsigned)(kk * 64 + 16 * g)) ^ qsw));
        short8v ph8 = *(const short8v*)(smem + pq);
        short8v pl8 = *(const short8v*)(smem + pq + 2048);
        unsigned koff = (unsigned)(kk * 64 + g * 16);
#pragma unroll
        for (int dt = 0; dt < 4; ++dt) {
          unsigned off = VB + (unsigned)((dt * 16 + q15) * 128) + (koff ^ qsw);
          short8v vh8 = *(const short8v*)(smem + off);
          short8v vl8 = *(const short8v*)(smem + off + 8192);
          o[dt] = MF32(vh8, ph8, o[dt]);
          o[dt] = MF32(vh8, pl8, o[dt]);
          o[dt] = MF32(vl8, ph8, o[dt]);
        }
      }
    }
    // ---- epilogue: write y as bf16 hi/lo (feeds bf16x3 proj GEMM) ----
    float inv = 1.0f / lsum;
    size_t ybase = ((size_t)(b * Tc + qtile * 64 + qloc)) * Cc + hh * 64;
#pragma unroll
    for (int dt = 0; dt < 4; dt++) {
      float4 s4 = make_float4(o[dt][0] * inv, o[dt][1] * inv, o[dt][2] * inv,
                              o[dt][3] * inv);
      short4v hi, lo;
      split4(s4, hi, lo);
      *(short4v*)&Yh[ybase + dt * 16 + 4 * g] = hi;
      *(short4v*)&Yl[ybase + dt * 16 + 4 * g] = lo;
    }
  }
}

// ---------------- prefix sums: gbase + tilebase ----------------
__global__ void k_meta(const int* __restrict__ cnt, int* __restrict__ meta) {
  if (threadIdx.x == 0) {
    int gb = 0, tb = 0;
    for (int e = 0; e < Ec; e++) {
      meta[e] = gb;
      meta[16 + e] = tb;
      gb += cnt[e * 32];
      tb += (cnt[e * 32] + 127) >> 7;
    }
    meta[8] = gb;
    meta[16 + 8] = tb;
  }
}

// ---------------- router: softmax -> top2 -> compact assignment lists --------
// counters padded to 1 cacheline each (cnt[e*32]) — kills the same-line atomic
// serialization that made this kernel 106us (8192 atomics x ~32cy on ONE line).
__global__ __launch_bounds__(256) void k_router(const float* __restrict__ h2,
                                                const float* __restrict__ rw,
                                                float* __restrict__ probs,
                                                int* __restrict__ idx,
                                                float* __restrict__ wt,
                                                int* __restrict__ cnt) {
  int gw = (blockIdx.x * 256 + threadIdx.x) >> 6;
  int lane = threadIdx.x & 63;
  if (gw >= Nc) return;
  const float* row = h2 + (size_t)gw * Cc;
  float acc[Ec] = {};
  for (int k = lane; k < Cc; k += 64) {
    float hv = row[k];
#pragma unroll
    for (int e = 0; e < Ec; e++) acc[e] += hv * rw[e * Cc + k];
  }
#pragma unroll
  for (int e = 0; e < Ec; e++) {
#pragma unroll
    for (int msk = 1; msk < 64; msk <<= 1) acc[e] += __shfl_xor(acc[e], msk);
  }
  if (lane == 0) {
    float mx = acc[0];
#pragma unroll
    for (int e = 1; e < Ec; e++) mx = fmaxf(mx, acc[e]);
    float p[Ec];
    float s = 0.f;
#pragma unroll
    for (int e = 0; e < Ec; e++) {
      p[e] = expf(acc[e] - mx);
      s += p[e];
    }
    float invs = 1.0f / s;
#pragma unroll
    for (int e = 0; e < Ec; e++) {
      p[e] *= invs;
      probs[(size_t)gw * Ec + e] = p[e];
    }
    int i0 = 0;
#pragma unroll
    for (int e = 1; e < Ec; e++)
      if (p[e] > p[i0]) i0 = e;
    int i1 = (i0 == 0) ? 1 : 0;
#pragma unroll
    for (int e = 0; e < Ec; e++)
      if (e != i0 && p[e] > p[i1]) i1 = e;
    float wsum = p[i0] + p[i1];
    int s0 = atomicAdd(&cnt[i0 * 32], 1);
    int s1 = atomicAdd(&cnt[i1 * 32], 1);
    idx[i0 * Nc + s0] = gw;
    wt[i0 * Nc + s0] = p[i0] / wsum;
    idx[i1 * Nc + s1] = gw;
    wt[i1 * Nc + s1] = p[i1] / wsum;
  }
}

__global__ __launch_bounds__(256) void k_aux(const float* __restrict__ probs,
                                             float* __restrict__ outp) {
  int tid = threadIdx.x;
  int lane = tid & 63, w = tid >> 6;
  float acc[Ec] = {};
  for (int n = tid; n < Nc; n += 256) {
#pragma unroll
    for (int e = 0; e < Ec; e++) acc[e] += probs[(size_t)n * Ec + e];
  }
#pragma unroll
  for (int e = 0; e < Ec; e++) {
#pragma unroll
    for (int msk = 1; msk < 64; msk <<= 1) acc[e] += __shfl_xor(acc[e], msk);
  }
  __shared__ float red[4][Ec];
  if (lane == 0) {
#pragma unroll
    for (int e = 0; e < Ec; e++) red[w][e] = acc[e];
  }
  __syncthreads();
  if (tid == 0) {
    float aux = 0.f;
#pragma unroll
    for (int e = 0; e < Ec; e++) {
      float tot = red[0][e] + red[1][e] + red[2][e] + red[3][e];
      float avg = tot * (1.0f / Nc);
      aux += avg * avg;
    }
    outp[0] = (float)Ec * aux;
  }
}

extern "C" void kernel_launch(void* const* d_in, const int* in_sizes, int n_in,
                              void* d_out, int out_size, void* d_ws, size_t ws_size,
                              hipStream_t stream) {
  const float* x      = (const float*)d_in[0];
  const float* ln1_w  = (const float*)d_in[1];
  const float* ln2_w  = (const float*)d_in[2];
  const float* conv_w = (const float*)d_in[3];
  const float* attn_w = (const float*)d_in[4];
  const float* proj_w = (const float*)d_in[5];
  const float* rout_w = (const float*)d_in[6];
  const float* ewv    = (const float*)d_in[7];
  const float* ewo    = (const float*)d_in[8];
  float* out = (float*)d_out;
  float* ws = (float*)d_ws;

  float* h    = ws + OFF_H;
  float* qkv  = ws + OFF_QKV;
  float* h2   = ws + OFF_H2;
  float* prob = ws + OFF_PROB;
  int*   idxp = (int*)(ws + OFF_IDX);
  float* wtp  = ws + OFF_WT;
  int*   cntp = (int*)(ws + OFF_CNT);
  int*   metap = (int*)(ws + OFF_META);
  unsigned short* wqh = (unsigned short*)(ws + OFF_WQH);
  unsigned short* wql = (unsigned short*)(ws + OFF_WQL);
  unsigned short* wph = (unsigned short*)(ws + OFF_WPH);
  unsigned short* wpl = (unsigned short*)(ws + OFF_WPL);
  unsigned short* hch = (unsigned short*)(ws + OFF_HCH);
  unsigned short* hcl = (unsigned short*)(ws + OFF_HCL);
  unsigned short* qhb = (unsigned short*)(ws + OFF_QHB);
  unsigned short* qlb = (unsigned short*)(ws + OFF_QLB);
  unsigned short* khb = (unsigned short*)(ws + OFF_KHB);
  unsigned short* klb = (unsigned short*)(ws + OFF_KLB);
  unsigned short* vhb = (unsigned short*)(ws + OFF_VHB);
  unsigned short* vlb = (unsigned short*)(ws + OFF_VLB);
  unsigned short* yh  = (unsigned short*)(ws + OFF_YH);
  unsigned short* yl  = (unsigned short*)(ws + OFF_YL);
  unsigned short* h2bf = (unsigned short*)(ws + OFF_H2BF);
  unsigned short* ehbf = (unsigned short*)(ws + OFF_EHBF);
  unsigned short* wvbf = (unsigned short*)(ws + OFF_WVBF);
  unsigned short* wobf = (unsigned short*)(ws + OFF_WOBF);

  // attention branch
  k_rmsnorm<<<Nc, 256, 0, stream>>>(x, ln1_w, h);
  k_conv_split<<<(Nc * Cc / 4) / 256, 256, 0, stream>>>(h, conv_w, hch, hcl);
  k_f2bsp<<<(QKVD * Cc / 4) / 256, 256, 0, stream>>>(attn_w, wqh, wql, QKVD * Cc);
  k_f2bsp<<<(Cc * Cc / 4) / 256, 256, 0, stream>>>(proj_w, wph, wpl, Cc * Cc);
  {
    dim3 g(QKVD / 128, Nc / 128);
    k_gemm_x3<0><<<g, 256, 0, stream>>>(hch, hcl, wqh, wql, qkv, nullptr, Nc, QKVD, Cc);
  }
  k_ropeln_q<<<(Nc * Hc * 64) / 256, 256, 0, stream>>>(qkv, qhb, qlb);
  k_ropeln_kv<<<(Nc * KVc * 64) / 256, 256, 0, stream>>>(qkv, khb, klb, vhb, vlb);
  k_attn2<<<dim3(Tc / 128, Hc, Bc), 256, 0, stream>>>(qhb, qlb, khb, klb, vhb, vlb, yh, yl);
  {
    dim3 g(Cc / 128, Nc / 128);
    k_gemm_x3<1><<<g, 256, 0, stream>>>(yh, yl, wph, wpl, out, x, Nc, Cc, Cc);
  }
  // MoE branch: router -> grouped single-launch expert GEMMs (fused silu)
  k_rmsnorm_bf<<<Nc, 256, 0, stream>>>(out, ln2_w, h2, h2bf, cntp);
  k_router<<<Nc / 4, 256, 0, stream>>>(h2, rout_w, prob, idxp, wtp, cntp);
  k_meta<<<1, 64, 0, stream>>>(cntp, metap);
  k_aux<<<1, 256, 0, stream>>>(prob, out + (size_t)Nc * Cc);
  k_f2b<<<(Ec * 2 * Fc * Cc / 4) / 256, 256, 0, stream>>>(ewv, wvbf, Ec * 2 * Fc * Cc);
  k_f2b<<<(Ec * Cc * Fc / 4) / 256, 256, 0, stream>>>(ewo, wobf, Ec * Cc * Fc);
  k_moe_wv<<<dim3(Fc / 64, MAXTILES), 256, 0, stream>>>(h2bf, wvbf, ehbf, idxp, cntp, metap);
  k_moe_wo<<<dim3(Cc / 128, MAXTILES), 256, 0, stream>>>(ehbf, wobf, out, idxp, wtp, cntp,
                                                         metap);
}